// Round 3
// baseline (886.972 us; speedup 1.0000x reference)
//
#include <hip/hip_runtime.h>
#include <stdint.h>

#define NN 20000
#define NE 320000

typedef unsigned short us16;
typedef __attribute__((ext_vector_type(8))) short short8;
typedef __attribute__((ext_vector_type(4))) float f32x4;

union U4 { uint4 v; us16 s[8]; };
union U2 { uint2 v; us16 s[4]; };

__device__ __forceinline__ float b2f(us16 u){ return __uint_as_float(((unsigned)u)<<16); }
__device__ __forceinline__ us16 f2b(float f){
  unsigned u = __float_as_uint(f);
  u += 0x7fffu + ((u>>16)&1u);
  return (us16)(u>>16);
}

// ---------------- Kernel 1: residual conv(k=1) + gated_conv1 + bn0 partial stats ----------------
// X fp32 [N,C,T]; outputs resid/gc1 bf16
__global__ __launch_bounds__(256) void k1_front(
    const float* __restrict__ X,
    const float* __restrict__ rp_w, const float* __restrict__ rp_b,
    const float* __restrict__ w1, const float* __restrict__ b1,
    const float* __restrict__ w2, const float* __restrict__ b2,
    const float* __restrict__ w3, const float* __restrict__ b3,
    us16* __restrict__ resid, us16* __restrict__ gc1,
    float* __restrict__ bn0_sum, float* __restrict__ bn0_sq)
{
  __shared__ float xs[2048];          // 8 nodes x 32ch x 8t, fp32
  __shared__ float wl[9216];          // [conv][ci*3+k][co] transposed -> conflict-free by co
  __shared__ float rpl[1024];         // [ci][co]
  __shared__ float redS[32], redQ[32];
  const int tid = threadIdx.x;
  for(int idx=tid; idx<3072; idx+=256){
    int co = idx/96, r = idx%96, ci = r/3, k = r%3;
    int l = (ci*3+k)*32 + co;
    wl[l]        = w1[idx];
    wl[3072 + l] = w2[idx];
    wl[6144 + l] = w3[idx];
  }
  for(int idx=tid; idx<1024; idx+=256){
    int co = idx>>5, ci = idx&31;
    rpl[ci*32+co] = rp_w[idx];
  }
  if(tid<32){ redS[tid]=0.f; redQ[tid]=0.f; }
  {
    const float4* Xv = (const float4*)(X + (size_t)blockIdx.x*2048);
    *(float4*)&xs[tid*8]   = Xv[tid*2];
    *(float4*)&xs[tid*8+4] = Xv[tid*2+1];
  }
  __syncthreads();
  const int nl = tid>>5, co = tid&31;
  const float* xrow = &xs[nl*256];
  float aR[8]={}, a1[8]={}, a2[8]={}, a3[8]={};
  for(int ci=0; ci<32; ci++){
    float xv[10];
    xv[0]=0.f; xv[9]=0.f;
    #pragma unroll
    for(int t=0;t<8;t++) xv[t+1] = xrow[ci*8+t];
    const float rw = rpl[ci*32+co];
    const float* wp = &wl[ci*96 + co];
    float u0=wp[0],    u1=wp[32],      u2=wp[64];
    float v0=wp[3072], v1=wp[3072+32], v2=wp[3072+64];
    float q0=wp[6144], q1=wp[6144+32], q2=wp[6144+64];
    #pragma unroll
    for(int t=0;t<8;t++){
      aR[t]=fmaf(rw,xv[t+1],aR[t]);
      a1[t]=fmaf(u0,xv[t],fmaf(u1,xv[t+1],fmaf(u2,xv[t+2],a1[t])));
      a2[t]=fmaf(v0,xv[t],fmaf(v1,xv[t+1],fmaf(v2,xv[t+2],a2[t])));
      a3[t]=fmaf(q0,xv[t],fmaf(q1,xv[t+1],fmaf(q2,xv[t+2],a3[t])));
    }
  }
  const float bR=rp_b[co], bb1=b1[co], bb2=b2[co], bb3=b3[co];
  U4 og, orr;
  float s=0.f, q=0.f;
  #pragma unroll
  for(int t=0;t<8;t++){
    float c1=a1[t]+bb1, c2=a2[t]+bb2, c3=a3[t]+bb3;
    float sg = 1.f/(1.f+__expf(-c2));
    float v = fmaf(c1, sg, c3);
    v = v>0.f ? v : 0.f;
    s += v; q += v*v;
    og.s[t]  = f2b(v);
    orr.s[t] = f2b(aR[t]+bR);
  }
  size_t base = (size_t)blockIdx.x*2048 + nl*256 + co*8;
  *(uint4*)(gc1+base)   = og.v;
  *(uint4*)(resid+base) = orr.v;
  atomicAdd(&redS[co], s); atomicAdd(&redQ[co], q);
  __syncthreads();
  if(tid<32)       atomicAdd(&bn0_sum[tid], redS[tid]);
  else if(tid<64)  atomicAdd(&bn0_sq[tid-32], redQ[tid-32]);
}

// ---------------- BN finalize: scale/shift from sums ----------------
__global__ void k_bnfin(const float* __restrict__ sum, const float* __restrict__ sq,
                        const float* __restrict__ g, const float* __restrict__ b,
                        float* __restrict__ ss, int nch, float inv)
{
  int i = blockIdx.x*blockDim.x + threadIdx.x;
  if(i>=nch) return;
  float m = sum[i]*inv;
  float v = sq[i]*inv - m*m;
  float a = g[i] * rsqrtf(v + 1e-5f);
  ss[2*i]   = a;
  ss[2*i+1] = b[i] - m*a;
}

// ---------------- apply bn0 in-place on gc1 (bf16) ----------------
__global__ __launch_bounds__(256) void k_xbn(us16* __restrict__ gc1, const float* __restrict__ ss)
{
  size_t base = ((size_t)blockIdx.x*256 + threadIdx.x)*8;
  U4 in, out;
  in.v = *(const uint4*)(gc1+base);
  int ch = (int)((base>>3)&31);
  float a = ss[2*ch], b = ss[2*ch+1];
  #pragma unroll
  for(int j=0;j<8;j++) out.s[j] = f2b(fmaf(a, b2f(in.s[j]), b));
  *(uint4*)(gc1+base) = out.v;
}

// ---------------- convert gat_w fp32 -> bf16 ----------------
__global__ __launch_bounds__(256) void k_cvtw(const float* __restrict__ W, us16* __restrict__ Wb)
{
  int i = blockIdx.x*256 + threadIdx.x;   // 65536 threads, 4 elems each
  float4 v = *(const float4*)(W + (size_t)i*4);
  U2 o;
  o.s[0]=f2b(v.x); o.s[1]=f2b(v.y); o.s[2]=f2b(v.z); o.s[3]=f2b(v.w);
  *(uint2*)(Wb + (size_t)i*4) = o.v;
}

// ---------------- GEMM: h[20000,1024] = A[20000,256] @ Wb[1024,256]^T (MFMA bf16) ----------------
__global__ __launch_bounds__(256) void k_gemm(const us16* __restrict__ A, const us16* __restrict__ B,
                                              us16* __restrict__ H)
{
  __shared__ us16 As[128*72];   // +8 pad: 2-way bank aliasing only (free per m136)
  __shared__ us16 Bs[128*72];
  const int tid = threadIdx.x;
  const int row0 = blockIdx.x*128, col0 = blockIdx.y*128;
  const int lane = tid&63, wv = tid>>6;
  const int wm = wv&1, wn = wv>>1;
  const int mrow = lane&15, kg = (lane>>4)*8;
  f32x4 acc[4][4] = {};
  for(int k0=0; k0<256; k0+=64){
    #pragma unroll
    for(int i=0;i<4;i++){
      int chunk = i*256 + tid;
      int row = chunk>>3, cc = chunk&7;
      int g = row0 + row;
      uint4 av; av.x=0;av.y=0;av.z=0;av.w=0;
      if(g < NN) av = *(const uint4*)(A + (size_t)g*256 + k0 + cc*8);
      *(uint4*)&As[row*72 + cc*8] = av;
      *(uint4*)&Bs[row*72 + cc*8] = *(const uint4*)(B + (size_t)(col0+row)*256 + k0 + cc*8);
    }
    __syncthreads();
    #pragma unroll
    for(int kk=0; kk<64; kk+=32){
      short8 af[4], bfr[4];
      #pragma unroll
      for(int i=0;i<4;i++) af[i]  = *(const short8*)&As[(wm*64 + i*16 + mrow)*72 + kk + kg];
      #pragma unroll
      for(int j=0;j<4;j++) bfr[j] = *(const short8*)&Bs[(wn*64 + j*16 + mrow)*72 + kk + kg];
      #pragma unroll
      for(int i=0;i<4;i++){
        #pragma unroll
        for(int j=0;j<4;j++)
          acc[i][j] = __builtin_amdgcn_mfma_f32_16x16x32_bf16(af[i], bfr[j], acc[i][j], 0, 0, 0);
      }
    }
    __syncthreads();
  }
  #pragma unroll
  for(int i=0;i<4;i++){
    #pragma unroll
    for(int j=0;j<4;j++){
      #pragma unroll
      for(int r=0;r<4;r++){
        int g = row0 + wm*64 + i*16 + (lane>>4)*4 + r;
        if(g < NN)
          H[(size_t)g*1024 + col0 + wn*64 + j*16 + (lane&15)] = f2b(acc[i][j][r]);
      }
    }
  }
}

// ---------------- el/er: per-node per-head attention dots (attn fp32) ----------------
__global__ __launch_bounds__(256) void k_eler(const us16* __restrict__ H,
    const float* __restrict__ al, const float* __restrict__ ar,
    float* __restrict__ el, float* __restrict__ er)
{
  const int wv = threadIdx.x>>6, lane = threadIdx.x&63;
  const int node = blockIdx.x*4 + wv;
  #pragma unroll
  for(int hd=0; hd<4; hd++){
    U2 hv;
    hv.v = *(const uint2*)(H + (size_t)node*1024 + hd*256 + lane*4);
    float4 lv = *(const float4*)(al + hd*256 + lane*4);
    float4 rv = *(const float4*)(ar + hd*256 + lane*4);
    float x0=b2f(hv.s[0]), x1=b2f(hv.s[1]), x2=b2f(hv.s[2]), x3=b2f(hv.s[3]);
    float sl = x0*lv.x + x1*lv.y + x2*lv.z + x3*lv.w;
    float sr = x0*rv.x + x1*rv.y + x2*rv.z + x3*rv.w;
    #pragma unroll
    for(int o=32;o;o>>=1){ sl += __shfl_xor(sl,o,64); sr += __shfl_xor(sr,o,64); }
    if(lane==0){ el[node*4+hd]=sl; er[node*4+hd]=sr; }
  }
}

// ---------------- CSR build ----------------
__global__ __launch_bounds__(256) void k_hist(const int* __restrict__ dst, int* __restrict__ counts){
  int e = blockIdx.x*256 + threadIdx.x;
  if(e < NE) atomicAdd(&counts[dst[e]], 1);
}

__global__ __launch_bounds__(1024) void k_scan(const int* __restrict__ counts,
                                               int* __restrict__ offsets, int* __restrict__ cursor)
{
  __shared__ int buf[1024];
  const int tid = threadIdx.x;
  const int base = tid*20;          // 1024*20 = 20480 >= 20000
  int loc[20];
  int s = 0;
  #pragma unroll
  for(int j=0;j<20;j++){
    int idx = base+j;
    int v = (idx<NN) ? counts[idx] : 0;
    loc[j] = s; s += v;
  }
  buf[tid] = s;
  __syncthreads();
  for(int off=1; off<1024; off<<=1){
    int t = (tid>=off) ? buf[tid-off] : 0;
    __syncthreads();
    buf[tid] += t;
    __syncthreads();
  }
  int excl = buf[tid] - s;
  #pragma unroll
  for(int j=0;j<20;j++){
    int idx = base+j;
    if(idx<NN){ offsets[idx]=excl+loc[j]; cursor[idx]=excl+loc[j]; }
  }
  if(tid==1023) offsets[NN] = excl + s;
}

__global__ __launch_bounds__(256) void k_scatter(const int* __restrict__ src, const int* __restrict__ dst,
    int* __restrict__ cursor, int* __restrict__ esrc)
{
  int e = blockIdx.x*256 + threadIdx.x;
  if(e < NE){
    int pos = atomicAdd(&cursor[dst[e]], 1);
    esrc[pos] = src[e];
  }
}

// ---------------- GAT aggregate: softmax over in-edges + weighted sum ----------------
__global__ __launch_bounds__(256) void k_agg(
    const int* __restrict__ offsets, const int* __restrict__ esrc,
    const float* __restrict__ el, const float* __restrict__ er,
    const us16* __restrict__ H, const float* __restrict__ gbias,
    us16* __restrict__ rst)
{
  const int node = blockIdx.x;
  const int hd = threadIdx.x>>6, lane = threadIdx.x&63;
  const int beg = offsets[node];
  const int deg = offsets[node+1] - beg;
  const float ern = er[node*4+hd];
  float m = -3.0e38f;
  for(int i=lane; i<deg; i+=64){
    float sc = el[esrc[beg+i]*4+hd] + ern;
    sc = sc>0.f ? sc : 0.2f*sc;
    m = fmaxf(m, sc);
  }
  #pragma unroll
  for(int o=32;o;o>>=1) m = fmaxf(m, __shfl_xor(m,o,64));
  float den = 0.f;
  for(int i=lane; i<deg; i+=64){
    float sc = el[esrc[beg+i]*4+hd] + ern;
    sc = sc>0.f ? sc : 0.2f*sc;
    den += __expf(sc - m);
  }
  #pragma unroll
  for(int o=32;o;o>>=1) den += __shfl_xor(den,o,64);
  const float inv = (deg>0) ? 1.f/den : 0.f;
  float a0=0.f, a1=0.f, a2=0.f, a3=0.f;
  for(int j=0; j<deg; j++){
    int sN = esrc[beg+j];
    float sc = el[sN*4+hd] + ern;
    sc = sc>0.f ? sc : 0.2f*sc;
    float alpha = __expf(sc - m) * inv;
    U2 hv; hv.v = *(const uint2*)(H + (size_t)sN*1024 + hd*256 + lane*4);
    a0 = fmaf(alpha, b2f(hv.s[0]), a0);
    a1 = fmaf(alpha, b2f(hv.s[1]), a1);
    a2 = fmaf(alpha, b2f(hv.s[2]), a2);
    a3 = fmaf(alpha, b2f(hv.s[3]), a3);
  }
  float4 bv = *(const float4*)(gbias + hd*256 + lane*4);
  U2 ov;
  float r0=a0+bv.x; r0 = r0>0.f?r0:0.f; ov.s[0]=f2b(r0);
  float r1=a1+bv.y; r1 = r1>0.f?r1:0.f; ov.s[1]=f2b(r1);
  float r2=a2+bv.z; r2 = r2>0.f?r2:0.f; ov.s[2]=f2b(r2);
  float r3=a3+bv.w; r3 = r3>0.f?r3:0.f; ov.s[3]=f2b(r3);
  *(uint2*)(rst + (size_t)node*1024 + hd*256 + lane*4) = ov.v;
}

// ---------------- bn1 column stats over N ----------------
__global__ __launch_bounds__(256) void k_colstats(const us16* __restrict__ rst,
    float* __restrict__ sum, float* __restrict__ sq)
{
  int f = blockIdx.x*256 + threadIdx.x;     // 0..1023
  int r0 = blockIdx.y*256;
  int r1 = min(r0+256, NN);
  float s=0.f, q=0.f;
  for(int r=r0; r<r1; r++){
    float v = b2f(rst[(size_t)r*1024 + f]);
    s += v; q += v*v;
  }
  atomicAdd(&sum[f], s);
  atomicAdd(&sq[f], q);
}

// ---------------- gated_conv2 (128->32, k=3, x3) + bn2 partial stats ----------------
__global__ __launch_bounds__(256) void k_conv2(
    const us16* __restrict__ rst, const float* __restrict__ ss1,
    const float* __restrict__ w1, const float* __restrict__ b1,
    const float* __restrict__ w2, const float* __restrict__ b2,
    const float* __restrict__ w3, const float* __restrict__ b3,
    us16* __restrict__ y2, float* __restrict__ bn2_sum, float* __restrict__ bn2_sq)
{
  __shared__ us16 xls[8192];     // 8 nodes x 1024 feats (bn1 applied), bf16
  __shared__ float wl[9216];     // ci-tile of 32: [conv][cil*3+k][co]
  __shared__ float redS[32], redQ[32];
  const int tid = threadIdx.x;
  if(tid<32){ redS[tid]=0.f; redQ[tid]=0.f; }
  const size_t gbase = (size_t)blockIdx.x*8192;
  #pragma unroll
  for(int i=0;i<4;i++){
    int e0 = (i*256 + tid)*8;
    U4 in, out;
    in.v = *(const uint4*)(rst + gbase + e0);
    int f0 = e0 & 1023;
    #pragma unroll
    for(int j=0;j<8;j++){
      float a = ss1[2*(f0+j)], b = ss1[2*(f0+j)+1];
      out.s[j] = f2b(fmaf(a, b2f(in.s[j]), b));
    }
    *(uint4*)&xls[e0] = out.v;
  }
  const int nl = tid>>5, co = tid&31;
  float a1[8]={}, a2[8]={}, a3[8]={};
  for(int ct=0; ct<4; ct++){
    __syncthreads();
    for(int idx=tid; idx<3072; idx+=256){
      int co_ = idx/96, r = idx%96, cil = r/3, k = r%3;
      int gidx = co_*384 + (ct*32+cil)*3 + k;
      int l = (cil*3+k)*32 + co_;
      wl[l]        = w1[gidx];
      wl[3072 + l] = w2[gidx];
      wl[6144 + l] = w3[gidx];
    }
    __syncthreads();
    const us16* xrow = &xls[nl*1024 + ct*256];
    for(int ci=0; ci<32; ci++){
      U4 xr; xr.v = *(const uint4*)(xrow + ci*8);
      float xv[10]; xv[0]=0.f; xv[9]=0.f;
      #pragma unroll
      for(int j=0;j<8;j++) xv[j+1] = b2f(xr.s[j]);
      const float* wp = &wl[ci*96 + co];
      float u0=wp[0],    u1=wp[32],      u2=wp[64];
      float v0=wp[3072], v1=wp[3072+32], v2=wp[3072+64];
      float q0=wp[6144], q1=wp[6144+32], q2=wp[6144+64];
      #pragma unroll
      for(int t=0;t<8;t++){
        a1[t]=fmaf(u0,xv[t],fmaf(u1,xv[t+1],fmaf(u2,xv[t+2],a1[t])));
        a2[t]=fmaf(v0,xv[t],fmaf(v1,xv[t+1],fmaf(v2,xv[t+2],a2[t])));
        a3[t]=fmaf(q0,xv[t],fmaf(q1,xv[t+1],fmaf(q2,xv[t+2],a3[t])));
      }
    }
  }
  const float bb1=b1[co], bb2=b2[co], bb3=b3[co];
  float s=0.f, q=0.f;
  U4 out;
  #pragma unroll
  for(int t=0;t<8;t++){
    float c1=a1[t]+bb1, c2=a2[t]+bb2, c3=a3[t]+bb3;
    float sg = 1.f/(1.f+__expf(-c2));
    float v = fmaf(c1, sg, c3);
    v = v>0.f ? v : 0.f;
    s += v; q += v*v;
    out.s[t] = f2b(v);
  }
  *(uint4*)(y2 + (size_t)(blockIdx.x*8+nl)*256 + co*8) = out.v;
  atomicAdd(&redS[co], s); atomicAdd(&redQ[co], q);
  __syncthreads();
  if(tid<32)      atomicAdd(&bn2_sum[tid], redS[tid]);
  else if(tid<64) atomicAdd(&bn2_sq[tid-32], redQ[tid-32]);
}

// ---------------- final: bn2 apply + residual + relu -> FP32 out ----------------
__global__ __launch_bounds__(256) void k_final(const us16* __restrict__ y2, const float* __restrict__ ss,
    const us16* __restrict__ resid, float* __restrict__ out)
{
  size_t base = ((size_t)blockIdx.x*256 + threadIdx.x)*8;
  int ch = (int)((base>>3)&31);
  float a = ss[2*ch], b = ss[2*ch+1];
  U4 yv, rv;
  yv.v = *(const uint4*)(y2+base);
  rv.v = *(const uint4*)(resid+base);
  float4 o0, o1;
  float vv[8];
  #pragma unroll
  for(int j=0;j<8;j++){
    float v = fmaf(a, b2f(yv.s[j]), b) + b2f(rv.s[j]);
    vv[j] = v>0.f ? v : 0.f;
  }
  o0.x=vv[0]; o0.y=vv[1]; o0.z=vv[2]; o0.w=vv[3];
  o1.x=vv[4]; o1.y=vv[5]; o1.z=vv[6]; o1.w=vv[7];
  *(float4*)(out+base)   = o0;
  *(float4*)(out+base+4) = o1;
}

extern "C" void kernel_launch(void* const* d_in, const int* in_sizes, int n_in,
                              void* d_out, int out_size, void* d_ws, size_t ws_size,
                              hipStream_t stream)
{
  const float* X    = (const float*)d_in[0];
  const int*  src   = (const int*)d_in[1];
  const int*  dst   = (const int*)d_in[2];
  const float* rp_w = (const float*)d_in[3];
  const float* rp_b = (const float*)d_in[4];
  const float* g1w1 = (const float*)d_in[5];
  const float* g1b1 = (const float*)d_in[6];
  const float* g1w2 = (const float*)d_in[7];
  const float* g1b2 = (const float*)d_in[8];
  const float* g1w3 = (const float*)d_in[9];
  const float* g1b3 = (const float*)d_in[10];
  const float* bn0g = (const float*)d_in[11];
  const float* bn0b = (const float*)d_in[12];
  const float* gatw = (const float*)d_in[13];
  const float* attnl= (const float*)d_in[14];
  const float* attnr= (const float*)d_in[15];
  const float* gbias= (const float*)d_in[16];
  const float* bn1g = (const float*)d_in[17];
  const float* bn1b = (const float*)d_in[18];
  const float* g2w1 = (const float*)d_in[19];
  const float* g2b1 = (const float*)d_in[20];
  const float* g2w2 = (const float*)d_in[21];
  const float* g2b2 = (const float*)d_in[22];
  const float* g2w3 = (const float*)d_in[23];
  const float* g2b3 = (const float*)d_in[24];
  const float* bn2g = (const float*)d_in[25];
  const float* bn2b = (const float*)d_in[26];
  float* out = (float*)d_out;
  (void)in_sizes; (void)n_in; (void)out_size; (void)ws_size;

  char* w = (char*)d_ws;
  float* bn0_sum = (float*)w;                 // 32
  float* bn0_sq  = bn0_sum + 32;              // 32
  float* bn1_sum = bn0_sum + 64;              // 1024
  float* bn1_sq  = bn1_sum + 1024;            // 1024
  float* bn2_sum = bn1_sq  + 1024;            // 32
  float* bn2_sq  = bn2_sum + 32;              // 32
  int*   counts  = (int*)(bn2_sq + 32);       // 20000  (zeroed region ends here)
  size_t zeroBytes = (size_t)((char*)(counts + NN) - w);   // 88704
  float* ss0     = (float*)(counts + NN);     // 64
  float* ss1     = ss0 + 64;                  // 2048
  float* ss2     = ss1 + 2048;                // 64
  int*   offsets = (int*)(ss2 + 64);          // 20004 (padded for 16B alignment)
  int*   cursor  = offsets + 20004;           // 20000
  int*   esrc    = cursor + NN;               // 320000
  float* el      = (float*)(esrc + NE);       // 80000
  float* er      = el + NN*4;                 // 80000
  us16*  wb      = (us16*)(er + NN*4);        // 262144 (gat_w in bf16)
  us16*  resid   = wb + 262144;               // 5,120,000
  us16*  gc1     = resid + 5120000;           // 5,120,000 (bn0 applied in-place; later reused as y2)
  us16*  h       = gc1   + 5120000;           // 20,480,000
  us16*  rst     = h     + 20480000;          // 20,480,000
  us16*  y2      = gc1;                       // alias: gc1 dead after GEMM

  hipMemsetAsync(d_ws, 0, zeroBytes, stream);
  k_cvtw<<<256, 256, 0, stream>>>(gatw, wb);
  k1_front<<<2500, 256, 0, stream>>>(X, rp_w, rp_b, g1w1, g1b1, g1w2, g1b2, g1w3, g1b3,
                                     resid, gc1, bn0_sum, bn0_sq);
  k_bnfin<<<1, 64, 0, stream>>>(bn0_sum, bn0_sq, bn0g, bn0b, ss0, 32, 1.f/160000.f);
  k_xbn<<<2500, 256, 0, stream>>>(gc1, ss0);
  k_gemm<<<dim3(157, 8), 256, 0, stream>>>(gc1, wb, h);
  k_eler<<<5000, 256, 0, stream>>>(h, attnl, attnr, el, er);
  k_hist<<<1250, 256, 0, stream>>>(dst, counts);
  k_scan<<<1, 1024, 0, stream>>>(counts, offsets, cursor);
  k_scatter<<<1250, 256, 0, stream>>>(src, dst, cursor, esrc);
  k_agg<<<NN, 256, 0, stream>>>(offsets, esrc, el, er, h, gbias, rst);
  k_colstats<<<dim3(4, 79), 256, 0, stream>>>(rst, bn1_sum, bn1_sq);
  k_bnfin<<<4, 256, 0, stream>>>(bn1_sum, bn1_sq, bn1g, bn1b, ss1, 1024, 1.f/20000.f);
  k_conv2<<<2500, 256, 0, stream>>>(rst, ss1, g2w1, g2b1, g2w2, g2b2, g2w3, g2b3,
                                    y2, bn2_sum, bn2_sq);
  k_bnfin<<<1, 64, 0, stream>>>(bn2_sum, bn2_sq, bn2g, bn2b, ss2, 32, 1.f/160000.f);
  k_final<<<2500, 256, 0, stream>>>(y2, ss2, resid, out);
}

// Round 4
// 614.786 us; speedup vs baseline: 1.4427x; 1.4427x over previous
//
#include <hip/hip_runtime.h>
#include <stdint.h>

#define NN 20000
#define NE 320000

typedef unsigned short us16;
typedef __attribute__((ext_vector_type(8))) short short8;
typedef __attribute__((ext_vector_type(4))) float f32x4;

union U4 { uint4 v; us16 s[8]; unsigned u[4]; };
union U2 { uint2 v; us16 s[4]; };

__device__ __forceinline__ float b2f(us16 u){ return __uint_as_float(((unsigned)u)<<16); }
__device__ __forceinline__ us16 f2b(float f){
  unsigned u = __float_as_uint(f);
  u += 0x7fffu + ((u>>16)&1u);
  return (us16)(u>>16);
}

// ---------------- Kernel 1: residual conv(k=1) + gated_conv1 + bn0 partial stats ----------------
__global__ __launch_bounds__(256) void k1_front(
    const float* __restrict__ X,
    const float* __restrict__ rp_w, const float* __restrict__ rp_b,
    const float* __restrict__ w1, const float* __restrict__ b1,
    const float* __restrict__ w2, const float* __restrict__ b2,
    const float* __restrict__ w3, const float* __restrict__ b3,
    us16* __restrict__ resid, us16* __restrict__ gc1,
    float* __restrict__ bn0_sum, float* __restrict__ bn0_sq)
{
  __shared__ float xs[2048];          // 8 nodes x 32ch x 8t, fp32
  __shared__ float wl[9216];          // [conv][ci*3+k][co]
  __shared__ float rpl[1024];         // [ci][co]
  __shared__ float redS[32], redQ[32];
  const int tid = threadIdx.x;
  // conflict-free staging: consecutive tid -> consecutive LDS addr (banks)
  for(int l=tid; l<3072; l+=256){
    int gidx = (l&31)*96 + (l>>5);    // w[co][ci*3+k]
    wl[l]        = w1[gidx];
    wl[3072 + l] = w2[gidx];
    wl[6144 + l] = w3[gidx];
  }
  for(int l=tid; l<1024; l+=256)
    rpl[l] = rp_w[(l&31)*32 + (l>>5)];   // rpl[ci*32+co] = rp_w[co*32+ci]
  if(tid<32){ redS[tid]=0.f; redQ[tid]=0.f; }
  {
    const float4* Xv = (const float4*)(X + (size_t)blockIdx.x*2048);
    *(float4*)&xs[tid*8]   = Xv[tid*2];
    *(float4*)&xs[tid*8+4] = Xv[tid*2+1];
  }
  __syncthreads();
  const int nl = tid>>5, co = tid&31;
  const float* xrow = &xs[nl*256];
  float aR[8]={}, a1[8]={}, a2[8]={}, a3[8]={};
  for(int ci=0; ci<32; ci++){
    float xv[10];
    xv[0]=0.f; xv[9]=0.f;
    #pragma unroll
    for(int t=0;t<8;t++) xv[t+1] = xrow[ci*8+t];
    const float rw = rpl[ci*32+co];
    const float* wp = &wl[ci*96 + co];
    float u0=wp[0],    u1=wp[32],      u2=wp[64];
    float v0=wp[3072], v1=wp[3072+32], v2=wp[3072+64];
    float q0=wp[6144], q1=wp[6144+32], q2=wp[6144+64];
    #pragma unroll
    for(int t=0;t<8;t++){
      aR[t]=fmaf(rw,xv[t+1],aR[t]);
      a1[t]=fmaf(u0,xv[t],fmaf(u1,xv[t+1],fmaf(u2,xv[t+2],a1[t])));
      a2[t]=fmaf(v0,xv[t],fmaf(v1,xv[t+1],fmaf(v2,xv[t+2],a2[t])));
      a3[t]=fmaf(q0,xv[t],fmaf(q1,xv[t+1],fmaf(q2,xv[t+2],a3[t])));
    }
  }
  const float bR=rp_b[co], bb1=b1[co], bb2=b2[co], bb3=b3[co];
  U4 og, orr;
  float s=0.f, q=0.f;
  #pragma unroll
  for(int t=0;t<8;t++){
    float c1=a1[t]+bb1, c2=a2[t]+bb2, c3=a3[t]+bb3;
    float sg = 1.f/(1.f+__expf(-c2));
    float v = fmaf(c1, sg, c3);
    v = v>0.f ? v : 0.f;
    s += v; q += v*v;
    og.s[t]  = f2b(v);
    orr.s[t] = f2b(aR[t]+bR);
  }
  size_t base = (size_t)blockIdx.x*2048 + nl*256 + co*8;
  *(uint4*)(gc1+base)   = og.v;
  *(uint4*)(resid+base) = orr.v;
  atomicAdd(&redS[co], s); atomicAdd(&redQ[co], q);
  __syncthreads();
  if(tid<32)       atomicAdd(&bn0_sum[tid], redS[tid]);
  else if(tid<64)  atomicAdd(&bn0_sq[tid-32], redQ[tid-32]);
}

// ---------------- BN finalize ----------------
__global__ void k_bnfin(const float* __restrict__ sum, const float* __restrict__ sq,
                        const float* __restrict__ g, const float* __restrict__ b,
                        float* __restrict__ ss, int nch, float inv)
{
  int i = blockIdx.x*blockDim.x + threadIdx.x;
  if(i>=nch) return;
  float m = sum[i]*inv;
  float v = sq[i]*inv - m*m;
  float a = g[i] * rsqrtf(v + 1e-5f);
  ss[2*i]   = a;
  ss[2*i+1] = b[i] - m*a;
}

// ---------------- apply bn0 in-place on gc1 ----------------
__global__ __launch_bounds__(256) void k_xbn(us16* __restrict__ gc1, const float* __restrict__ ss)
{
  size_t base = ((size_t)blockIdx.x*256 + threadIdx.x)*8;
  U4 in, out;
  in.v = *(const uint4*)(gc1+base);
  int ch = (int)((base>>3)&31);
  float a = ss[2*ch], b = ss[2*ch+1];
  #pragma unroll
  for(int j=0;j<8;j++) out.s[j] = f2b(fmaf(a, b2f(in.s[j]), b));
  *(uint4*)(gc1+base) = out.v;
}

// ---------------- convert gat_w fp32 -> bf16 ----------------
__global__ __launch_bounds__(256) void k_cvtw(const float* __restrict__ W, us16* __restrict__ Wb)
{
  int i = blockIdx.x*256 + threadIdx.x;
  float4 v = *(const float4*)(W + (size_t)i*4);
  U2 o;
  o.s[0]=f2b(v.x); o.s[1]=f2b(v.y); o.s[2]=f2b(v.z); o.s[3]=f2b(v.w);
  *(uint2*)(Wb + (size_t)i*4) = o.v;
}

// ---------------- GAT fc GEMM: h = A[20000,256] @ Wb[1024,256]^T ----------------
__global__ __launch_bounds__(256) void k_gemm(const us16* __restrict__ A, const us16* __restrict__ B,
                                              us16* __restrict__ H)
{
  __shared__ us16 As[128*72];
  __shared__ us16 Bs[128*72];
  const int tid = threadIdx.x;
  const int row0 = blockIdx.x*128, col0 = blockIdx.y*128;
  const int lane = tid&63, wv = tid>>6;
  const int wm = wv&1, wn = wv>>1;
  const int mrow = lane&15, kg = (lane>>4)*8;
  f32x4 acc[4][4] = {};
  for(int k0=0; k0<256; k0+=64){
    #pragma unroll
    for(int i=0;i<4;i++){
      int chunk = i*256 + tid;
      int row = chunk>>3, cc = chunk&7;
      int g = row0 + row;
      uint4 av; av.x=0;av.y=0;av.z=0;av.w=0;
      if(g < NN) av = *(const uint4*)(A + (size_t)g*256 + k0 + cc*8);
      *(uint4*)&As[row*72 + cc*8] = av;
      *(uint4*)&Bs[row*72 + cc*8] = *(const uint4*)(B + (size_t)(col0+row)*256 + k0 + cc*8);
    }
    __syncthreads();
    #pragma unroll
    for(int kk=0; kk<64; kk+=32){
      short8 af[4], bfr[4];
      #pragma unroll
      for(int i=0;i<4;i++) af[i]  = *(const short8*)&As[(wm*64 + i*16 + mrow)*72 + kk + kg];
      #pragma unroll
      for(int j=0;j<4;j++) bfr[j] = *(const short8*)&Bs[(wn*64 + j*16 + mrow)*72 + kk + kg];
      #pragma unroll
      for(int i=0;i<4;i++){
        #pragma unroll
        for(int j=0;j<4;j++)
          acc[i][j] = __builtin_amdgcn_mfma_f32_16x16x32_bf16(af[i], bfr[j], acc[i][j], 0, 0, 0);
      }
    }
    __syncthreads();
  }
  #pragma unroll
  for(int i=0;i<4;i++){
    #pragma unroll
    for(int j=0;j<4;j++){
      #pragma unroll
      for(int r=0;r<4;r++){
        int g = row0 + wm*64 + i*16 + (lane>>4)*4 + r;
        if(g < NN)
          H[(size_t)g*1024 + col0 + wn*64 + j*16 + (lane&15)] = f2b(acc[i][j][r]);
      }
    }
  }
}

// ---------------- el/er ----------------
__global__ __launch_bounds__(256) void k_eler(const us16* __restrict__ H,
    const float* __restrict__ al, const float* __restrict__ ar,
    float* __restrict__ el, float* __restrict__ er)
{
  const int wv = threadIdx.x>>6, lane = threadIdx.x&63;
  const int node = blockIdx.x*4 + wv;
  #pragma unroll
  for(int hd=0; hd<4; hd++){
    U2 hv;
    hv.v = *(const uint2*)(H + (size_t)node*1024 + hd*256 + lane*4);
    float4 lv = *(const float4*)(al + hd*256 + lane*4);
    float4 rv = *(const float4*)(ar + hd*256 + lane*4);
    float x0=b2f(hv.s[0]), x1=b2f(hv.s[1]), x2=b2f(hv.s[2]), x3=b2f(hv.s[3]);
    float sl = x0*lv.x + x1*lv.y + x2*lv.z + x3*lv.w;
    float sr = x0*rv.x + x1*rv.y + x2*rv.z + x3*rv.w;
    #pragma unroll
    for(int o=32;o;o>>=1){ sl += __shfl_xor(sl,o,64); sr += __shfl_xor(sr,o,64); }
    if(lane==0){ el[node*4+hd]=sl; er[node*4+hd]=sr; }
  }
}

// ---------------- CSR build ----------------
__global__ __launch_bounds__(256) void k_hist(const int* __restrict__ dst, int* __restrict__ counts){
  int e = blockIdx.x*256 + threadIdx.x;
  if(e < NE) atomicAdd(&counts[dst[e]], 1);
}

__global__ __launch_bounds__(1024) void k_scan(const int* __restrict__ counts,
                                               int* __restrict__ offsets, int* __restrict__ cursor)
{
  __shared__ int buf[1024];
  const int tid = threadIdx.x;
  const int base = tid*20;
  int loc[20];
  int s = 0;
  #pragma unroll
  for(int j=0;j<20;j++){
    int idx = base+j;
    int v = (idx<NN) ? counts[idx] : 0;
    loc[j] = s; s += v;
  }
  buf[tid] = s;
  __syncthreads();
  for(int off=1; off<1024; off<<=1){
    int t = (tid>=off) ? buf[tid-off] : 0;
    __syncthreads();
    buf[tid] += t;
    __syncthreads();
  }
  int excl = buf[tid] - s;
  #pragma unroll
  for(int j=0;j<20;j++){
    int idx = base+j;
    if(idx<NN){ offsets[idx]=excl+loc[j]; cursor[idx]=excl+loc[j]; }
  }
  if(tid==1023) offsets[NN] = excl + s;
}

__global__ __launch_bounds__(256) void k_scatter(const int* __restrict__ src, const int* __restrict__ dst,
    int* __restrict__ cursor, int* __restrict__ esrc)
{
  int e = blockIdx.x*256 + threadIdx.x;
  if(e < NE){
    int pos = atomicAdd(&cursor[dst[e]], 1);
    esrc[pos] = src[e];
  }
}

// ---------------- GAT aggregate ----------------
__global__ __launch_bounds__(256) void k_agg(
    const int* __restrict__ offsets, const int* __restrict__ esrc,
    const float* __restrict__ el, const float* __restrict__ er,
    const us16* __restrict__ H, const float* __restrict__ gbias,
    us16* __restrict__ rst)
{
  const int node = blockIdx.x;
  const int hd = threadIdx.x>>6, lane = threadIdx.x&63;
  const int beg = offsets[node];
  const int deg = offsets[node+1] - beg;
  const float ern = er[node*4+hd];
  float m = -3.0e38f;
  for(int i=lane; i<deg; i+=64){
    float sc = el[esrc[beg+i]*4+hd] + ern;
    sc = sc>0.f ? sc : 0.2f*sc;
    m = fmaxf(m, sc);
  }
  #pragma unroll
  for(int o=32;o;o>>=1) m = fmaxf(m, __shfl_xor(m,o,64));
  float den = 0.f;
  for(int i=lane; i<deg; i+=64){
    float sc = el[esrc[beg+i]*4+hd] + ern;
    sc = sc>0.f ? sc : 0.2f*sc;
    den += __expf(sc - m);
  }
  #pragma unroll
  for(int o=32;o;o>>=1) den += __shfl_xor(den,o,64);
  const float inv = (deg>0) ? 1.f/den : 0.f;
  float a0=0.f, a1=0.f, a2=0.f, a3=0.f;
  for(int j=0; j<deg; j++){
    int sN = esrc[beg+j];
    float sc = el[sN*4+hd] + ern;
    sc = sc>0.f ? sc : 0.2f*sc;
    float alpha = __expf(sc - m) * inv;
    U2 hv; hv.v = *(const uint2*)(H + (size_t)sN*1024 + hd*256 + lane*4);
    a0 = fmaf(alpha, b2f(hv.s[0]), a0);
    a1 = fmaf(alpha, b2f(hv.s[1]), a1);
    a2 = fmaf(alpha, b2f(hv.s[2]), a2);
    a3 = fmaf(alpha, b2f(hv.s[3]), a3);
  }
  float4 bv = *(const float4*)(gbias + hd*256 + lane*4);
  U2 ov;
  float r0=a0+bv.x; r0 = r0>0.f?r0:0.f; ov.s[0]=f2b(r0);
  float r1=a1+bv.y; r1 = r1>0.f?r1:0.f; ov.s[1]=f2b(r1);
  float r2=a2+bv.z; r2 = r2>0.f?r2:0.f; ov.s[2]=f2b(r2);
  float r3=a3+bv.w; r3 = r3>0.f?r3:0.f; ov.s[3]=f2b(r3);
  *(uint2*)(rst + (size_t)node*1024 + hd*256 + lane*4) = ov.v;
}

// ---------------- bn1 column stats ----------------
__global__ __launch_bounds__(256) void k_colstats(const us16* __restrict__ rst,
    float* __restrict__ sum, float* __restrict__ sq)
{
  int f = blockIdx.x*256 + threadIdx.x;
  int r0 = blockIdx.y*256;
  int r1 = min(r0+256, NN);
  float s=0.f, q=0.f;
  for(int r=r0; r<r1; r++){
    float v = b2f(rst[(size_t)r*1024 + f]);
    s += v; q += v*v;
  }
  atomicAdd(&sum[f], s);
  atomicAdd(&sq[f], q);
}

// ---------------- prep conv2 weights: Wt[s][co3][ci] bf16 (co3 = conv*32+co) ----------------
__global__ __launch_bounds__(256) void k_wprep(
    const float* __restrict__ w1, const float* __restrict__ w2, const float* __restrict__ w3,
    us16* __restrict__ Wt)
{
  int i = blockIdx.x*256 + threadIdx.x;   // 36864 total
  int s = i/12288, rem = i%12288;
  int co3 = rem>>7, ci = rem&127;
  const float* w = (co3<32) ? w1 : (co3<64) ? w2 : w3;
  int co = co3&31;
  Wt[i] = f2b(w[co*384 + ci*3 + s]);
}

// ---------------- bn1 apply + transpose: rst[n, c*8+t] -> Xc[n, t, c] bf16 ----------------
__global__ __launch_bounds__(256) void k_xc(const us16* __restrict__ rst, const float* __restrict__ ss1,
                                            us16* __restrict__ Xc)
{
  __shared__ us16 xt[8*1040];      // [n][t*130 + c] : stride 130 -> 2-way aliasing only
  const int tid = threadIdx.x;
  const size_t gbase = (size_t)blockIdx.x*8192;
  #pragma unroll
  for(int i=0;i<4;i++){
    int chunk = i*256 + tid;              // 0..1023
    int n = chunk>>7, c = chunk&127;
    U4 in; in.v = *(const uint4*)(rst + gbase + chunk*8);
    int f0 = c*8;
    #pragma unroll
    for(int t=0;t<8;t++){
      float a = ss1[2*(f0+t)], b = ss1[2*(f0+t)+1];
      xt[n*1040 + t*130 + c] = f2b(fmaf(a, b2f(in.s[t]), b));
    }
  }
  __syncthreads();
  #pragma unroll
  for(int i=0;i<4;i++){
    int chunk = i*256 + tid;
    int o0 = chunk*8;
    int n = o0>>10, rem = o0&1023;
    int t = rem>>7, c0 = rem&127;
    U4 out;
    #pragma unroll
    for(int m2=0;m2<4;m2++)
      out.u[m2] = *(const unsigned*)&xt[n*1040 + t*130 + c0 + m2*2];
    *(uint4*)(Xc + gbase + o0) = out.v;
  }
}

// ---------------- conv2 as MFMA GEMM: [160000 rows(n,t)] x [96 co3] , K=3 shifts x 128 ci ----------------
// epilogue: gate + relu + bn2 partial stats; output y2 in [n][co][t] layout
__global__ __launch_bounds__(256) void k_gemm2(
    const us16* __restrict__ Xc, const us16* __restrict__ Wt,
    const float* __restrict__ b1, const float* __restrict__ b2, const float* __restrict__ b3,
    us16* __restrict__ y2, float* __restrict__ bn2_sum, float* __restrict__ bn2_sq)
{
  __shared__ float smemF[12800];                 // 51200 B union
  us16* As = (us16*)smemF;                       // [128][72]
  us16* Bs = As + 9216;                          // [96][72]
  float* Cs = smemF;                             // [128][100] epilogue
  __shared__ float redS[32], redQ[32];
  const int tid = threadIdx.x;
  if(tid<32){ redS[tid]=0.f; redQ[tid]=0.f; }
  const int row0 = blockIdx.x*128;
  const int lane = tid&63, wv = tid>>6;
  const int wm = wv&1, wn = wv>>1;
  const int mrow = lane&15, kg = (lane>>4)*8;
  f32x4 acc[4][3] = {};
  for(int rd=0; rd<6; rd++){
    const int s = rd>>1, kc = rd&1;
    #pragma unroll
    for(int i=0;i<4;i++){
      int chunk = i*256 + tid;
      int row = chunk>>3, cc = chunk&7;
      int grow = row0 + row;
      int tsrc = (grow&7) + s - 1;
      uint4 av; av.x=0;av.y=0;av.z=0;av.w=0;
      if((unsigned)tsrc < 8u)
        av = *(const uint4*)(Xc + (size_t)(grow + s - 1)*128 + kc*64 + cc*8);
      *(uint4*)&As[row*72 + cc*8] = av;
    }
    #pragma unroll
    for(int i=0;i<3;i++){
      int chunk = i*256 + tid;              // 0..767
      int brow = chunk>>3, cc = chunk&7;
      *(uint4*)&Bs[brow*72 + cc*8] =
        *(const uint4*)(Wt + s*12288 + brow*128 + kc*64 + cc*8);
    }
    __syncthreads();
    #pragma unroll
    for(int kk=0; kk<64; kk+=32){
      short8 af[4], bfr[3];
      #pragma unroll
      for(int i=0;i<4;i++) af[i]  = *(const short8*)&As[(wm*64 + i*16 + mrow)*72 + kk + kg];
      #pragma unroll
      for(int j=0;j<3;j++) bfr[j] = *(const short8*)&Bs[(wn*48 + j*16 + mrow)*72 + kk + kg];
      #pragma unroll
      for(int i=0;i<4;i++){
        #pragma unroll
        for(int j=0;j<3;j++)
          acc[i][j] = __builtin_amdgcn_mfma_f32_16x16x32_bf16(af[i], bfr[j], acc[i][j], 0, 0, 0);
      }
    }
    __syncthreads();
  }
  // dump acc to LDS (C-layout: col=lane&15, row=(lane>>4)*4+r); 100-col pad -> 2-way only
  #pragma unroll
  for(int i=0;i<4;i++){
    #pragma unroll
    for(int j=0;j<3;j++){
      #pragma unroll
      for(int r=0;r<4;r++)
        Cs[(wm*64 + i*16 + (lane>>4)*4 + r)*100 + wn*48 + j*16 + (lane&15)] = acc[i][j][r];
    }
  }
  __syncthreads();
  // epilogue: thread (co=tid&31, rg=tid>>5) handles 16 rows = 2 nodes
  const int co = tid&31, rg = tid>>5;
  const float bb1=b1[co], bb2=b2[co], bb3=b3[co];
  float s=0.f, q=0.f;
  #pragma unroll
  for(int half=0; half<2; half++){
    U4 ov;
    #pragma unroll
    for(int t=0;t<8;t++){
      int r = rg*16 + half*8 + t;
      float c1 = Cs[r*100 + co]      + bb1;
      float c2 = Cs[r*100 + co + 32] + bb2;
      float c3 = Cs[r*100 + co + 64] + bb3;
      float sg = 1.f/(1.f+__expf(-c2));
      float v = fmaf(c1, sg, c3);
      v = v>0.f ? v : 0.f;
      s += v; q += v*v;
      ov.s[t] = f2b(v);
    }
    int node = (row0>>3) + rg*2 + half;
    *(uint4*)(y2 + (size_t)node*256 + co*8) = ov.v;
  }
  atomicAdd(&redS[co], s); atomicAdd(&redQ[co], q);
  __syncthreads();
  if(tid<32)      atomicAdd(&bn2_sum[tid], redS[tid]);
  else if(tid<64) atomicAdd(&bn2_sq[tid-32], redQ[tid-32]);
}

// ---------------- final: bn2 apply + residual + relu -> FP32 out ----------------
__global__ __launch_bounds__(256) void k_final(const us16* __restrict__ y2, const float* __restrict__ ss,
    const us16* __restrict__ resid, float* __restrict__ out)
{
  size_t base = ((size_t)blockIdx.x*256 + threadIdx.x)*8;
  int ch = (int)((base>>3)&31);
  float a = ss[2*ch], b = ss[2*ch+1];
  U4 yv, rv;
  yv.v = *(const uint4*)(y2+base);
  rv.v = *(const uint4*)(resid+base);
  float4 o0, o1;
  float vv[8];
  #pragma unroll
  for(int j=0;j<8;j++){
    float v = fmaf(a, b2f(yv.s[j]), b) + b2f(rv.s[j]);
    vv[j] = v>0.f ? v : 0.f;
  }
  o0.x=vv[0]; o0.y=vv[1]; o0.z=vv[2]; o0.w=vv[3];
  o1.x=vv[4]; o1.y=vv[5]; o1.z=vv[6]; o1.w=vv[7];
  *(float4*)(out+base)   = o0;
  *(float4*)(out+base+4) = o1;
}

extern "C" void kernel_launch(void* const* d_in, const int* in_sizes, int n_in,
                              void* d_out, int out_size, void* d_ws, size_t ws_size,
                              hipStream_t stream)
{
  const float* X    = (const float*)d_in[0];
  const int*  src   = (const int*)d_in[1];
  const int*  dst   = (const int*)d_in[2];
  const float* rp_w = (const float*)d_in[3];
  const float* rp_b = (const float*)d_in[4];
  const float* g1w1 = (const float*)d_in[5];
  const float* g1b1 = (const float*)d_in[6];
  const float* g1w2 = (const float*)d_in[7];
  const float* g1b2 = (const float*)d_in[8];
  const float* g1w3 = (const float*)d_in[9];
  const float* g1b3 = (const float*)d_in[10];
  const float* bn0g = (const float*)d_in[11];
  const float* bn0b = (const float*)d_in[12];
  const float* gatw = (const float*)d_in[13];
  const float* attnl= (const float*)d_in[14];
  const float* attnr= (const float*)d_in[15];
  const float* gbias= (const float*)d_in[16];
  const float* bn1g = (const float*)d_in[17];
  const float* bn1b = (const float*)d_in[18];
  const float* g2w1 = (const float*)d_in[19];
  const float* g2b1 = (const float*)d_in[20];
  const float* g2w2 = (const float*)d_in[21];
  const float* g2b2 = (const float*)d_in[22];
  const float* g2w3 = (const float*)d_in[23];
  const float* g2b3 = (const float*)d_in[24];
  const float* bn2g = (const float*)d_in[25];
  const float* bn2b = (const float*)d_in[26];
  float* out = (float*)d_out;
  (void)in_sizes; (void)n_in; (void)out_size; (void)ws_size;

  char* w = (char*)d_ws;
  float* bn0_sum = (float*)w;                 // 32
  float* bn0_sq  = bn0_sum + 32;              // 32
  float* bn1_sum = bn0_sum + 64;              // 1024
  float* bn1_sq  = bn1_sum + 1024;            // 1024
  float* bn2_sum = bn1_sq  + 1024;            // 32
  float* bn2_sq  = bn2_sum + 32;              // 32
  int*   counts  = (int*)(bn2_sq + 32);       // 20000  (zeroed region ends here)
  size_t zeroBytes = (size_t)((char*)(counts + NN) - w);
  float* ss0     = (float*)(counts + NN);     // 64
  float* ss1     = ss0 + 64;                  // 2048
  float* ss2     = ss1 + 2048;                // 64
  int*   offsets = (int*)(ss2 + 64);          // 20004
  int*   cursor  = offsets + 20004;           // 20000
  int*   esrc    = cursor + NN;               // 320000
  float* el      = (float*)(esrc + NE);       // 80000
  float* er      = el + NN*4;                 // 80000
  us16*  wb      = (us16*)(er + NN*4);        // 262144 (gat_w bf16)
  us16*  resid   = wb + 262144;               // 5,120,000
  us16*  gc1     = resid + 5120000;           // 5,120,000
  us16*  h       = gc1   + 5120000;           // 20,480,000
  us16*  rst     = h     + 20480000;          // 20,480,000
  us16*  Wt      = rst   + 20480000;          // 36,864  (conv2 weights bf16)
  us16*  Xc      = h;                         // alias: h dead after k_agg
  us16*  y2      = gc1;                       // alias: gc1 dead after k_gemm

  hipMemsetAsync(d_ws, 0, zeroBytes, stream);
  k_cvtw<<<256, 256, 0, stream>>>(gatw, wb);
  k_wprep<<<144, 256, 0, stream>>>(g2w1, g2w2, g2w3, Wt);
  k1_front<<<2500, 256, 0, stream>>>(X, rp_w, rp_b, g1w1, g1b1, g1w2, g1b2, g1w3, g1b3,
                                     resid, gc1, bn0_sum, bn0_sq);
  k_bnfin<<<1, 64, 0, stream>>>(bn0_sum, bn0_sq, bn0g, bn0b, ss0, 32, 1.f/160000.f);
  k_xbn<<<2500, 256, 0, stream>>>(gc1, ss0);
  k_gemm<<<dim3(157, 8), 256, 0, stream>>>(gc1, wb, h);
  k_eler<<<5000, 256, 0, stream>>>(h, attnl, attnr, el, er);
  k_hist<<<1250, 256, 0, stream>>>(dst, counts);
  k_scan<<<1, 1024, 0, stream>>>(counts, offsets, cursor);
  k_scatter<<<1250, 256, 0, stream>>>(src, dst, cursor, esrc);
  k_agg<<<NN, 256, 0, stream>>>(offsets, esrc, el, er, h, gbias, rst);
  k_colstats<<<dim3(4, 79), 256, 0, stream>>>(rst, bn1_sum, bn1_sq);
  k_bnfin<<<4, 256, 0, stream>>>(bn1_sum, bn1_sq, bn1g, bn1b, ss1, 1024, 1.f/20000.f);
  k_xc<<<2500, 256, 0, stream>>>(rst, ss1, Xc);
  k_gemm2<<<1250, 256, 0, stream>>>(Xc, Wt, g2b1, g2b2, g2b3, y2, bn2_sum, bn2_sq);
  k_bnfin<<<1, 64, 0, stream>>>(bn2_sum, bn2_sq, bn2g, bn2b, ss2, 32, 1.f/160000.f);
  k_final<<<2500, 256, 0, stream>>>(y2, ss2, resid, out);
}

// Round 5
// 600.908 us; speedup vs baseline: 1.4761x; 1.0231x over previous
//
#include <hip/hip_runtime.h>
#include <stdint.h>

#define NN 20000
#define NE 320000

typedef unsigned short us16;
typedef __attribute__((ext_vector_type(8))) short short8;
typedef __attribute__((ext_vector_type(4))) float f32x4;

union U4 { uint4 v; us16 s[8]; unsigned u[4]; };
union U2 { uint2 v; us16 s[4]; };

__device__ __forceinline__ float b2f(us16 u){ return __uint_as_float(((unsigned)u)<<16); }
__device__ __forceinline__ us16 f2b(float f){
  unsigned u = __float_as_uint(f);
  u += 0x7fffu + ((u>>16)&1u);
  return (us16)(u>>16);
}

// ---------------- Kernel 1: residual conv(k=1) + gated_conv1 + bn0 partial stats ----------------
__global__ __launch_bounds__(256) void k1_front(
    const float* __restrict__ X,
    const float* __restrict__ rp_w, const float* __restrict__ rp_b,
    const float* __restrict__ w1, const float* __restrict__ b1,
    const float* __restrict__ w2, const float* __restrict__ b2,
    const float* __restrict__ w3, const float* __restrict__ b3,
    us16* __restrict__ resid, us16* __restrict__ gc1,
    float* __restrict__ bn0_sum, float* __restrict__ bn0_sq)
{
  __shared__ float xs[2048];
  __shared__ float wl[9216];
  __shared__ float rpl[1024];
  __shared__ float redS[32], redQ[32];
  const int tid = threadIdx.x;
  for(int l=tid; l<3072; l+=256){
    int gidx = (l&31)*96 + (l>>5);
    wl[l]        = w1[gidx];
    wl[3072 + l] = w2[gidx];
    wl[6144 + l] = w3[gidx];
  }
  for(int l=tid; l<1024; l+=256)
    rpl[l] = rp_w[(l&31)*32 + (l>>5)];
  if(tid<32){ redS[tid]=0.f; redQ[tid]=0.f; }
  {
    const float4* Xv = (const float4*)(X + (size_t)blockIdx.x*2048);
    *(float4*)&xs[tid*8]   = Xv[tid*2];
    *(float4*)&xs[tid*8+4] = Xv[tid*2+1];
  }
  __syncthreads();
  const int nl = tid>>5, co = tid&31;
  const float* xrow = &xs[nl*256];
  float aR[8]={}, a1[8]={}, a2[8]={}, a3[8]={};
  for(int ci=0; ci<32; ci++){
    float xv[10];
    xv[0]=0.f; xv[9]=0.f;
    #pragma unroll
    for(int t=0;t<8;t++) xv[t+1] = xrow[ci*8+t];
    const float rw = rpl[ci*32+co];
    const float* wp = &wl[ci*96 + co];
    float u0=wp[0],    u1=wp[32],      u2=wp[64];
    float v0=wp[3072], v1=wp[3072+32], v2=wp[3072+64];
    float q0=wp[6144], q1=wp[6144+32], q2=wp[6144+64];
    #pragma unroll
    for(int t=0;t<8;t++){
      aR[t]=fmaf(rw,xv[t+1],aR[t]);
      a1[t]=fmaf(u0,xv[t],fmaf(u1,xv[t+1],fmaf(u2,xv[t+2],a1[t])));
      a2[t]=fmaf(v0,xv[t],fmaf(v1,xv[t+1],fmaf(v2,xv[t+2],a2[t])));
      a3[t]=fmaf(q0,xv[t],fmaf(q1,xv[t+1],fmaf(q2,xv[t+2],a3[t])));
    }
  }
  const float bR=rp_b[co], bb1=b1[co], bb2=b2[co], bb3=b3[co];
  U4 og, orr;
  float s=0.f, q=0.f;
  #pragma unroll
  for(int t=0;t<8;t++){
    float c1=a1[t]+bb1, c2=a2[t]+bb2, c3=a3[t]+bb3;
    float sg = 1.f/(1.f+__expf(-c2));
    float v = fmaf(c1, sg, c3);
    v = v>0.f ? v : 0.f;
    s += v; q += v*v;
    og.s[t]  = f2b(v);
    orr.s[t] = f2b(aR[t]+bR);
  }
  size_t base = (size_t)blockIdx.x*2048 + nl*256 + co*8;
  *(uint4*)(gc1+base)   = og.v;
  *(uint4*)(resid+base) = orr.v;
  atomicAdd(&redS[co], s); atomicAdd(&redQ[co], q);
  __syncthreads();
  if(tid<32)       atomicAdd(&bn0_sum[tid], redS[tid]);
  else if(tid<64)  atomicAdd(&bn0_sq[tid-32], redQ[tid-32]);
}

// ---------------- BN finalize ----------------
__global__ void k_bnfin(const float* __restrict__ sum, const float* __restrict__ sq,
                        const float* __restrict__ g, const float* __restrict__ b,
                        float* __restrict__ ss, int nch, float inv)
{
  int i = blockIdx.x*blockDim.x + threadIdx.x;
  if(i>=nch) return;
  float m = sum[i]*inv;
  float v = sq[i]*inv - m*m;
  float a = g[i] * rsqrtf(v + 1e-5f);
  ss[2*i]   = a;
  ss[2*i+1] = b[i] - m*a;
}

// ---------------- apply bn0 in-place on gc1 ----------------
__global__ __launch_bounds__(256) void k_xbn(us16* __restrict__ gc1, const float* __restrict__ ss)
{
  size_t base = ((size_t)blockIdx.x*256 + threadIdx.x)*8;
  U4 in, out;
  in.v = *(const uint4*)(gc1+base);
  int ch = (int)((base>>3)&31);
  float a = ss[2*ch], b = ss[2*ch+1];
  #pragma unroll
  for(int j=0;j<8;j++) out.s[j] = f2b(fmaf(a, b2f(in.s[j]), b));
  *(uint4*)(gc1+base) = out.v;
}

// ---------------- merged misc: gat_w cvt (256 blk) + conv2 wprep (144 blk) + hist (1250 blk) ----------------
__global__ __launch_bounds__(256) void k_misc(
    const float* __restrict__ gatw, us16* __restrict__ Wb,
    const float* __restrict__ w1, const float* __restrict__ w2, const float* __restrict__ w3,
    us16* __restrict__ Wt,
    const int* __restrict__ dst, int* __restrict__ counts)
{
  const int b = blockIdx.x, tid = threadIdx.x;
  if(b < 256){
    int i = b*256 + tid;
    float4 v = *(const float4*)(gatw + (size_t)i*4);
    U2 o;
    o.s[0]=f2b(v.x); o.s[1]=f2b(v.y); o.s[2]=f2b(v.z); o.s[3]=f2b(v.w);
    *(uint2*)(Wb + (size_t)i*4) = o.v;
  } else if(b < 400){
    int i = (b-256)*256 + tid;       // 36864 total
    int s = i/12288, rem = i%12288;
    int co3 = rem>>7, ci = rem&127;
    const float* w = (co3<32) ? w1 : (co3<64) ? w2 : w3;
    Wt[i] = f2b(w[(co3&31)*384 + ci*3 + s]);
  } else {
    int e = (b-400)*256 + tid;
    if(e < NE) atomicAdd(&counts[dst[e]], 1);
  }
}

// ---------------- GAT fc GEMM: h = A[20000,256] @ Wb[1024,256]^T ----------------
__global__ __launch_bounds__(256) void k_gemm(const us16* __restrict__ A, const us16* __restrict__ B,
                                              us16* __restrict__ H)
{
  __shared__ us16 As[128*72];
  __shared__ us16 Bs[128*72];
  const int tid = threadIdx.x;
  const int row0 = blockIdx.x*128, col0 = blockIdx.y*128;
  const int lane = tid&63, wv = tid>>6;
  const int wm = wv&1, wn = wv>>1;
  const int mrow = lane&15, kg = (lane>>4)*8;
  f32x4 acc[4][4] = {};
  for(int k0=0; k0<256; k0+=64){
    #pragma unroll
    for(int i=0;i<4;i++){
      int chunk = i*256 + tid;
      int row = chunk>>3, cc = chunk&7;
      int g = row0 + row;
      uint4 av; av.x=0;av.y=0;av.z=0;av.w=0;
      if(g < NN) av = *(const uint4*)(A + (size_t)g*256 + k0 + cc*8);
      *(uint4*)&As[row*72 + cc*8] = av;
      *(uint4*)&Bs[row*72 + cc*8] = *(const uint4*)(B + (size_t)(col0+row)*256 + k0 + cc*8);
    }
    __syncthreads();
    #pragma unroll
    for(int kk=0; kk<64; kk+=32){
      short8 af[4], bfr[4];
      #pragma unroll
      for(int i=0;i<4;i++) af[i]  = *(const short8*)&As[(wm*64 + i*16 + mrow)*72 + kk + kg];
      #pragma unroll
      for(int j=0;j<4;j++) bfr[j] = *(const short8*)&Bs[(wn*64 + j*16 + mrow)*72 + kk + kg];
      #pragma unroll
      for(int i=0;i<4;i++){
        #pragma unroll
        for(int j=0;j<4;j++)
          acc[i][j] = __builtin_amdgcn_mfma_f32_16x16x32_bf16(af[i], bfr[j], acc[i][j], 0, 0, 0);
      }
    }
    __syncthreads();
  }
  #pragma unroll
  for(int i=0;i<4;i++){
    #pragma unroll
    for(int j=0;j<4;j++){
      #pragma unroll
      for(int r=0;r<4;r++){
        int g = row0 + wm*64 + i*16 + (lane>>4)*4 + r;
        if(g < NN)
          H[(size_t)g*1024 + col0 + wn*64 + j*16 + (lane&15)] = f2b(acc[i][j][r]);
      }
    }
  }
}

// ---------------- el/er ----------------
__global__ __launch_bounds__(256) void k_eler(const us16* __restrict__ H,
    const float* __restrict__ al, const float* __restrict__ ar,
    float* __restrict__ el, float* __restrict__ er)
{
  const int wv = threadIdx.x>>6, lane = threadIdx.x&63;
  const int node = blockIdx.x*4 + wv;
  #pragma unroll
  for(int hd=0; hd<4; hd++){
    U2 hv;
    hv.v = *(const uint2*)(H + (size_t)node*1024 + hd*256 + lane*4);
    float4 lv = *(const float4*)(al + hd*256 + lane*4);
    float4 rv = *(const float4*)(ar + hd*256 + lane*4);
    float x0=b2f(hv.s[0]), x1=b2f(hv.s[1]), x2=b2f(hv.s[2]), x3=b2f(hv.s[3]);
    float sl = x0*lv.x + x1*lv.y + x2*lv.z + x3*lv.w;
    float sr = x0*rv.x + x1*rv.y + x2*rv.z + x3*rv.w;
    #pragma unroll
    for(int o=32;o;o>>=1){ sl += __shfl_xor(sl,o,64); sr += __shfl_xor(sr,o,64); }
    if(lane==0){ el[node*4+hd]=sl; er[node*4+hd]=sr; }
  }
}

// ---------------- scan ----------------
__global__ __launch_bounds__(1024) void k_scan(const int* __restrict__ counts,
                                               int* __restrict__ offsets, int* __restrict__ cursor)
{
  __shared__ int buf[1024];
  const int tid = threadIdx.x;
  const int base = tid*20;
  int loc[20];
  int s = 0;
  #pragma unroll
  for(int j=0;j<20;j++){
    int idx = base+j;
    int v = (idx<NN) ? counts[idx] : 0;
    loc[j] = s; s += v;
  }
  buf[tid] = s;
  __syncthreads();
  for(int off=1; off<1024; off<<=1){
    int t = (tid>=off) ? buf[tid-off] : 0;
    __syncthreads();
    buf[tid] += t;
    __syncthreads();
  }
  int excl = buf[tid] - s;
  #pragma unroll
  for(int j=0;j<20;j++){
    int idx = base+j;
    if(idx<NN){ offsets[idx]=excl+loc[j]; cursor[idx]=excl+loc[j]; }
  }
  if(tid==1023) offsets[NN] = excl + s;
}

// ---------------- scatter + edge scores: ew[pos][h] = leaky(el[src]+er[dst]) ----------------
__global__ __launch_bounds__(256) void k_scatter(const int* __restrict__ src, const int* __restrict__ dst,
    int* __restrict__ cursor, int* __restrict__ esrc,
    const float* __restrict__ el, const float* __restrict__ er,
    float* __restrict__ ew)
{
  int e = blockIdx.x*256 + threadIdx.x;
  if(e < NE){
    int s = src[e], d = dst[e];
    int pos = atomicAdd(&cursor[d], 1);
    esrc[pos] = s;
    float4 lv = *(const float4*)(el + s*4);
    float4 rv = *(const float4*)(er + d*4);
    float4 sc;
    sc.x = lv.x+rv.x; sc.x = sc.x>0.f ? sc.x : 0.2f*sc.x;
    sc.y = lv.y+rv.y; sc.y = sc.y>0.f ? sc.y : 0.2f*sc.y;
    sc.z = lv.z+rv.z; sc.z = sc.z>0.f ? sc.z : 0.2f*sc.z;
    sc.w = lv.w+rv.w; sc.w = sc.w>0.f ? sc.w : 0.2f*sc.w;
    *(float4*)(ew + (size_t)pos*4) = sc;
  }
}

// ---------------- GAT aggregate: contiguous scores + 2-edge-wide gather ----------------
__global__ __launch_bounds__(256) void k_agg(
    const int* __restrict__ offsets, const int* __restrict__ esrc,
    const float* __restrict__ ew,
    const us16* __restrict__ H, const float* __restrict__ gbias,
    us16* __restrict__ rst)
{
  const int node = blockIdx.x;
  const int hd = threadIdx.x>>6, lane = threadIdx.x&63;
  const int beg = offsets[node];
  const int deg = offsets[node+1] - beg;
  // phase 1: m, den over contiguous CSR-ordered scores
  float m = -3.0e38f;
  for(int i=lane; i<deg; i+=64) m = fmaxf(m, ew[(size_t)(beg+i)*4+hd]);
  #pragma unroll
  for(int o=32;o;o>>=1) m = fmaxf(m, __shfl_xor(m,o,64));
  float den = 0.f;
  for(int i=lane; i<deg; i+=64) den += __expf(ew[(size_t)(beg+i)*4+hd] - m);
  #pragma unroll
  for(int o=32;o;o>>=1) den += __shfl_xor(den,o,64);
  const float inv = (deg>0) ? 1.f/den : 0.f;
  // main: 2 edges per iteration; 32 lanes x 8 feats per edge
  const int half = lane>>5, l32 = lane&31;
  float acc[8] = {};
  #pragma unroll 2
  for(int j=half; j<deg; j+=2){
    float alpha = __expf(ew[(size_t)(beg+j)*4+hd] - m) * inv;
    int sN = esrc[beg+j];
    U4 hv; hv.v = *(const uint4*)(H + (size_t)sN*1024 + hd*256 + l32*8);
    #pragma unroll
    for(int k2=0;k2<8;k2++) acc[k2] = fmaf(alpha, b2f(hv.s[k2]), acc[k2]);
  }
  #pragma unroll
  for(int k2=0;k2<8;k2++) acc[k2] += __shfl_xor(acc[k2], 32, 64);
  if(lane < 32){
    float4 b0 = *(const float4*)(gbias + hd*256 + l32*8);
    float4 b1v = *(const float4*)(gbias + hd*256 + l32*8 + 4);
    float bb[8] = {b0.x,b0.y,b0.z,b0.w,b1v.x,b1v.y,b1v.z,b1v.w};
    U4 ov;
    #pragma unroll
    for(int k2=0;k2<8;k2++){
      float r = acc[k2] + bb[k2];
      r = r>0.f ? r : 0.f;
      ov.s[k2] = f2b(r);
    }
    *(uint4*)(rst + (size_t)node*1024 + hd*256 + l32*8) = ov.v;
  }
}

// ---------------- bn1 column stats ----------------
__global__ __launch_bounds__(256) void k_colstats(const us16* __restrict__ rst,
    float* __restrict__ sum, float* __restrict__ sq)
{
  const int tid = threadIdx.x;
  const int c0 = tid*4;
  int r0 = blockIdx.x*256;
  int r1 = min(r0+256, NN);
  float s[4]={}, q[4]={};
  for(int r=r0; r<r1; r++){
    U2 v; v.v = *(const uint2*)(rst + (size_t)r*1024 + c0);
    #pragma unroll
    for(int k2=0;k2<4;k2++){
      float f = b2f(v.s[k2]);
      s[k2] += f; q[k2] += f*f;
    }
  }
  #pragma unroll
  for(int k2=0;k2<4;k2++){
    atomicAdd(&sum[c0+k2], s[k2]);
    atomicAdd(&sq[c0+k2],  q[k2]);
  }
}

// ---------------- bn1 apply + transpose: rst[n, c*8+t] -> Xc[n, t, c] ----------------
__global__ __launch_bounds__(256) void k_xc(const us16* __restrict__ rst, const float* __restrict__ ss1,
                                            us16* __restrict__ Xc)
{
  __shared__ us16 xt[8*1040];
  const int tid = threadIdx.x;
  const size_t gbase = (size_t)blockIdx.x*8192;
  #pragma unroll
  for(int i=0;i<4;i++){
    int chunk = i*256 + tid;
    int n = chunk>>7, c = chunk&127;
    U4 in; in.v = *(const uint4*)(rst + gbase + chunk*8);
    int f0 = c*8;
    #pragma unroll
    for(int t=0;t<8;t++){
      float a = ss1[2*(f0+t)], b = ss1[2*(f0+t)+1];
      xt[n*1040 + t*130 + c] = f2b(fmaf(a, b2f(in.s[t]), b));
    }
  }
  __syncthreads();
  #pragma unroll
  for(int i=0;i<4;i++){
    int chunk = i*256 + tid;
    int o0 = chunk*8;
    int n = o0>>10, rem = o0&1023;
    int t = rem>>7, c0 = rem&127;
    U4 out;
    #pragma unroll
    for(int m2=0;m2<4;m2++)
      out.u[m2] = *(const unsigned*)&xt[n*1040 + t*130 + c0 + m2*2];
    *(uint4*)(Xc + gbase + o0) = out.v;
  }
}

// ---------------- conv2 as MFMA GEMM ----------------
__global__ __launch_bounds__(256) void k_gemm2(
    const us16* __restrict__ Xc, const us16* __restrict__ Wt,
    const float* __restrict__ b1, const float* __restrict__ b2, const float* __restrict__ b3,
    us16* __restrict__ y2, float* __restrict__ bn2_sum, float* __restrict__ bn2_sq)
{
  __shared__ float smemF[12800];
  us16* As = (us16*)smemF;
  us16* Bs = As + 9216;
  float* Cs = smemF;
  __shared__ float redS[32], redQ[32];
  const int tid = threadIdx.x;
  if(tid<32){ redS[tid]=0.f; redQ[tid]=0.f; }
  const int row0 = blockIdx.x*128;
  const int lane = tid&63, wv = tid>>6;
  const int wm = wv&1, wn = wv>>1;
  const int mrow = lane&15, kg = (lane>>4)*8;
  f32x4 acc[4][3] = {};
  for(int rd=0; rd<6; rd++){
    const int s = rd>>1, kc = rd&1;
    #pragma unroll
    for(int i=0;i<4;i++){
      int chunk = i*256 + tid;
      int row = chunk>>3, cc = chunk&7;
      int grow = row0 + row;
      int tsrc = (grow&7) + s - 1;
      uint4 av; av.x=0;av.y=0;av.z=0;av.w=0;
      if((unsigned)tsrc < 8u)
        av = *(const uint4*)(Xc + (size_t)(grow + s - 1)*128 + kc*64 + cc*8);
      *(uint4*)&As[row*72 + cc*8] = av;
    }
    #pragma unroll
    for(int i=0;i<3;i++){
      int chunk = i*256 + tid;
      int brow = chunk>>3, cc = chunk&7;
      *(uint4*)&Bs[brow*72 + cc*8] =
        *(const uint4*)(Wt + s*12288 + brow*128 + kc*64 + cc*8);
    }
    __syncthreads();
    #pragma unroll
    for(int kk=0; kk<64; kk+=32){
      short8 af[4], bfr[3];
      #pragma unroll
      for(int i=0;i<4;i++) af[i]  = *(const short8*)&As[(wm*64 + i*16 + mrow)*72 + kk + kg];
      #pragma unroll
      for(int j=0;j<3;j++) bfr[j] = *(const short8*)&Bs[(wn*48 + j*16 + mrow)*72 + kk + kg];
      #pragma unroll
      for(int i=0;i<4;i++){
        #pragma unroll
        for(int j=0;j<3;j++)
          acc[i][j] = __builtin_amdgcn_mfma_f32_16x16x32_bf16(af[i], bfr[j], acc[i][j], 0, 0, 0);
      }
    }
    __syncthreads();
  }
  #pragma unroll
  for(int i=0;i<4;i++){
    #pragma unroll
    for(int j=0;j<3;j++){
      #pragma unroll
      for(int r=0;r<4;r++)
        Cs[(wm*64 + i*16 + (lane>>4)*4 + r)*100 + wn*48 + j*16 + (lane&15)] = acc[i][j][r];
    }
  }
  __syncthreads();
  const int co = tid&31, rg = tid>>5;
  const float bb1=b1[co], bb2=b2[co], bb3=b3[co];
  float s=0.f, q=0.f;
  #pragma unroll
  for(int half=0; half<2; half++){
    U4 ov;
    #pragma unroll
    for(int t=0;t<8;t++){
      int r = rg*16 + half*8 + t;
      float c1 = Cs[r*100 + co]      + bb1;
      float c2 = Cs[r*100 + co + 32] + bb2;
      float c3 = Cs[r*100 + co + 64] + bb3;
      float sg = 1.f/(1.f+__expf(-c2));
      float v = fmaf(c1, sg, c3);
      v = v>0.f ? v : 0.f;
      s += v; q += v*v;
      ov.s[t] = f2b(v);
    }
    int node = (row0>>3) + rg*2 + half;
    *(uint4*)(y2 + (size_t)node*256 + co*8) = ov.v;
  }
  atomicAdd(&redS[co], s); atomicAdd(&redQ[co], q);
  __syncthreads();
  if(tid<32)      atomicAdd(&bn2_sum[tid], redS[tid]);
  else if(tid<64) atomicAdd(&bn2_sq[tid-32], redQ[tid-32]);
}

// ---------------- final ----------------
__global__ __launch_bounds__(256) void k_final(const us16* __restrict__ y2, const float* __restrict__ ss,
    const us16* __restrict__ resid, float* __restrict__ out)
{
  size_t base = ((size_t)blockIdx.x*256 + threadIdx.x)*8;
  int ch = (int)((base>>3)&31);
  float a = ss[2*ch], b = ss[2*ch+1];
  U4 yv, rv;
  yv.v = *(const uint4*)(y2+base);
  rv.v = *(const uint4*)(resid+base);
  float4 o0, o1;
  float vv[8];
  #pragma unroll
  for(int j=0;j<8;j++){
    float v = fmaf(a, b2f(yv.s[j]), b) + b2f(rv.s[j]);
    vv[j] = v>0.f ? v : 0.f;
  }
  o0.x=vv[0]; o0.y=vv[1]; o0.z=vv[2]; o0.w=vv[3];
  o1.x=vv[4]; o1.y=vv[5]; o1.z=vv[6]; o1.w=vv[7];
  *(float4*)(out+base)   = o0;
  *(float4*)(out+base+4) = o1;
}

extern "C" void kernel_launch(void* const* d_in, const int* in_sizes, int n_in,
                              void* d_out, int out_size, void* d_ws, size_t ws_size,
                              hipStream_t stream)
{
  const float* X    = (const float*)d_in[0];
  const int*  src   = (const int*)d_in[1];
  const int*  dst   = (const int*)d_in[2];
  const float* rp_w = (const float*)d_in[3];
  const float* rp_b = (const float*)d_in[4];
  const float* g1w1 = (const float*)d_in[5];
  const float* g1b1 = (const float*)d_in[6];
  const float* g1w2 = (const float*)d_in[7];
  const float* g1b2 = (const float*)d_in[8];
  const float* g1w3 = (const float*)d_in[9];
  const float* g1b3 = (const float*)d_in[10];
  const float* bn0g = (const float*)d_in[11];
  const float* bn0b = (const float*)d_in[12];
  const float* gatw = (const float*)d_in[13];
  const float* attnl= (const float*)d_in[14];
  const float* attnr= (const float*)d_in[15];
  const float* gbias= (const float*)d_in[16];
  const float* bn1g = (const float*)d_in[17];
  const float* bn1b = (const float*)d_in[18];
  const float* g2w1 = (const float*)d_in[19];
  const float* g2b1 = (const float*)d_in[20];
  const float* g2w2 = (const float*)d_in[21];
  const float* g2b2 = (const float*)d_in[22];
  const float* g2w3 = (const float*)d_in[23];
  const float* g2b3 = (const float*)d_in[24];
  const float* bn2g = (const float*)d_in[25];
  const float* bn2b = (const float*)d_in[26];
  float* out = (float*)d_out;
  (void)in_sizes; (void)n_in; (void)out_size; (void)ws_size;

  char* w = (char*)d_ws;
  float* bn0_sum = (float*)w;                 // 32
  float* bn0_sq  = bn0_sum + 32;              // 32
  float* bn1_sum = bn0_sum + 64;              // 1024
  float* bn1_sq  = bn1_sum + 1024;            // 1024
  float* bn2_sum = bn1_sq  + 1024;            // 32
  float* bn2_sq  = bn2_sum + 32;              // 32
  int*   counts  = (int*)(bn2_sq + 32);       // 20000  (zeroed region ends here)
  size_t zeroBytes = (size_t)((char*)(counts + NN) - w);
  float* ss0     = (float*)(counts + NN);     // 64
  float* ss1     = ss0 + 64;                  // 2048
  float* ss2     = ss1 + 2048;                // 64
  int*   offsets = (int*)(ss2 + 64);          // 20004
  int*   cursor  = offsets + 20004;           // 20000
  int*   esrc    = cursor + NN;               // 320000
  float* ew      = (float*)(esrc + NE);       // 1,280,000 floats (CSR-ordered scores)
  float* el      = ew + (size_t)NE*4;         // 80000
  float* er      = el + NN*4;                 // 80000
  us16*  wb      = (us16*)(er + NN*4);        // 262144
  us16*  resid   = wb + 262144;               // 5,120,000
  us16*  gc1     = resid + 5120000;           // 5,120,000
  us16*  h       = gc1   + 5120000;           // 20,480,000
  us16*  rst     = h     + 20480000;          // 20,480,000
  us16*  Wt      = rst   + 20480000;          // 36,864
  us16*  Xc      = h;                         // alias: h dead after k_agg
  us16*  y2      = gc1;                       // alias: gc1 dead after k_gemm

  hipMemsetAsync(d_ws, 0, zeroBytes, stream);
  k_misc<<<1650, 256, 0, stream>>>(gatw, wb, g2w1, g2w2, g2w3, Wt, dst, counts);
  k1_front<<<2500, 256, 0, stream>>>(X, rp_w, rp_b, g1w1, g1b1, g1w2, g1b2, g1w3, g1b3,
                                     resid, gc1, bn0_sum, bn0_sq);
  k_bnfin<<<1, 64, 0, stream>>>(bn0_sum, bn0_sq, bn0g, bn0b, ss0, 32, 1.f/160000.f);
  k_xbn<<<2500, 256, 0, stream>>>(gc1, ss0);
  k_gemm<<<dim3(157, 8), 256, 0, stream>>>(gc1, wb, h);
  k_eler<<<5000, 256, 0, stream>>>(h, attnl, attnr, el, er);
  k_scan<<<1, 1024, 0, stream>>>(counts, offsets, cursor);
  k_scatter<<<1250, 256, 0, stream>>>(src, dst, cursor, esrc, el, er, ew);
  k_agg<<<NN, 256, 0, stream>>>(offsets, esrc, ew, h, gbias, rst);
  k_colstats<<<79, 256, 0, stream>>>(rst, bn1_sum, bn1_sq);
  k_bnfin<<<4, 256, 0, stream>>>(bn1_sum, bn1_sq, bn1g, bn1b, ss1, 1024, 1.f/20000.f);
  k_xc<<<2500, 256, 0, stream>>>(rst, ss1, Xc);
  k_gemm2<<<1250, 256, 0, stream>>>(Xc, Wt, g2b1, g2b2, g2b3, y2, bn2_sum, bn2_sq);
  k_bnfin<<<1, 64, 0, stream>>>(bn2_sum, bn2_sq, bn2g, bn2b, ss2, 32, 1.f/160000.f);
  k_final<<<2500, 256, 0, stream>>>(y2, ss2, resid, out);
}

// Round 6
// 552.678 us; speedup vs baseline: 1.6049x; 1.0873x over previous
//
#include <hip/hip_runtime.h>
#include <stdint.h>

#define NN 20000
#define NE 320000

typedef unsigned short us16;
typedef __attribute__((ext_vector_type(8))) short short8;
typedef __attribute__((ext_vector_type(4))) float f32x4;

union U4 { uint4 v; us16 s[8]; unsigned u[4]; };
union U2 { uint2 v; us16 s[4]; };

__device__ __forceinline__ float b2f(us16 u){ return __uint_as_float(((unsigned)u)<<16); }
__device__ __forceinline__ us16 f2b(float f){
  unsigned u = __float_as_uint(f);
  u += 0x7fffu + ((u>>16)&1u);
  return (us16)(u>>16);
}

// ---------------- BN finalize ----------------
__global__ void k_bnfin(const float* __restrict__ sum, const float* __restrict__ sq,
                        const float* __restrict__ g, const float* __restrict__ b,
                        float* __restrict__ ss, int nch, float inv)
{
  int i = blockIdx.x*blockDim.x + threadIdx.x;
  if(i>=nch) return;
  float m = sum[i]*inv;
  float v = sq[i]*inv - m*m;
  float a = g[i] * rsqrtf(v + 1e-5f);
  ss[2*i]   = a;
  ss[2*i+1] = b[i] - m*a;
}

// ---------------- transpose X [n,c,t] fp32 -> Xc1 [n,t,c] bf16 ----------------
__global__ __launch_bounds__(256) void k_xc1(const float* __restrict__ X, us16* __restrict__ Xc1)
{
  __shared__ float xs[8*288];          // [n][c*9 + t] : stride 9 -> conflict-free both phases
  const int tid = threadIdx.x;
  {
    const int n = tid>>5, c = tid&31;
    const float4* Xv = (const float4*)(X + (size_t)blockIdx.x*2048);
    float4 a = Xv[tid*2], b = Xv[tid*2+1];
    float* p = &xs[n*288 + c*9];
    p[0]=a.x; p[1]=a.y; p[2]=a.z; p[3]=a.w;
    p[4]=b.x; p[5]=b.y; p[6]=b.z; p[7]=b.w;
  }
  __syncthreads();
  {
    int o0 = tid*8;
    int n = o0>>8, rem = o0&255;
    int t = rem>>5, c0 = rem&31;
    const float* p = &xs[n*288 + t];
    U4 out;
    #pragma unroll
    for(int j=0;j<8;j++) out.s[j] = f2b(p[(c0+j)*9]);
    *(uint4*)(Xc1 + (size_t)blockIdx.x*2048 + o0) = out.v;
  }
}

// ---------------- merged misc: gat_w cvt + conv2 wprep + conv1 wprep + hist ----------------
__global__ __launch_bounds__(256) void k_misc(
    const float* __restrict__ gatw, us16* __restrict__ Wb,
    const float* __restrict__ w1, const float* __restrict__ w2, const float* __restrict__ w3,
    us16* __restrict__ Wt,
    const float* __restrict__ c1w1, const float* __restrict__ c1w2, const float* __restrict__ c1w3,
    const float* __restrict__ rp_w, us16* __restrict__ Wt1,
    const int* __restrict__ dst, int* __restrict__ counts)
{
  const int b = blockIdx.x, tid = threadIdx.x;
  if(b < 256){
    int i = b*256 + tid;
    float4 v = *(const float4*)(gatw + (size_t)i*4);
    U2 o;
    o.s[0]=f2b(v.x); o.s[1]=f2b(v.y); o.s[2]=f2b(v.z); o.s[3]=f2b(v.w);
    *(uint2*)(Wb + (size_t)i*4) = o.v;
  } else if(b < 400){
    int i = (b-256)*256 + tid;       // 36864 total
    int s = i/12288, rem = i%12288;
    int co3 = rem>>7, ci = rem&127;
    const float* w = (co3<32) ? w1 : (co3<64) ? w2 : w3;
    Wt[i] = f2b(w[(co3&31)*384 + ci*3 + s]);
  } else if(b < 448){
    int i = (b-400)*256 + tid;       // 12288 total: Wt1[s][co3(128)][ci(32)]
    int s = i>>12, rem = i&4095;
    int co3 = rem>>5, ci = rem&31;
    float v;
    if(co3 < 96){
      const float* w = (co3<32) ? c1w1 : (co3<64) ? c1w2 : c1w3;
      v = w[(co3&31)*96 + ci*3 + s];
    } else {
      v = (s==1) ? rp_w[(co3-96)*32 + ci] : 0.f;
    }
    Wt1[i] = f2b(v);
  } else {
    int e = (b-448)*256 + tid;
    if(e < NE) atomicAdd(&counts[dst[e]], 1);
  }
}

// ---------------- conv1 (+residual k1) as MFMA GEMM: M=160000, N=128, K=3x32 ----------------
// epilogue: gate+relu -> gc1 [n][co][t]; resid [n][co][t]; bn0 stats
__global__ __launch_bounds__(256) void k_gemm1(
    const us16* __restrict__ Xc1, const us16* __restrict__ Wt1,
    const float* __restrict__ b1, const float* __restrict__ b2, const float* __restrict__ b3,
    const float* __restrict__ rp_b,
    us16* __restrict__ gc1, us16* __restrict__ resid,
    float* __restrict__ bn0_sum, float* __restrict__ bn0_sq)
{
  __shared__ float smemF[16896];          // 67584 B union
  us16* As = (us16*)smemF;                // [128][40]
  us16* Bs = As + 5120;                   // [128][40]
  float* Cs = smemF;                      // [128][132]
  __shared__ float redS[32], redQ[32];
  const int tid = threadIdx.x;
  if(tid<32){ redS[tid]=0.f; redQ[tid]=0.f; }
  const int row0 = blockIdx.x*128;
  const int lane = tid&63, wv = tid>>6;
  const int wm = wv&1, wn = wv>>1;
  const int mrow = lane&15, kg = (lane>>4)*8;
  f32x4 acc[4][4] = {};
  for(int s=0; s<3; s++){
    #pragma unroll
    for(int i=0;i<2;i++){
      int chunk = i*256 + tid;            // 512 chunks of 8 elems
      int row = chunk>>2, cc = chunk&3;
      int grow = row0 + row;
      int tsrc = (grow&7) + s - 1;
      uint4 av; av.x=0;av.y=0;av.z=0;av.w=0;
      if((unsigned)tsrc < 8u)
        av = *(const uint4*)(Xc1 + (size_t)(grow + s - 1)*32 + cc*8);
      *(uint4*)&As[row*40 + cc*8] = av;
      *(uint4*)&Bs[row*40 + cc*8] = *(const uint4*)(Wt1 + s*4096 + row*32 + cc*8);
    }
    __syncthreads();
    short8 af[4], bfr[4];
    #pragma unroll
    for(int i=0;i<4;i++) af[i]  = *(const short8*)&As[(wm*64 + i*16 + mrow)*40 + kg];
    #pragma unroll
    for(int j=0;j<4;j++) bfr[j] = *(const short8*)&Bs[(wn*64 + j*16 + mrow)*40 + kg];
    #pragma unroll
    for(int i=0;i<4;i++){
      #pragma unroll
      for(int j=0;j<4;j++)
        acc[i][j] = __builtin_amdgcn_mfma_f32_16x16x32_bf16(af[i], bfr[j], acc[i][j], 0, 0, 0);
    }
    __syncthreads();
  }
  // dump to LDS (C-layout: col=lane&15, row=(lane>>4)*4+r); 132-col pad
  #pragma unroll
  for(int i=0;i<4;i++){
    #pragma unroll
    for(int j=0;j<4;j++){
      #pragma unroll
      for(int r=0;r<4;r++)
        Cs[(wm*64 + i*16 + (lane>>4)*4 + r)*132 + wn*64 + j*16 + (lane&15)] = acc[i][j][r];
    }
  }
  __syncthreads();
  // epilogue: thread (co=tid&31, rg=tid>>5) handles 16 rows = 2 nodes
  const int co = tid&31, rg = tid>>5;
  const float bb1=b1[co], bb2=b2[co], bb3=b3[co], bbr=rp_b[co];
  float s=0.f, q=0.f;
  #pragma unroll
  for(int half=0; half<2; half++){
    U4 ov, rv;
    #pragma unroll
    for(int t=0;t<8;t++){
      int r = rg*16 + half*8 + t;
      float c1 = Cs[r*132 + co]      + bb1;
      float c2 = Cs[r*132 + co + 32] + bb2;
      float c3 = Cs[r*132 + co + 64] + bb3;
      float rr = Cs[r*132 + co + 96] + bbr;
      float sg = 1.f/(1.f+__expf(-c2));
      float v = fmaf(c1, sg, c3);
      v = v>0.f ? v : 0.f;
      s += v; q += v*v;
      ov.s[t] = f2b(v);
      rv.s[t] = f2b(rr);
    }
    int node = (row0>>3) + rg*2 + half;
    *(uint4*)(gc1   + (size_t)node*256 + co*8) = ov.v;
    *(uint4*)(resid + (size_t)node*256 + co*8) = rv.v;
  }
  atomicAdd(&redS[co], s); atomicAdd(&redQ[co], q);
  __syncthreads();
  if(tid<32)      atomicAdd(&bn0_sum[tid], redS[tid]);
  else if(tid<64) atomicAdd(&bn0_sq[tid-32], redQ[tid-32]);
}

// ---------------- apply bn0 in-place on gc1 ----------------
__global__ __launch_bounds__(256) void k_xbn(us16* __restrict__ gc1, const float* __restrict__ ss)
{
  size_t base = ((size_t)blockIdx.x*256 + threadIdx.x)*8;
  U4 in, out;
  in.v = *(const uint4*)(gc1+base);
  int ch = (int)((base>>3)&31);
  float a = ss[2*ch], b = ss[2*ch+1];
  #pragma unroll
  for(int j=0;j<8;j++) out.s[j] = f2b(fmaf(a, b2f(in.s[j]), b));
  *(uint4*)(gc1+base) = out.v;
}

// ---------------- GAT fc GEMM: h = A[20000,256] @ Wb[1024,256]^T ----------------
__global__ __launch_bounds__(256) void k_gemm(const us16* __restrict__ A, const us16* __restrict__ B,
                                              us16* __restrict__ H)
{
  __shared__ us16 As[128*72];
  __shared__ us16 Bs[128*72];
  const int tid = threadIdx.x;
  const int row0 = blockIdx.x*128, col0 = blockIdx.y*128;
  const int lane = tid&63, wv = tid>>6;
  const int wm = wv&1, wn = wv>>1;
  const int mrow = lane&15, kg = (lane>>4)*8;
  f32x4 acc[4][4] = {};
  for(int k0=0; k0<256; k0+=64){
    #pragma unroll
    for(int i=0;i<4;i++){
      int chunk = i*256 + tid;
      int row = chunk>>3, cc = chunk&7;
      int g = row0 + row;
      uint4 av; av.x=0;av.y=0;av.z=0;av.w=0;
      if(g < NN) av = *(const uint4*)(A + (size_t)g*256 + k0 + cc*8);
      *(uint4*)&As[row*72 + cc*8] = av;
      *(uint4*)&Bs[row*72 + cc*8] = *(const uint4*)(B + (size_t)(col0+row)*256 + k0 + cc*8);
    }
    __syncthreads();
    #pragma unroll
    for(int kk=0; kk<64; kk+=32){
      short8 af[4], bfr[4];
      #pragma unroll
      for(int i=0;i<4;i++) af[i]  = *(const short8*)&As[(wm*64 + i*16 + mrow)*72 + kk + kg];
      #pragma unroll
      for(int j=0;j<4;j++) bfr[j] = *(const short8*)&Bs[(wn*64 + j*16 + mrow)*72 + kk + kg];
      #pragma unroll
      for(int i=0;i<4;i++){
        #pragma unroll
        for(int j=0;j<4;j++)
          acc[i][j] = __builtin_amdgcn_mfma_f32_16x16x32_bf16(af[i], bfr[j], acc[i][j], 0, 0, 0);
      }
    }
    __syncthreads();
  }
  #pragma unroll
  for(int i=0;i<4;i++){
    #pragma unroll
    for(int j=0;j<4;j++){
      #pragma unroll
      for(int r=0;r<4;r++){
        int g = row0 + wm*64 + i*16 + (lane>>4)*4 + r;
        if(g < NN)
          H[(size_t)g*1024 + col0 + wn*64 + j*16 + (lane&15)] = f2b(acc[i][j][r]);
      }
    }
  }
}

// ---------------- el/er ----------------
__global__ __launch_bounds__(256) void k_eler(const us16* __restrict__ H,
    const float* __restrict__ al, const float* __restrict__ ar,
    float* __restrict__ el, float* __restrict__ er)
{
  const int wv = threadIdx.x>>6, lane = threadIdx.x&63;
  const int node = blockIdx.x*4 + wv;
  #pragma unroll
  for(int hd=0; hd<4; hd++){
    U2 hv;
    hv.v = *(const uint2*)(H + (size_t)node*1024 + hd*256 + lane*4);
    float4 lv = *(const float4*)(al + hd*256 + lane*4);
    float4 rv = *(const float4*)(ar + hd*256 + lane*4);
    float x0=b2f(hv.s[0]), x1=b2f(hv.s[1]), x2=b2f(hv.s[2]), x3=b2f(hv.s[3]);
    float sl = x0*lv.x + x1*lv.y + x2*lv.z + x3*lv.w;
    float sr = x0*rv.x + x1*rv.y + x2*rv.z + x3*rv.w;
    #pragma unroll
    for(int o=32;o;o>>=1){ sl += __shfl_xor(sl,o,64); sr += __shfl_xor(sr,o,64); }
    if(lane==0){ el[node*4+hd]=sl; er[node*4+hd]=sr; }
  }
}

// ---------------- scan ----------------
__global__ __launch_bounds__(1024) void k_scan(const int* __restrict__ counts,
                                               int* __restrict__ offsets, int* __restrict__ cursor)
{
  __shared__ int buf[1024];
  const int tid = threadIdx.x;
  const int base = tid*20;
  int loc[20];
  int s = 0;
  #pragma unroll
  for(int j=0;j<20;j++){
    int idx = base+j;
    int v = (idx<NN) ? counts[idx] : 0;
    loc[j] = s; s += v;
  }
  buf[tid] = s;
  __syncthreads();
  for(int off=1; off<1024; off<<=1){
    int t = (tid>=off) ? buf[tid-off] : 0;
    __syncthreads();
    buf[tid] += t;
    __syncthreads();
  }
  int excl = buf[tid] - s;
  #pragma unroll
  for(int j=0;j<20;j++){
    int idx = base+j;
    if(idx<NN){ offsets[idx]=excl+loc[j]; cursor[idx]=excl+loc[j]; }
  }
  if(tid==1023) offsets[NN] = excl + s;
}

// ---------------- scatter + edge scores ----------------
__global__ __launch_bounds__(256) void k_scatter(const int* __restrict__ src, const int* __restrict__ dst,
    int* __restrict__ cursor, int* __restrict__ esrc,
    const float* __restrict__ el, const float* __restrict__ er,
    float* __restrict__ ew)
{
  int e = blockIdx.x*256 + threadIdx.x;
  if(e < NE){
    int s = src[e], d = dst[e];
    int pos = atomicAdd(&cursor[d], 1);
    esrc[pos] = s;
    float4 lv = *(const float4*)(el + s*4);
    float4 rv = *(const float4*)(er + d*4);
    float4 sc;
    sc.x = lv.x+rv.x; sc.x = sc.x>0.f ? sc.x : 0.2f*sc.x;
    sc.y = lv.y+rv.y; sc.y = sc.y>0.f ? sc.y : 0.2f*sc.y;
    sc.z = lv.z+rv.z; sc.z = sc.z>0.f ? sc.z : 0.2f*sc.z;
    sc.w = lv.w+rv.w; sc.w = sc.w>0.f ? sc.w : 0.2f*sc.w;
    *(float4*)(ew + (size_t)pos*4) = sc;
  }
}

// ---------------- GAT aggregate ----------------
__global__ __launch_bounds__(256) void k_agg(
    const int* __restrict__ offsets, const int* __restrict__ esrc,
    const float* __restrict__ ew,
    const us16* __restrict__ H, const float* __restrict__ gbias,
    us16* __restrict__ rst)
{
  const int node = blockIdx.x;
  const int hd = threadIdx.x>>6, lane = threadIdx.x&63;
  const int beg = offsets[node];
  const int deg = offsets[node+1] - beg;
  float m = -3.0e38f;
  for(int i=lane; i<deg; i+=64) m = fmaxf(m, ew[(size_t)(beg+i)*4+hd]);
  #pragma unroll
  for(int o=32;o;o>>=1) m = fmaxf(m, __shfl_xor(m,o,64));
  float den = 0.f;
  for(int i=lane; i<deg; i+=64) den += __expf(ew[(size_t)(beg+i)*4+hd] - m);
  #pragma unroll
  for(int o=32;o;o>>=1) den += __shfl_xor(den,o,64);
  const float inv = (deg>0) ? 1.f/den : 0.f;
  const int half = lane>>5, l32 = lane&31;
  float acc[8] = {};
  #pragma unroll 2
  for(int j=half; j<deg; j+=2){
    float alpha = __expf(ew[(size_t)(beg+j)*4+hd] - m) * inv;
    int sN = esrc[beg+j];
    U4 hv; hv.v = *(const uint4*)(H + (size_t)sN*1024 + hd*256 + l32*8);
    #pragma unroll
    for(int k2=0;k2<8;k2++) acc[k2] = fmaf(alpha, b2f(hv.s[k2]), acc[k2]);
  }
  #pragma unroll
  for(int k2=0;k2<8;k2++) acc[k2] += __shfl_xor(acc[k2], 32, 64);
  if(lane < 32){
    float4 b0 = *(const float4*)(gbias + hd*256 + l32*8);
    float4 b1v = *(const float4*)(gbias + hd*256 + l32*8 + 4);
    float bb[8] = {b0.x,b0.y,b0.z,b0.w,b1v.x,b1v.y,b1v.z,b1v.w};
    U4 ov;
    #pragma unroll
    for(int k2=0;k2<8;k2++){
      float r = acc[k2] + bb[k2];
      r = r>0.f ? r : 0.f;
      ov.s[k2] = f2b(r);
    }
    *(uint4*)(rst + (size_t)node*1024 + hd*256 + l32*8) = ov.v;
  }
}

// ---------------- bn1 column stats ----------------
__global__ __launch_bounds__(256) void k_colstats(const us16* __restrict__ rst,
    float* __restrict__ sum, float* __restrict__ sq)
{
  const int tid = threadIdx.x;
  const int c0 = tid*4;
  int r0 = blockIdx.x*256;
  int r1 = min(r0+256, NN);
  float s[4]={}, q[4]={};
  for(int r=r0; r<r1; r++){
    U2 v; v.v = *(const uint2*)(rst + (size_t)r*1024 + c0);
    #pragma unroll
    for(int k2=0;k2<4;k2++){
      float f = b2f(v.s[k2]);
      s[k2] += f; q[k2] += f*f;
    }
  }
  #pragma unroll
  for(int k2=0;k2<4;k2++){
    atomicAdd(&sum[c0+k2], s[k2]);
    atomicAdd(&sq[c0+k2],  q[k2]);
  }
}

// ---------------- bn1 apply + transpose: rst[n, c*8+t] -> Xc[n, t, c] ----------------
__global__ __launch_bounds__(256) void k_xc(const us16* __restrict__ rst, const float* __restrict__ ss1,
                                            us16* __restrict__ Xc)
{
  __shared__ us16 xt[8*1040];
  const int tid = threadIdx.x;
  const size_t gbase = (size_t)blockIdx.x*8192;
  #pragma unroll
  for(int i=0;i<4;i++){
    int chunk = i*256 + tid;
    int n = chunk>>7, c = chunk&127;
    U4 in; in.v = *(const uint4*)(rst + gbase + chunk*8);
    int f0 = c*8;
    #pragma unroll
    for(int t=0;t<8;t++){
      float a = ss1[2*(f0+t)], b = ss1[2*(f0+t)+1];
      xt[n*1040 + t*130 + c] = f2b(fmaf(a, b2f(in.s[t]), b));
    }
  }
  __syncthreads();
  #pragma unroll
  for(int i=0;i<4;i++){
    int chunk = i*256 + tid;
    int o0 = chunk*8;
    int n = o0>>10, rem = o0&1023;
    int t = rem>>7, c0 = rem&127;
    U4 out;
    #pragma unroll
    for(int m2=0;m2<4;m2++)
      out.u[m2] = *(const unsigned*)&xt[n*1040 + t*130 + c0 + m2*2];
    *(uint4*)(Xc + gbase + o0) = out.v;
  }
}

// ---------------- conv2 as MFMA GEMM ----------------
__global__ __launch_bounds__(256) void k_gemm2(
    const us16* __restrict__ Xc, const us16* __restrict__ Wt,
    const float* __restrict__ b1, const float* __restrict__ b2, const float* __restrict__ b3,
    us16* __restrict__ y2, float* __restrict__ bn2_sum, float* __restrict__ bn2_sq)
{
  __shared__ float smemF[12800];
  us16* As = (us16*)smemF;
  us16* Bs = As + 9216;
  float* Cs = smemF;
  __shared__ float redS[32], redQ[32];
  const int tid = threadIdx.x;
  if(tid<32){ redS[tid]=0.f; redQ[tid]=0.f; }
  const int row0 = blockIdx.x*128;
  const int lane = tid&63, wv = tid>>6;
  const int wm = wv&1, wn = wv>>1;
  const int mrow = lane&15, kg = (lane>>4)*8;
  f32x4 acc[4][3] = {};
  for(int rd=0; rd<6; rd++){
    const int s = rd>>1, kc = rd&1;
    #pragma unroll
    for(int i=0;i<4;i++){
      int chunk = i*256 + tid;
      int row = chunk>>3, cc = chunk&7;
      int grow = row0 + row;
      int tsrc = (grow&7) + s - 1;
      uint4 av; av.x=0;av.y=0;av.z=0;av.w=0;
      if((unsigned)tsrc < 8u)
        av = *(const uint4*)(Xc + (size_t)(grow + s - 1)*128 + kc*64 + cc*8);
      *(uint4*)&As[row*72 + cc*8] = av;
    }
    #pragma unroll
    for(int i=0;i<3;i++){
      int chunk = i*256 + tid;
      int brow = chunk>>3, cc = chunk&7;
      *(uint4*)&Bs[brow*72 + cc*8] =
        *(const uint4*)(Wt + s*12288 + brow*128 + kc*64 + cc*8);
    }
    __syncthreads();
    #pragma unroll
    for(int kk=0; kk<64; kk+=32){
      short8 af[4], bfr[3];
      #pragma unroll
      for(int i=0;i<4;i++) af[i]  = *(const short8*)&As[(wm*64 + i*16 + mrow)*72 + kk + kg];
      #pragma unroll
      for(int j=0;j<3;j++) bfr[j] = *(const short8*)&Bs[(wn*48 + j*16 + mrow)*72 + kk + kg];
      #pragma unroll
      for(int i=0;i<4;i++){
        #pragma unroll
        for(int j=0;j<3;j++)
          acc[i][j] = __builtin_amdgcn_mfma_f32_16x16x32_bf16(af[i], bfr[j], acc[i][j], 0, 0, 0);
      }
    }
    __syncthreads();
  }
  #pragma unroll
  for(int i=0;i<4;i++){
    #pragma unroll
    for(int j=0;j<3;j++){
      #pragma unroll
      for(int r=0;r<4;r++)
        Cs[(wm*64 + i*16 + (lane>>4)*4 + r)*100 + wn*48 + j*16 + (lane&15)] = acc[i][j][r];
    }
  }
  __syncthreads();
  const int co = tid&31, rg = tid>>5;
  const float bb1=b1[co], bb2=b2[co], bb3=b3[co];
  float s=0.f, q=0.f;
  #pragma unroll
  for(int half=0; half<2; half++){
    U4 ov;
    #pragma unroll
    for(int t=0;t<8;t++){
      int r = rg*16 + half*8 + t;
      float c1 = Cs[r*100 + co]      + bb1;
      float c2 = Cs[r*100 + co + 32] + bb2;
      float c3 = Cs[r*100 + co + 64] + bb3;
      float sg = 1.f/(1.f+__expf(-c2));
      float v = fmaf(c1, sg, c3);
      v = v>0.f ? v : 0.f;
      s += v; q += v*v;
      ov.s[t] = f2b(v);
    }
    int node = (row0>>3) + rg*2 + half;
    *(uint4*)(y2 + (size_t)node*256 + co*8) = ov.v;
  }
  atomicAdd(&redS[co], s); atomicAdd(&redQ[co], q);
  __syncthreads();
  if(tid<32)      atomicAdd(&bn2_sum[tid], redS[tid]);
  else if(tid<64) atomicAdd(&bn2_sq[tid-32], redQ[tid-32]);
}

// ---------------- final ----------------
__global__ __launch_bounds__(256) void k_final(const us16* __restrict__ y2, const float* __restrict__ ss,
    const us16* __restrict__ resid, float* __restrict__ out)
{
  size_t base = ((size_t)blockIdx.x*256 + threadIdx.x)*8;
  int ch = (int)((base>>3)&31);
  float a = ss[2*ch], b = ss[2*ch+1];
  U4 yv, rv;
  yv.v = *(const uint4*)(y2+base);
  rv.v = *(const uint4*)(resid+base);
  float4 o0, o1;
  float vv[8];
  #pragma unroll
  for(int j=0;j<8;j++){
    float v = fmaf(a, b2f(yv.s[j]), b) + b2f(rv.s[j]);
    vv[j] = v>0.f ? v : 0.f;
  }
  o0.x=vv[0]; o0.y=vv[1]; o0.z=vv[2]; o0.w=vv[3];
  o1.x=vv[4]; o1.y=vv[5]; o1.z=vv[6]; o1.w=vv[7];
  *(float4*)(out+base)   = o0;
  *(float4*)(out+base+4) = o1;
}

extern "C" void kernel_launch(void* const* d_in, const int* in_sizes, int n_in,
                              void* d_out, int out_size, void* d_ws, size_t ws_size,
                              hipStream_t stream)
{
  const float* X    = (const float*)d_in[0];
  const int*  src   = (const int*)d_in[1];
  const int*  dst   = (const int*)d_in[2];
  const float* rp_w = (const float*)d_in[3];
  const float* rp_b = (const float*)d_in[4];
  const float* g1w1 = (const float*)d_in[5];
  const float* g1b1 = (const float*)d_in[6];
  const float* g1w2 = (const float*)d_in[7];
  const float* g1b2 = (const float*)d_in[8];
  const float* g1w3 = (const float*)d_in[9];
  const float* g1b3 = (const float*)d_in[10];
  const float* bn0g = (const float*)d_in[11];
  const float* bn0b = (const float*)d_in[12];
  const float* gatw = (const float*)d_in[13];
  const float* attnl= (const float*)d_in[14];
  const float* attnr= (const float*)d_in[15];
  const float* gbias= (const float*)d_in[16];
  const float* bn1g = (const float*)d_in[17];
  const float* bn1b = (const float*)d_in[18];
  const float* g2w1 = (const float*)d_in[19];
  const float* g2b1 = (const float*)d_in[20];
  const float* g2w2 = (const float*)d_in[21];
  const float* g2b2 = (const float*)d_in[22];
  const float* g2w3 = (const float*)d_in[23];
  const float* g2b3 = (const float*)d_in[24];
  const float* bn2g = (const float*)d_in[25];
  const float* bn2b = (const float*)d_in[26];
  float* out = (float*)d_out;
  (void)in_sizes; (void)n_in; (void)out_size; (void)ws_size;

  char* w = (char*)d_ws;
  float* bn0_sum = (float*)w;                 // 32
  float* bn0_sq  = bn0_sum + 32;              // 32
  float* bn1_sum = bn0_sum + 64;              // 1024
  float* bn1_sq  = bn1_sum + 1024;            // 1024
  float* bn2_sum = bn1_sq  + 1024;            // 32
  float* bn2_sq  = bn2_sum + 32;              // 32
  int*   counts  = (int*)(bn2_sq + 32);       // 20000  (zeroed region ends here)
  size_t zeroBytes = (size_t)((char*)(counts + NN) - w);
  float* ss0     = (float*)(counts + NN);     // 64
  float* ss1     = ss0 + 64;                  // 2048
  float* ss2     = ss1 + 2048;                // 64
  int*   offsets = (int*)(ss2 + 64);          // 20004
  int*   cursor  = offsets + 20004;           // 20000
  int*   esrc    = cursor + NN;               // 320000
  float* ew      = (float*)(esrc + NE);       // 1,280,000
  float* el      = ew + (size_t)NE*4;         // 80000
  float* er      = el + NN*4;                 // 80000
  us16*  wb      = (us16*)(er + NN*4);        // 262144
  us16*  resid   = wb + 262144;               // 5,120,000
  us16*  gc1     = resid + 5120000;           // 5,120,000
  us16*  h       = gc1   + 5120000;           // 20,480,000
  us16*  rst     = h     + 20480000;          // 20,480,000
  us16*  Wt      = rst   + 20480000;          // 36,864
  us16*  Wt1     = Wt    + 36864;             // 12,288
  us16*  Xc1     = rst;                       // alias: rst written later (k_agg)
  us16*  Xc      = h;                         // alias: h dead after k_agg
  us16*  y2      = gc1;                       // alias: gc1 dead after k_gemm

  hipMemsetAsync(d_ws, 0, zeroBytes, stream);
  k_misc<<<1698, 256, 0, stream>>>(gatw, wb, g2w1, g2w2, g2w3, Wt,
                                   g1w1, g1w2, g1w3, rp_w, Wt1, dst, counts);
  k_xc1<<<2500, 256, 0, stream>>>(X, Xc1);
  k_gemm1<<<1250, 256, 0, stream>>>(Xc1, Wt1, g1b1, g1b2, g1b3, rp_b,
                                    gc1, resid, bn0_sum, bn0_sq);
  k_bnfin<<<1, 64, 0, stream>>>(bn0_sum, bn0_sq, bn0g, bn0b, ss0, 32, 1.f/160000.f);
  k_xbn<<<2500, 256, 0, stream>>>(gc1, ss0);
  k_gemm<<<dim3(157, 8), 256, 0, stream>>>(gc1, wb, h);
  k_eler<<<5000, 256, 0, stream>>>(h, attnl, attnr, el, er);
  k_scan<<<1, 1024, 0, stream>>>(counts, offsets, cursor);
  k_scatter<<<1250, 256, 0, stream>>>(src, dst, cursor, esrc, el, er, ew);
  k_agg<<<NN, 256, 0, stream>>>(offsets, esrc, ew, h, gbias, rst);
  k_colstats<<<79, 256, 0, stream>>>(rst, bn1_sum, bn1_sq);
  k_bnfin<<<4, 256, 0, stream>>>(bn1_sum, bn1_sq, bn1g, bn1b, ss1, 1024, 1.f/20000.f);
  k_xc<<<2500, 256, 0, stream>>>(rst, ss1, Xc);
  k_gemm2<<<1250, 256, 0, stream>>>(Xc, Wt, g2b1, g2b2, g2b3, y2, bn2_sum, bn2_sq);
  k_bnfin<<<1, 64, 0, stream>>>(bn2_sum, bn2_sq, bn2g, bn2b, ss2, 32, 1.f/160000.f);
  k_final<<<2500, 256, 0, stream>>>(y2, ss2, resid, out);
}

// Round 7
// 522.742 us; speedup vs baseline: 1.6968x; 1.0573x over previous
//
#include <hip/hip_runtime.h>
#include <stdint.h>

#define NN 20000
#define NE 320000

typedef unsigned short us16;
typedef __attribute__((ext_vector_type(8))) short short8;
typedef __attribute__((ext_vector_type(4))) float f32x4;

union U4 { uint4 v; us16 s[8]; unsigned u[4]; };
union U2 { uint2 v; us16 s[4]; };

__device__ __forceinline__ float b2f(us16 u){ return __uint_as_float(((unsigned)u)<<16); }
__device__ __forceinline__ us16 f2b(float f){
  unsigned u = __float_as_uint(f);
  u += 0x7fffu + ((u>>16)&1u);
  return (us16)(u>>16);
}

// ---------------- merged misc: gat_w cvt + conv2 wprep + conv1 wprep + hist ----------------
__global__ __launch_bounds__(256) void k_misc(
    const float* __restrict__ gatw, us16* __restrict__ Wb,
    const float* __restrict__ w1, const float* __restrict__ w2, const float* __restrict__ w3,
    us16* __restrict__ Wt,
    const float* __restrict__ c1w1, const float* __restrict__ c1w2, const float* __restrict__ c1w3,
    const float* __restrict__ rp_w, us16* __restrict__ Wt1,
    const int* __restrict__ dst, int* __restrict__ counts)
{
  const int b = blockIdx.x, tid = threadIdx.x;
  if(b < 256){
    int i = b*256 + tid;
    float4 v = *(const float4*)(gatw + (size_t)i*4);
    U2 o;
    o.s[0]=f2b(v.x); o.s[1]=f2b(v.y); o.s[2]=f2b(v.z); o.s[3]=f2b(v.w);
    *(uint2*)(Wb + (size_t)i*4) = o.v;
  } else if(b < 400){
    int i = (b-256)*256 + tid;       // 36864 total: Wt[s][co3(96)][ci(128)]
    int s = i/12288, rem = i%12288;
    int co3 = rem>>7, ci = rem&127;
    const float* w = (co3<32) ? w1 : (co3<64) ? w2 : w3;
    Wt[i] = f2b(w[(co3&31)*384 + ci*3 + s]);
  } else if(b < 448){
    int i = (b-400)*256 + tid;       // 12288 total: Wt1[s][co3(128)][ci(32)]
    int s = i>>12, rem = i&4095;
    int co3 = rem>>5, ci = rem&31;
    float v;
    if(co3 < 96){
      const float* w = (co3<32) ? c1w1 : (co3<64) ? c1w2 : c1w3;
      v = w[(co3&31)*96 + ci*3 + s];
    } else {
      v = (s==1) ? rp_w[(co3-96)*32 + ci] : 0.f;
    }
    Wt1[i] = f2b(v);
  } else {
    int e = (b-448)*256 + tid;
    if(e < NE) atomicAdd(&counts[dst[e]], 1);
  }
}

// ---------------- conv1 (+residual k1) as MFMA GEMM, X read direct (fp32) ----------------
// A-tile: [16 nodes][10 t-slots][40 pad] bf16, slots 0/9 zero; B: all 3 shifts staged once.
// epilogue: gate+relu -> gc1 (RAW, bn0 later), resid, bn0 stats
__global__ __launch_bounds__(256) void k_gemm1(
    const float* __restrict__ X, const us16* __restrict__ Wt1,
    const float* __restrict__ b1, const float* __restrict__ b2, const float* __restrict__ b3,
    const float* __restrict__ rp_b,
    us16* __restrict__ gc1, us16* __restrict__ resid,
    float* __restrict__ bn0_sum, float* __restrict__ bn0_sq)
{
  __shared__ float smemF[16896];          // 67584 B union
  us16* As = (us16*)smemF;                // [16][10][40] = 6400
  us16* Bs = As + 6400;                   // [3][128][40] = 15360
  float* Cs = smemF;                      // [128][132]
  __shared__ float redS[32], redQ[32];
  const int tid = threadIdx.x;
  if(tid<32){ redS[tid]=0.f; redQ[tid]=0.f; }
  const int row0 = blockIdx.x*128;        // node0 = blockIdx.x*16
  const int node0 = blockIdx.x*16;
  const int lane = tid&63, wv = tid>>6;
  const int wm = wv&1, wn = wv>>1;
  const int mrow = lane&15, kg = (lane>>4)*8;
  // zero halo slots: 16 nodes x {0,9} x 32 ci
  for(int idx=tid; idx<1024; idx+=256){
    int n = idx>>6, rem = idx&63, slot = (rem>>5)*9, ci = rem&31;
    As[n*400 + slot*40 + ci] = 0;
  }
  // stage A: X[node][ci][t] fp32 -> As[n][t+1][ci]
  #pragma unroll
  for(int i=0;i<4;i++){
    int idx = i*256 + tid;                // 1024 float4 reads
    int n = idx>>6, rem = idx&63, ci = rem>>1, tq = rem&1;
    float4 xv = *(const float4*)(X + (size_t)(node0+n)*256 + ci*8 + tq*4);
    us16* p = &As[n*400 + (tq*4+1)*40 + ci];
    p[0]   = f2b(xv.x);
    p[40]  = f2b(xv.y);
    p[80]  = f2b(xv.z);
    p[120] = f2b(xv.w);
  }
  // stage B: all 3 shifts
  #pragma unroll
  for(int i=0;i<6;i++){
    int c = i*256 + tid;                  // 1536 uint4 chunks
    int s = c>>9, rem = c&511, co = rem>>2, cq = rem&3;
    *(uint4*)&Bs[s*5120 + co*40 + cq*8] = *(const uint4*)(Wt1 + s*4096 + co*32 + cq*8);
  }
  __syncthreads();
  f32x4 acc[4][4] = {};
  #pragma unroll
  for(int s=0; s<3; s++){
    short8 af[4], bfr[4];
    #pragma unroll
    for(int i=0;i<4;i++){
      int r = wm*64 + i*16 + mrow;
      af[i] = *(const short8*)&As[(r>>3)*400 + ((r&7)+s)*40 + kg];
    }
    #pragma unroll
    for(int j=0;j<4;j++)
      bfr[j] = *(const short8*)&Bs[s*5120 + (wn*64 + j*16 + mrow)*40 + kg];
    #pragma unroll
    for(int i=0;i<4;i++){
      #pragma unroll
      for(int j=0;j<4;j++)
        acc[i][j] = __builtin_amdgcn_mfma_f32_16x16x32_bf16(af[i], bfr[j], acc[i][j], 0, 0, 0);
    }
  }
  __syncthreads();
  #pragma unroll
  for(int i=0;i<4;i++){
    #pragma unroll
    for(int j=0;j<4;j++){
      #pragma unroll
      for(int r=0;r<4;r++)
        Cs[(wm*64 + i*16 + (lane>>4)*4 + r)*132 + wn*64 + j*16 + (lane&15)] = acc[i][j][r];
    }
  }
  __syncthreads();
  const int co = tid&31, rg = tid>>5;
  const float bb1=b1[co], bb2=b2[co], bb3=b3[co], bbr=rp_b[co];
  float s=0.f, q=0.f;
  #pragma unroll
  for(int half=0; half<2; half++){
    U4 ov, rv;
    #pragma unroll
    for(int t=0;t<8;t++){
      int r = rg*16 + half*8 + t;
      float c1 = Cs[r*132 + co]      + bb1;
      float c2 = Cs[r*132 + co + 32] + bb2;
      float c3 = Cs[r*132 + co + 64] + bb3;
      float rr = Cs[r*132 + co + 96] + bbr;
      float sg = 1.f/(1.f+__expf(-c2));
      float v = fmaf(c1, sg, c3);
      v = v>0.f ? v : 0.f;
      s += v; q += v*v;
      ov.s[t] = f2b(v);
      rv.s[t] = f2b(rr);
    }
    int node = node0 + rg*2 + half;
    *(uint4*)(gc1   + (size_t)node*256 + co*8) = ov.v;
    *(uint4*)(resid + (size_t)node*256 + co*8) = rv.v;
  }
  atomicAdd(&redS[co], s); atomicAdd(&redQ[co], q);
  __syncthreads();
  if(tid<32)      atomicAdd(&bn0_sum[tid], redS[tid]);
  else if(tid<64) atomicAdd(&bn0_sq[tid-32], redQ[tid-32]);
}

// ---------------- GAT fc GEMM + bn0 apply at staging + el/er in epilogue ----------------
__global__ __launch_bounds__(256) void k_gemm(const us16* __restrict__ A, const us16* __restrict__ B,
    const float* __restrict__ bn0_sum, const float* __restrict__ bn0_sq,
    const float* __restrict__ bn0g, const float* __restrict__ bn0b,
    const float* __restrict__ attnl, const float* __restrict__ attnr,
    us16* __restrict__ H, float* __restrict__ el, float* __restrict__ er)
{
  __shared__ us16 As[128*72];
  __shared__ us16 Bs[128*72];
  __shared__ float s0a[32], s0b[32];
  const int tid = threadIdx.x;
  const int row0 = blockIdx.x*128, col0 = blockIdx.y*128;
  const int lane = tid&63, wv = tid>>6;
  const int wm = wv&1, wn = wv>>1;
  const int mrow = lane&15, kg = (lane>>4)*8;
  if(tid<32){
    float m = bn0_sum[tid]*(1.f/160000.f);
    float v = bn0_sq[tid]*(1.f/160000.f) - m*m;
    float a = bn0g[tid]*rsqrtf(v + 1e-5f);
    s0a[tid] = a; s0b[tid] = bn0b[tid] - m*a;
  }
  __syncthreads();
  f32x4 acc[4][4] = {};
  for(int k0=0; k0<256; k0+=64){
    #pragma unroll
    for(int i=0;i<4;i++){
      int chunk = i*256 + tid;
      int row = chunk>>3, cc = chunk&7;
      int g = row0 + row;
      int ch = (k0>>3) + cc;              // channel for this uint4
      float a = s0a[ch], b = s0b[ch];
      U4 av; av.v.x=0;av.v.y=0;av.v.z=0;av.v.w=0;
      if(g < NN){
        av.v = *(const uint4*)(A + (size_t)g*256 + k0 + cc*8);
        #pragma unroll
        for(int j=0;j<8;j++) av.s[j] = f2b(fmaf(a, b2f(av.s[j]), b));
      }
      *(uint4*)&As[row*72 + cc*8] = av.v;
      *(uint4*)&Bs[row*72 + cc*8] = *(const uint4*)(B + (size_t)(col0+row)*256 + k0 + cc*8);
    }
    __syncthreads();
    #pragma unroll
    for(int kk=0; kk<64; kk+=32){
      short8 af[4], bfr[4];
      #pragma unroll
      for(int i=0;i<4;i++) af[i]  = *(const short8*)&As[(wm*64 + i*16 + mrow)*72 + kk + kg];
      #pragma unroll
      for(int j=0;j<4;j++) bfr[j] = *(const short8*)&Bs[(wn*64 + j*16 + mrow)*72 + kk + kg];
      #pragma unroll
      for(int i=0;i<4;i++){
        #pragma unroll
        for(int j=0;j<4;j++)
          acc[i][j] = __builtin_amdgcn_mfma_f32_16x16x32_bf16(af[i], bfr[j], acc[i][j], 0, 0, 0);
      }
    }
    __syncthreads();
  }
  // write H
  #pragma unroll
  for(int i=0;i<4;i++){
    #pragma unroll
    for(int j=0;j<4;j++){
      #pragma unroll
      for(int r=0;r<4;r++){
        int g = row0 + wm*64 + i*16 + (lane>>4)*4 + r;
        if(g < NN)
          H[(size_t)g*1024 + col0 + wn*64 + j*16 + (lane&15)] = f2b(acc[i][j][r]);
      }
    }
  }
  // el/er partials: this block covers cols [col0, col0+128) = half of head (col0>>8)
  const int head = col0>>8;
  float alv[4], arv[4];
  #pragma unroll
  for(int j=0;j<4;j++){
    int c = col0 + wn*64 + j*16 + (lane&15);
    alv[j] = attnl[c]; arv[j] = attnr[c];
  }
  float elp[4][4] = {}, erp[4][4] = {};
  #pragma unroll
  for(int i=0;i<4;i++){
    #pragma unroll
    for(int j=0;j<4;j++){
      #pragma unroll
      for(int r=0;r<4;r++){
        elp[i][r] = fmaf(acc[i][j][r], alv[j], elp[i][r]);
        erp[i][r] = fmaf(acc[i][j][r], arv[j], erp[i][r]);
      }
    }
  }
  #pragma unroll
  for(int off=1; off<16; off<<=1){
    #pragma unroll
    for(int i=0;i<4;i++){
      #pragma unroll
      for(int r=0;r<4;r++){
        elp[i][r] += __shfl_xor(elp[i][r], off, 64);
        erp[i][r] += __shfl_xor(erp[i][r], off, 64);
      }
    }
  }
  if((lane&15)==0){
    #pragma unroll
    for(int i=0;i<4;i++){
      #pragma unroll
      for(int r=0;r<4;r++){
        int g = row0 + wm*64 + i*16 + (lane>>4)*4 + r;
        if(g < NN){
          atomicAdd(&el[g*4+head], elp[i][r]);
          atomicAdd(&er[g*4+head], erp[i][r]);
        }
      }
    }
  }
}

// ---------------- scan ----------------
__global__ __launch_bounds__(1024) void k_scan(const int* __restrict__ counts,
                                               int* __restrict__ offsets, int* __restrict__ cursor)
{
  __shared__ int buf[1024];
  const int tid = threadIdx.x;
  const int base = tid*20;
  int loc[20];
  int s = 0;
  #pragma unroll
  for(int j=0;j<20;j++){
    int idx = base+j;
    int v = (idx<NN) ? counts[idx] : 0;
    loc[j] = s; s += v;
  }
  buf[tid] = s;
  __syncthreads();
  for(int off=1; off<1024; off<<=1){
    int t = (tid>=off) ? buf[tid-off] : 0;
    __syncthreads();
    buf[tid] += t;
    __syncthreads();
  }
  int excl = buf[tid] - s;
  #pragma unroll
  for(int j=0;j<20;j++){
    int idx = base+j;
    if(idx<NN){ offsets[idx]=excl+loc[j]; cursor[idx]=excl+loc[j]; }
  }
  if(tid==1023) offsets[NN] = excl + s;
}

// ---------------- scatter + edge scores ----------------
__global__ __launch_bounds__(256) void k_scatter(const int* __restrict__ src, const int* __restrict__ dst,
    int* __restrict__ cursor, int* __restrict__ esrc,
    const float* __restrict__ el, const float* __restrict__ er,
    float* __restrict__ ew)
{
  int e = blockIdx.x*256 + threadIdx.x;
  if(e < NE){
    int s = src[e], d = dst[e];
    int pos = atomicAdd(&cursor[d], 1);
    esrc[pos] = s;
    float4 lv = *(const float4*)(el + s*4);
    float4 rv = *(const float4*)(er + d*4);
    float4 sc;
    sc.x = lv.x+rv.x; sc.x = sc.x>0.f ? sc.x : 0.2f*sc.x;
    sc.y = lv.y+rv.y; sc.y = sc.y>0.f ? sc.y : 0.2f*sc.y;
    sc.z = lv.z+rv.z; sc.z = sc.z>0.f ? sc.z : 0.2f*sc.z;
    sc.w = lv.w+rv.w; sc.w = sc.w>0.f ? sc.w : 0.2f*sc.w;
    *(float4*)(ew + (size_t)pos*4) = sc;
  }
}

// ---------------- GAT aggregate ----------------
__global__ __launch_bounds__(256) void k_agg(
    const int* __restrict__ offsets, const int* __restrict__ esrc,
    const float* __restrict__ ew,
    const us16* __restrict__ H, const float* __restrict__ gbias,
    us16* __restrict__ rst)
{
  const int node = blockIdx.x;
  const int hd = threadIdx.x>>6, lane = threadIdx.x&63;
  const int beg = offsets[node];
  const int deg = offsets[node+1] - beg;
  float m = -3.0e38f;
  for(int i=lane; i<deg; i+=64) m = fmaxf(m, ew[(size_t)(beg+i)*4+hd]);
  #pragma unroll
  for(int o=32;o;o>>=1) m = fmaxf(m, __shfl_xor(m,o,64));
  float den = 0.f;
  for(int i=lane; i<deg; i+=64) den += __expf(ew[(size_t)(beg+i)*4+hd] - m);
  #pragma unroll
  for(int o=32;o;o>>=1) den += __shfl_xor(den,o,64);
  const float inv = (deg>0) ? 1.f/den : 0.f;
  const int half = lane>>5, l32 = lane&31;
  float acc[8] = {};
  #pragma unroll 2
  for(int j=half; j<deg; j+=2){
    float alpha = __expf(ew[(size_t)(beg+j)*4+hd] - m) * inv;
    int sN = esrc[beg+j];
    U4 hv; hv.v = *(const uint4*)(H + (size_t)sN*1024 + hd*256 + l32*8);
    #pragma unroll
    for(int k2=0;k2<8;k2++) acc[k2] = fmaf(alpha, b2f(hv.s[k2]), acc[k2]);
  }
  #pragma unroll
  for(int k2=0;k2<8;k2++) acc[k2] += __shfl_xor(acc[k2], 32, 64);
  if(lane < 32){
    float4 b0 = *(const float4*)(gbias + hd*256 + l32*8);
    float4 b1v = *(const float4*)(gbias + hd*256 + l32*8 + 4);
    float bb[8] = {b0.x,b0.y,b0.z,b0.w,b1v.x,b1v.y,b1v.z,b1v.w};
    U4 ov;
    #pragma unroll
    for(int k2=0;k2<8;k2++){
      float r = acc[k2] + bb[k2];
      r = r>0.f ? r : 0.f;
      ov.s[k2] = f2b(r);
    }
    *(uint4*)(rst + (size_t)node*1024 + hd*256 + l32*8) = ov.v;
  }
}

// ---------------- bn1 column stats ----------------
__global__ __launch_bounds__(256) void k_colstats(const us16* __restrict__ rst,
    float* __restrict__ sum, float* __restrict__ sq)
{
  const int tid = threadIdx.x;
  const int c0 = tid*4;
  int r0 = blockIdx.x*256;
  int r1 = min(r0+256, NN);
  float s[4]={}, q[4]={};
  for(int r=r0; r<r1; r++){
    U2 v; v.v = *(const uint2*)(rst + (size_t)r*1024 + c0);
    #pragma unroll
    for(int k2=0;k2<4;k2++){
      float f = b2f(v.s[k2]);
      s[k2] += f; q[k2] += f*f;
    }
  }
  #pragma unroll
  for(int k2=0;k2<4;k2++){
    atomicAdd(&sum[c0+k2], s[k2]);
    atomicAdd(&sq[c0+k2],  q[k2]);
  }
}

// ---------------- conv2 as MFMA GEMM; rst read direct with bn1 applied at staging ----------------
__global__ __launch_bounds__(256) void k_gemm2(
    const us16* __restrict__ rst, const us16* __restrict__ Wt,
    const float* __restrict__ bn1_sum, const float* __restrict__ bn1_sq,
    const float* __restrict__ bn1g, const float* __restrict__ bn1b,
    const float* __restrict__ b1, const float* __restrict__ b2, const float* __restrict__ b3,
    us16* __restrict__ y2, float* __restrict__ bn2_sum, float* __restrict__ bn2_sq)
{
  __shared__ float smemF[16384];          // 65536 B
  float* s1a = smemF;                     // [t][ci] transposed: 1024
  float* s1b = smemF + 1024;              // 1024
  us16* As = (us16*)(smemF + 2048);       // [16][10][136] = 21760
  us16* Bs = As + 21760;                  // [96][72] = 6912 per-round chunk
  float* Cs = (float*)(smemF + 2048);     // [128][100] epilogue (overlaps As/Bs)
  __shared__ float redS[32], redQ[32];
  const int tid = threadIdx.x;
  if(tid<32){ redS[tid]=0.f; redQ[tid]=0.f; }
  const int row0 = blockIdx.x*128;
  const int node0 = blockIdx.x*16;
  const int lane = tid&63, wv = tid>>6;
  const int wm = wv&1, wn = wv>>1;
  const int mrow = lane&15, kg = (lane>>4)*8;
  // in-block bn1 finalize, stored transposed [t][ci]
  for(int f=tid; f<1024; f+=256){
    float m = bn1_sum[f]*(1.f/20000.f);
    float v = bn1_sq[f]*(1.f/20000.f) - m*m;
    float a = bn1g[f]*rsqrtf(v + 1e-5f);
    int l = (f&7)*128 + (f>>3);
    s1a[l] = a; s1b[l] = bn1b[f] - m*a;
  }
  // zero halo slots: 16 x {0,9} x 128
  for(int idx=tid; idx<4096; idx+=256){
    int n = idx>>8, rem = idx&255, slot = (rem>>7)*9, ci = rem&127;
    As[n*1360 + slot*136 + ci] = 0;
  }
  __syncthreads();
  // stage A: rst[node][ci*8+t] -> bn1 -> As[n][t+1][ci]
  #pragma unroll
  for(int i=0;i<8;i++){
    int idx = i*256 + tid;                // 2048 uint4
    int n = idx>>7, ci = idx&127;
    U4 in; in.v = *(const uint4*)(rst + (size_t)(node0+n)*1024 + ci*8);
    us16* p = &As[n*1360 + 136 + ci];
    #pragma unroll
    for(int t=0;t<8;t++){
      float a = s1a[t*128+ci], b = s1b[t*128+ci];
      p[t*136] = f2b(fmaf(a, b2f(in.s[t]), b));
    }
  }
  f32x4 acc[4][3] = {};
  for(int rd=0; rd<6; rd++){
    const int s = rd>>1, kc = rd&1;
    __syncthreads();                      // protect Bs WAR + first-round A visibility
    #pragma unroll
    for(int i=0;i<3;i++){
      int chunk = i*256 + tid;            // 768 uint4
      int brow = chunk>>3, cc = chunk&7;
      *(uint4*)&Bs[brow*72 + cc*8] =
        *(const uint4*)(Wt + s*12288 + brow*128 + kc*64 + cc*8);
    }
    __syncthreads();
    #pragma unroll
    for(int kk=0; kk<64; kk+=32){
      short8 af[4], bfr[3];
      #pragma unroll
      for(int i=0;i<4;i++){
        int r = wm*64 + i*16 + mrow;
        af[i] = *(const short8*)&As[(r>>3)*1360 + ((r&7)+s)*136 + kc*64 + kk + kg];
      }
      #pragma unroll
      for(int j=0;j<3;j++)
        bfr[j] = *(const short8*)&Bs[(wn*48 + j*16 + mrow)*72 + kk + kg];
      #pragma unroll
      for(int i=0;i<4;i++){
        #pragma unroll
        for(int j=0;j<3;j++)
          acc[i][j] = __builtin_amdgcn_mfma_f32_16x16x32_bf16(af[i], bfr[j], acc[i][j], 0, 0, 0);
      }
    }
  }
  __syncthreads();
  #pragma unroll
  for(int i=0;i<4;i++){
    #pragma unroll
    for(int j=0;j<3;j++){
      #pragma unroll
      for(int r=0;r<4;r++)
        Cs[(wm*64 + i*16 + (lane>>4)*4 + r)*100 + wn*48 + j*16 + (lane&15)] = acc[i][j][r];
    }
  }
  __syncthreads();
  const int co = tid&31, rg = tid>>5;
  const float bb1=b1[co], bb2=b2[co], bb3=b3[co];
  float s=0.f, q=0.f;
  #pragma unroll
  for(int half=0; half<2; half++){
    U4 ov;
    #pragma unroll
    for(int t=0;t<8;t++){
      int r = rg*16 + half*8 + t;
      float c1 = Cs[r*100 + co]      + bb1;
      float c2 = Cs[r*100 + co + 32] + bb2;
      float c3 = Cs[r*100 + co + 64] + bb3;
      float sg = 1.f/(1.f+__expf(-c2));
      float v = fmaf(c1, sg, c3);
      v = v>0.f ? v : 0.f;
      s += v; q += v*v;
      ov.s[t] = f2b(v);
    }
    int node = node0 + rg*2 + half;
    *(uint4*)(y2 + (size_t)node*256 + co*8) = ov.v;
  }
  atomicAdd(&redS[co], s); atomicAdd(&redQ[co], q);
  __syncthreads();
  if(tid<32)      atomicAdd(&bn2_sum[tid], redS[tid]);
  else if(tid<64) atomicAdd(&bn2_sq[tid-32], redQ[tid-32]);
}

// ---------------- final: bn2 finalize in-block + residual + relu -> fp32 out ----------------
__global__ __launch_bounds__(256) void k_final(const us16* __restrict__ y2,
    const float* __restrict__ bn2_sum, const float* __restrict__ bn2_sq,
    const float* __restrict__ bn2g, const float* __restrict__ bn2b,
    const us16* __restrict__ resid, float* __restrict__ out)
{
  __shared__ float fa[32], fb[32];
  const int tid = threadIdx.x;
  if(tid<32){
    float m = bn2_sum[tid]*(1.f/160000.f);
    float v = bn2_sq[tid]*(1.f/160000.f) - m*m;
    float a = bn2g[tid]*rsqrtf(v + 1e-5f);
    fa[tid] = a; fb[tid] = bn2b[tid] - m*a;
  }
  __syncthreads();
  size_t base = ((size_t)blockIdx.x*256 + tid)*8;
  int ch = (int)((base>>3)&31);
  float a = fa[ch], b = fb[ch];
  U4 yv, rv;
  yv.v = *(const uint4*)(y2+base);
  rv.v = *(const uint4*)(resid+base);
  float4 o0, o1;
  float vv[8];
  #pragma unroll
  for(int j=0;j<8;j++){
    float v = fmaf(a, b2f(yv.s[j]), b) + b2f(rv.s[j]);
    vv[j] = v>0.f ? v : 0.f;
  }
  o0.x=vv[0]; o0.y=vv[1]; o0.z=vv[2]; o0.w=vv[3];
  o1.x=vv[4]; o1.y=vv[5]; o1.z=vv[6]; o1.w=vv[7];
  *(float4*)(out+base)   = o0;
  *(float4*)(out+base+4) = o1;
}

extern "C" void kernel_launch(void* const* d_in, const int* in_sizes, int n_in,
                              void* d_out, int out_size, void* d_ws, size_t ws_size,
                              hipStream_t stream)
{
  const float* X    = (const float*)d_in[0];
  const int*  src   = (const int*)d_in[1];
  const int*  dst   = (const int*)d_in[2];
  const float* rp_w = (const float*)d_in[3];
  const float* rp_b = (const float*)d_in[4];
  const float* g1w1 = (const float*)d_in[5];
  const float* g1b1 = (const float*)d_in[6];
  const float* g1w2 = (const float*)d_in[7];
  const float* g1b2 = (const float*)d_in[8];
  const float* g1w3 = (const float*)d_in[9];
  const float* g1b3 = (const float*)d_in[10];
  const float* bn0g = (const float*)d_in[11];
  const float* bn0b = (const float*)d_in[12];
  const float* gatw = (const float*)d_in[13];
  const float* attnl= (const float*)d_in[14];
  const float* attnr= (const float*)d_in[15];
  const float* gbias= (const float*)d_in[16];
  const float* bn1g = (const float*)d_in[17];
  const float* bn1b = (const float*)d_in[18];
  const float* g2w1 = (const float*)d_in[19];
  const float* g2b1 = (const float*)d_in[20];
  const float* g2w2 = (const float*)d_in[21];
  const float* g2b2 = (const float*)d_in[22];
  const float* g2w3 = (const float*)d_in[23];
  const float* g2b3 = (const float*)d_in[24];
  const float* bn2g = (const float*)d_in[25];
  const float* bn2b = (const float*)d_in[26];
  float* out = (float*)d_out;
  (void)in_sizes; (void)n_in; (void)out_size; (void)ws_size;

  char* w = (char*)d_ws;
  float* bn0_sum = (float*)w;                 // 32
  float* bn0_sq  = bn0_sum + 32;              // 32
  float* bn1_sum = bn0_sum + 64;              // 1024
  float* bn1_sq  = bn1_sum + 1024;            // 1024
  float* bn2_sum = bn1_sq  + 1024;            // 32
  float* bn2_sq  = bn2_sum + 32;              // 32
  int*   counts  = (int*)(bn2_sq + 32);       // 20000
  float* el      = (float*)(counts + NN);     // 80000  (zeroed: el/er accumulated atomically)
  float* er      = el + NN*4;                 // 80000
  size_t zeroBytes = (size_t)((char*)(er + NN*4) - w);   // ~712 KB
  int*   offsets = (int*)(er + NN*4);         // 20004
  int*   cursor  = offsets + 20004;           // 20000
  int*   esrc    = cursor + NN;               // 320000
  float* ew      = (float*)(esrc + NE);       // 1,280,000
  us16*  wb      = (us16*)(ew + (size_t)NE*4);// 262144
  us16*  resid   = wb + 262144;               // 5,120,000
  us16*  gc1     = resid + 5120000;           // 5,120,000 (raw gated conv1; bn0 applied in k_gemm)
  us16*  h       = gc1   + 5120000;           // 20,480,000
  us16*  rst     = h     + 20480000;          // 20,480,000
  us16*  Wt      = rst   + 20480000;          // 36,864
  us16*  Wt1     = Wt    + 36864;             // 12,288
  us16*  y2      = gc1;                       // alias: gc1 dead after k_gemm

  hipMemsetAsync(d_ws, 0, zeroBytes, stream);
  k_misc<<<1698, 256, 0, stream>>>(gatw, wb, g2w1, g2w2, g2w3, Wt,
                                   g1w1, g1w2, g1w3, rp_w, Wt1, dst, counts);
  k_gemm1<<<1250, 256, 0, stream>>>(X, Wt1, g1b1, g1b2, g1b3, rp_b,
                                    gc1, resid, bn0_sum, bn0_sq);
  k_gemm<<<dim3(157, 8), 256, 0, stream>>>(gc1, wb, bn0_sum, bn0_sq, bn0g, bn0b,
                                           attnl, attnr, h, el, er);
  k_scan<<<1, 1024, 0, stream>>>(counts, offsets, cursor);
  k_scatter<<<1250, 256, 0, stream>>>(src, dst, cursor, esrc, el, er, ew);
  k_agg<<<NN, 256, 0, stream>>>(offsets, esrc, ew, h, gbias, rst);
  k_colstats<<<79, 256, 0, stream>>>(rst, bn1_sum, bn1_sq);
  k_gemm2<<<1250, 256, 0, stream>>>(rst, Wt, bn1_sum, bn1_sq, bn1g, bn1b,
                                    g2b1, g2b2, g2b3, y2, bn2_sum, bn2_sq);
  k_final<<<2500, 256, 0, stream>>>(y2, bn2_sum, bn2_sq, bn2g, bn2b, resid, out);
}

// Round 8
// 457.594 us; speedup vs baseline: 1.9383x; 1.1424x over previous
//
#include <hip/hip_runtime.h>
#include <stdint.h>

#define NN 20000
#define NE 320000

typedef unsigned short us16;
typedef __attribute__((ext_vector_type(8))) short short8;
typedef __attribute__((ext_vector_type(4))) float f32x4;

union U4 { uint4 v; us16 s[8]; unsigned u[4]; };
union U2 { uint2 v; us16 s[4]; };

__device__ __forceinline__ float b2f(us16 u){ return __uint_as_float(((unsigned)u)<<16); }
__device__ __forceinline__ us16 f2b(float f){
  unsigned u = __float_as_uint(f);
  u += 0x7fffu + ((u>>16)&1u);
  return (us16)(u>>16);
}

// ---------------- merged misc: gat_w cvt + conv2 wprep + conv1 wprep + wl/wr + hist ----------------
__global__ __launch_bounds__(256) void k_misc(
    const float* __restrict__ gatw, us16* __restrict__ Wb,
    const float* __restrict__ w1, const float* __restrict__ w2, const float* __restrict__ w3,
    us16* __restrict__ Wt,
    const float* __restrict__ c1w1, const float* __restrict__ c1w2, const float* __restrict__ c1w3,
    const float* __restrict__ rp_w, us16* __restrict__ Wt1,
    const float* __restrict__ attnl, const float* __restrict__ attnr,
    float* __restrict__ wl, float* __restrict__ wr,
    const int* __restrict__ dst, int* __restrict__ counts)
{
  const int b = blockIdx.x, tid = threadIdx.x;
  if(b < 256){
    int i = b*256 + tid;
    float4 v = *(const float4*)(gatw + (size_t)i*4);
    U2 o;
    o.s[0]=f2b(v.x); o.s[1]=f2b(v.y); o.s[2]=f2b(v.z); o.s[3]=f2b(v.w);
    *(uint2*)(Wb + (size_t)i*4) = o.v;
  } else if(b < 400){
    int i = (b-256)*256 + tid;       // 36864: Wt[s][co3(96)][ci(128)]
    int s = i/12288, rem = i%12288;
    int co3 = rem>>7, ci = rem&127;
    const float* w = (co3<32) ? w1 : (co3<64) ? w2 : w3;
    Wt[i] = f2b(w[(co3&31)*384 + ci*3 + s]);
  } else if(b < 448){
    int i = (b-400)*256 + tid;       // 12288: Wt1[s][co3(128)][ci(32)]
    int s = i>>12, rem = i&4095;
    int co3 = rem>>5, ci = rem&31;
    float v;
    if(co3 < 96){
      const float* w = (co3<32) ? c1w1 : (co3<64) ? c1w2 : c1w3;
      v = w[(co3&31)*96 + ci*3 + s];
    } else {
      v = (s==1) ? rp_w[(co3-96)*32 + ci] : 0.f;
    }
    Wt1[i] = f2b(v);
  } else if(b < 456){
    // wl/wr[hd][k] = sum_f attn[hd][f] * W[hd*256+f][k]
    int bb = b-448;
    int sel = bb>>2, hd = bb&3, k = tid;
    const float* attn = sel ? attnr : attnl;
    float s = 0.f;
    for(int f=0; f<256; f++)
      s = fmaf(attn[hd*256+f], gatw[(size_t)(hd*256+f)*256 + k], s);
    (sel ? wr : wl)[hd*256+k] = s;
  } else {
    int e = (b-456)*256 + tid;
    if(e < NE) atomicAdd(&counts[dst[e]], 1);
  }
}

// ---------------- conv1 (+residual k1) as MFMA GEMM, X read direct (fp32) ----------------
__global__ __launch_bounds__(256) void k_gemm1(
    const float* __restrict__ X, const us16* __restrict__ Wt1,
    const float* __restrict__ b1, const float* __restrict__ b2, const float* __restrict__ b3,
    const float* __restrict__ rp_b,
    us16* __restrict__ gc1, us16* __restrict__ resid,
    float* __restrict__ bn0_sum, float* __restrict__ bn0_sq)
{
  __shared__ float smemF[16896];
  us16* As = (us16*)smemF;                // [16][10][40]
  us16* Bs = As + 6400;                   // [3][128][40]
  float* Cs = smemF;                      // [128][132]
  __shared__ float redS[32], redQ[32];
  const int tid = threadIdx.x;
  if(tid<32){ redS[tid]=0.f; redQ[tid]=0.f; }
  const int node0 = blockIdx.x*16;
  const int lane = tid&63, wv = tid>>6;
  const int wm = wv&1, wn = wv>>1;
  const int mrow = lane&15, kg = (lane>>4)*8;
  for(int idx=tid; idx<1024; idx+=256){
    int n = idx>>6, rem = idx&63, slot = (rem>>5)*9, ci = rem&31;
    As[n*400 + slot*40 + ci] = 0;
  }
  #pragma unroll
  for(int i=0;i<4;i++){
    int idx = i*256 + tid;
    int n = idx>>6, rem = idx&63, ci = rem>>1, tq = rem&1;
    float4 xv = *(const float4*)(X + (size_t)(node0+n)*256 + ci*8 + tq*4);
    us16* p = &As[n*400 + (tq*4+1)*40 + ci];
    p[0]   = f2b(xv.x);
    p[40]  = f2b(xv.y);
    p[80]  = f2b(xv.z);
    p[120] = f2b(xv.w);
  }
  #pragma unroll
  for(int i=0;i<6;i++){
    int c = i*256 + tid;
    int s = c>>9, rem = c&511, co = rem>>2, cq = rem&3;
    *(uint4*)&Bs[s*5120 + co*40 + cq*8] = *(const uint4*)(Wt1 + s*4096 + co*32 + cq*8);
  }
  __syncthreads();
  f32x4 acc[4][4] = {};
  #pragma unroll
  for(int s=0; s<3; s++){
    short8 af[4], bfr[4];
    #pragma unroll
    for(int i=0;i<4;i++){
      int r = wm*64 + i*16 + mrow;
      af[i] = *(const short8*)&As[(r>>3)*400 + ((r&7)+s)*40 + kg];
    }
    #pragma unroll
    for(int j=0;j<4;j++)
      bfr[j] = *(const short8*)&Bs[s*5120 + (wn*64 + j*16 + mrow)*40 + kg];
    #pragma unroll
    for(int i=0;i<4;i++){
      #pragma unroll
      for(int j=0;j<4;j++)
        acc[i][j] = __builtin_amdgcn_mfma_f32_16x16x32_bf16(af[i], bfr[j], acc[i][j], 0, 0, 0);
    }
  }
  __syncthreads();
  #pragma unroll
  for(int i=0;i<4;i++){
    #pragma unroll
    for(int j=0;j<4;j++){
      #pragma unroll
      for(int r=0;r<4;r++)
        Cs[(wm*64 + i*16 + (lane>>4)*4 + r)*132 + wn*64 + j*16 + (lane&15)] = acc[i][j][r];
    }
  }
  __syncthreads();
  const int co = tid&31, rg = tid>>5;
  const float bb1=b1[co], bb2=b2[co], bb3=b3[co], bbr=rp_b[co];
  float s=0.f, q=0.f;
  #pragma unroll
  for(int half=0; half<2; half++){
    U4 ov, rv;
    #pragma unroll
    for(int t=0;t<8;t++){
      int r = rg*16 + half*8 + t;
      float c1 = Cs[r*132 + co]      + bb1;
      float c2 = Cs[r*132 + co + 32] + bb2;
      float c3 = Cs[r*132 + co + 64] + bb3;
      float rr = Cs[r*132 + co + 96] + bbr;
      float sg = 1.f/(1.f+__expf(-c2));
      float v = fmaf(c1, sg, c3);
      v = v>0.f ? v : 0.f;
      s += v; q += v*v;
      ov.s[t] = f2b(v);
      rv.s[t] = f2b(rr);
    }
    int node = node0 + rg*2 + half;
    *(uint4*)(gc1   + (size_t)node*256 + co*8) = ov.v;
    *(uint4*)(resid + (size_t)node*256 + co*8) = rv.v;
  }
  atomicAdd(&redS[co], s); atomicAdd(&redQ[co], q);
  __syncthreads();
  if(tid<32)      atomicAdd(&bn0_sum[tid], redS[tid]);
  else if(tid<64) atomicAdd(&bn0_sq[tid-32], redQ[tid-32]);
}

// ---------------- el/er directly from gc1 (bn0 folded): wave per node ----------------
__global__ __launch_bounds__(256) void k_eler2(const us16* __restrict__ gc1,
    const float* __restrict__ bn0_sum, const float* __restrict__ bn0_sq,
    const float* __restrict__ bn0g, const float* __restrict__ bn0b,
    const float* __restrict__ wl, const float* __restrict__ wr,
    float* __restrict__ el, float* __restrict__ er)
{
  __shared__ float sa[32], sb[32];
  const int tid = threadIdx.x;
  if(tid<32){
    float m = bn0_sum[tid]*(1.f/160000.f);
    float v = bn0_sq[tid]*(1.f/160000.f) - m*m;
    float a = bn0g[tid]*rsqrtf(v + 1e-5f);
    sa[tid] = a; sb[tid] = bn0b[tid] - m*a;
  }
  __syncthreads();
  const int wv = tid>>6, lane = tid&63;
  const int node = blockIdx.x*4 + wv;
  U2 g; g.v = *(const uint2*)(gc1 + (size_t)node*256 + lane*4);
  const float a = sa[lane>>1], b = sb[lane>>1];
  float xv[4];
  #pragma unroll
  for(int j=0;j<4;j++) xv[j] = fmaf(a, b2f(g.s[j]), b);
  float res[8];
  #pragma unroll
  for(int hd=0; hd<4; hd++){
    float4 lv = *(const float4*)(wl + hd*256 + lane*4);
    float4 rv = *(const float4*)(wr + hd*256 + lane*4);
    res[hd]   = xv[0]*lv.x + xv[1]*lv.y + xv[2]*lv.z + xv[3]*lv.w;
    res[4+hd] = xv[0]*rv.x + xv[1]*rv.y + xv[2]*rv.z + xv[3]*rv.w;
  }
  #pragma unroll
  for(int o=32;o;o>>=1){
    #pragma unroll
    for(int k=0;k<8;k++) res[k] += __shfl_xor(res[k], o, 64);
  }
  if(lane==0){
    #pragma unroll
    for(int hd=0;hd<4;hd++){ el[node*4+hd]=res[hd]; er[node*4+hd]=res[4+hd]; }
  }
}

// ---------------- scan ----------------
__global__ __launch_bounds__(1024) void k_scan(const int* __restrict__ counts,
                                               int* __restrict__ offsets, int* __restrict__ cursor)
{
  __shared__ int buf[1024];
  const int tid = threadIdx.x;
  const int base = tid*20;
  int loc[20];
  int s = 0;
  #pragma unroll
  for(int j=0;j<20;j++){
    int idx = base+j;
    int v = (idx<NN) ? counts[idx] : 0;
    loc[j] = s; s += v;
  }
  buf[tid] = s;
  __syncthreads();
  for(int off=1; off<1024; off<<=1){
    int t = (tid>=off) ? buf[tid-off] : 0;
    __syncthreads();
    buf[tid] += t;
    __syncthreads();
  }
  int excl = buf[tid] - s;
  #pragma unroll
  for(int j=0;j<20;j++){
    int idx = base+j;
    if(idx<NN){ offsets[idx]=excl+loc[j]; cursor[idx]=excl+loc[j]; }
  }
  if(tid==1023) offsets[NN] = excl + s;
}

// ---------------- scatter + edge scores ----------------
__global__ __launch_bounds__(256) void k_scatter(const int* __restrict__ src, const int* __restrict__ dst,
    int* __restrict__ cursor, int* __restrict__ esrc,
    const float* __restrict__ el, const float* __restrict__ er,
    float* __restrict__ ew)
{
  int e = blockIdx.x*256 + threadIdx.x;
  if(e < NE){
    int s = src[e], d = dst[e];
    int pos = atomicAdd(&cursor[d], 1);
    esrc[pos] = s;
    float4 lv = *(const float4*)(el + s*4);
    float4 rv = *(const float4*)(er + d*4);
    float4 sc;
    sc.x = lv.x+rv.x; sc.x = sc.x>0.f ? sc.x : 0.2f*sc.x;
    sc.y = lv.y+rv.y; sc.y = sc.y>0.f ? sc.y : 0.2f*sc.y;
    sc.z = lv.z+rv.z; sc.z = sc.z>0.f ? sc.z : 0.2f*sc.z;
    sc.w = lv.w+rv.w; sc.w = sc.w>0.f ? sc.w : 0.2f*sc.w;
    *(float4*)(ew + (size_t)pos*4) = sc;
  }
}

// ---------------- GAT aggregate in x-space: Axg[hd][node][256] = bn0(sum alpha_e gc1[src]) ----------------
__global__ __launch_bounds__(256) void k_agg2(
    const int* __restrict__ offsets, const int* __restrict__ esrc,
    const float* __restrict__ ew, const us16* __restrict__ gc1,
    const float* __restrict__ bn0_sum, const float* __restrict__ bn0_sq,
    const float* __restrict__ bn0g, const float* __restrict__ bn0b,
    us16* __restrict__ Axg)
{
  __shared__ float sa[32], sb[32];
  __shared__ float mh[4], dh[4];
  __shared__ float red[4096];           // [wv][hd][k(8)][l32(32)]
  const int tid = threadIdx.x;
  if(tid<32){
    float m = bn0_sum[tid]*(1.f/160000.f);
    float v = bn0_sq[tid]*(1.f/160000.f) - m*m;
    float a = bn0g[tid]*rsqrtf(v + 1e-5f);
    sa[tid] = a; sb[tid] = bn0b[tid] - m*a;
  }
  const int wv = tid>>6, lane = tid&63;
  const int half = lane>>5, l32 = lane&31;
  const int node = blockIdx.x;
  const int beg = offsets[node];
  const int deg = offsets[node+1] - beg;
  // phase 1: wave wv computes m/den for head wv over contiguous scores
  float m = -3.0e38f;
  for(int i=lane; i<deg; i+=64) m = fmaxf(m, ew[(size_t)(beg+i)*4+wv]);
  #pragma unroll
  for(int o=32;o;o>>=1) m = fmaxf(m, __shfl_xor(m,o,64));
  float den = 0.f;
  for(int i=lane; i<deg; i+=64) den += __expf(ew[(size_t)(beg+i)*4+wv] - m);
  #pragma unroll
  for(int o=32;o;o>>=1) den += __shfl_xor(den,o,64);
  if(lane==0){ mh[wv]=m; dh[wv]=(den>0.f)?1.f/den:0.f; }
  __syncthreads();
  const float m0=mh[0],m1=mh[1],m2=mh[2],m3=mh[3];
  const float i0=dh[0],i1=dh[1],i2=dh[2],i3=dh[3];
  float acc[4][8] = {};
  for(int j = wv*2+half; j<deg; j+=8){
    int pos = beg+j;
    float4 w4 = *(const float4*)(ew + (size_t)pos*4);
    float a0 = __expf(w4.x-m0)*i0;
    float a1 = __expf(w4.y-m1)*i1;
    float a2 = __expf(w4.z-m2)*i2;
    float a3 = __expf(w4.w-m3)*i3;
    int sN = esrc[pos];
    U4 hv; hv.v = *(const uint4*)(gc1 + (size_t)sN*256 + l32*8);
    #pragma unroll
    for(int k=0;k<8;k++){
      float x = b2f(hv.s[k]);
      acc[0][k] = fmaf(a0, x, acc[0][k]);
      acc[1][k] = fmaf(a1, x, acc[1][k]);
      acc[2][k] = fmaf(a2, x, acc[2][k]);
      acc[3][k] = fmaf(a3, x, acc[3][k]);
    }
  }
  #pragma unroll
  for(int hd=0;hd<4;hd++)
    #pragma unroll
    for(int k=0;k<8;k++) acc[hd][k] += __shfl_xor(acc[hd][k], 32, 64);
  if(lane<32){
    #pragma unroll
    for(int hd=0;hd<4;hd++)
      #pragma unroll
      for(int k=0;k<8;k++)
        red[((wv*4+hd)*8 + k)*32 + l32] = acc[hd][k];
  }
  __syncthreads();
  // final: thread handles 4 consecutive outputs o = tid*4 (o = hd*256 + f)
  const float ind = (deg>0) ? 1.f : 0.f;
  int o = tid*4;
  int hd = o>>8, f0 = o&255;
  int lr = f0>>3, k0 = f0&7;
  U2 ov;
  #pragma unroll
  for(int kk=0;kk<4;kk++){
    float s = 0.f;
    #pragma unroll
    for(int w=0;w<4;w++) s += red[((w*4+hd)*8 + k0+kk)*32 + lr];
    int feat = f0 + kk;
    int ch = feat>>3;
    ov.s[kk] = f2b(fmaf(sa[ch], s, sb[ch]*ind));
  }
  *(uint2*)(Axg + ((size_t)hd*NN + node)*256 + f0) = ov.v;
}

// ---------------- rst GEMM: rst[d][hd*256+c] = relu(Axg[hd][d] @ Wb_hd^T + gbias) ----------------
__global__ __launch_bounds__(256) void k_gemm3(const us16* __restrict__ Axg, const us16* __restrict__ Wb,
    const float* __restrict__ gbias, us16* __restrict__ rst)
{
  __shared__ us16 As[128*72];
  __shared__ us16 Bs[128*72];
  const int tid = threadIdx.x;
  const int row0 = blockIdx.x*128;
  const int cb   = blockIdx.y*128;      // col within head
  const int hd   = blockIdx.z;
  const us16* A = Axg + (size_t)hd*NN*256;
  const us16* B = Wb  + (size_t)(hd*256 + cb)*256;
  const int lane = tid&63, wv = tid>>6;
  const int wm = wv&1, wn = wv>>1;
  const int mrow = lane&15, kg = (lane>>4)*8;
  f32x4 acc[4][4] = {};
  for(int k0=0; k0<256; k0+=64){
    #pragma unroll
    for(int i=0;i<4;i++){
      int chunk = i*256 + tid;
      int row = chunk>>3, cc = chunk&7;
      int g = row0 + row;
      uint4 av; av.x=0;av.y=0;av.z=0;av.w=0;
      if(g < NN) av = *(const uint4*)(A + (size_t)g*256 + k0 + cc*8);
      *(uint4*)&As[row*72 + cc*8] = av;
      *(uint4*)&Bs[row*72 + cc*8] = *(const uint4*)(B + (size_t)row*256 + k0 + cc*8);
    }
    __syncthreads();
    #pragma unroll
    for(int kk=0; kk<64; kk+=32){
      short8 af[4], bfr[4];
      #pragma unroll
      for(int i=0;i<4;i++) af[i]  = *(const short8*)&As[(wm*64 + i*16 + mrow)*72 + kk + kg];
      #pragma unroll
      for(int j=0;j<4;j++) bfr[j] = *(const short8*)&Bs[(wn*64 + j*16 + mrow)*72 + kk + kg];
      #pragma unroll
      for(int i=0;i<4;i++){
        #pragma unroll
        for(int j=0;j<4;j++)
          acc[i][j] = __builtin_amdgcn_mfma_f32_16x16x32_bf16(af[i], bfr[j], acc[i][j], 0, 0, 0);
      }
    }
    __syncthreads();
  }
  float gb[4];
  #pragma unroll
  for(int j=0;j<4;j++)
    gb[j] = gbias[hd*256 + cb + wn*64 + j*16 + (lane&15)];
  #pragma unroll
  for(int i=0;i<4;i++){
    #pragma unroll
    for(int j=0;j<4;j++){
      #pragma unroll
      for(int r=0;r<4;r++){
        int g = row0 + wm*64 + i*16 + (lane>>4)*4 + r;
        if(g < NN){
          float v = acc[i][j][r] + gb[j];
          v = v>0.f ? v : 0.f;
          rst[(size_t)g*1024 + hd*256 + cb + wn*64 + j*16 + (lane&15)] = f2b(v);
        }
      }
    }
  }
}

// ---------------- bn1 column stats (313 blocks x 64 rows) ----------------
__global__ __launch_bounds__(256) void k_colstats(const us16* __restrict__ rst,
    float* __restrict__ sum, float* __restrict__ sq)
{
  const int tid = threadIdx.x;
  const int c0 = tid*4;
  int r0 = blockIdx.x*64;
  int r1 = min(r0+64, NN);
  float s[4]={}, q[4]={};
  for(int r=r0; r<r1; r++){
    U2 v; v.v = *(const uint2*)(rst + (size_t)r*1024 + c0);
    #pragma unroll
    for(int k2=0;k2<4;k2++){
      float f = b2f(v.s[k2]);
      s[k2] += f; q[k2] += f*f;
    }
  }
  #pragma unroll
  for(int k2=0;k2<4;k2++){
    atomicAdd(&sum[c0+k2], s[k2]);
    atomicAdd(&sq[c0+k2],  q[k2]);
  }
}

// ---------------- conv2 as MFMA GEMM; rst direct, bn1 at staging ----------------
__global__ __launch_bounds__(256) void k_gemm2(
    const us16* __restrict__ rst, const us16* __restrict__ Wt,
    const float* __restrict__ bn1_sum, const float* __restrict__ bn1_sq,
    const float* __restrict__ bn1g, const float* __restrict__ bn1b,
    const float* __restrict__ b1, const float* __restrict__ b2, const float* __restrict__ b3,
    us16* __restrict__ y2, float* __restrict__ bn2_sum, float* __restrict__ bn2_sq)
{
  __shared__ float smemF[16384];
  float* s1a = smemF;
  float* s1b = smemF + 1024;
  us16* As = (us16*)(smemF + 2048);       // [16][10][136]
  us16* Bs = As + 21760;                  // [96][72]
  float* Cs = (float*)(smemF + 2048);     // [128][100]
  __shared__ float redS[32], redQ[32];
  const int tid = threadIdx.x;
  if(tid<32){ redS[tid]=0.f; redQ[tid]=0.f; }
  const int node0 = blockIdx.x*16;
  const int lane = tid&63, wv = tid>>6;
  const int wm = wv&1, wn = wv>>1;
  const int mrow = lane&15, kg = (lane>>4)*8;
  for(int f=tid; f<1024; f+=256){
    float m = bn1_sum[f]*(1.f/20000.f);
    float v = bn1_sq[f]*(1.f/20000.f) - m*m;
    float a = bn1g[f]*rsqrtf(v + 1e-5f);
    int l = (f&7)*128 + (f>>3);
    s1a[l] = a; s1b[l] = bn1b[f] - m*a;
  }
  for(int idx=tid; idx<4096; idx+=256){
    int n = idx>>8, rem = idx&255, slot = (rem>>7)*9, ci = rem&127;
    As[n*1360 + slot*136 + ci] = 0;
  }
  __syncthreads();
  #pragma unroll
  for(int i=0;i<8;i++){
    int idx = i*256 + tid;
    int n = idx>>7, ci = idx&127;
    U4 in; in.v = *(const uint4*)(rst + (size_t)(node0+n)*1024 + ci*8);
    us16* p = &As[n*1360 + 136 + ci];
    #pragma unroll
    for(int t=0;t<8;t++){
      float a = s1a[t*128+ci], b = s1b[t*128+ci];
      p[t*136] = f2b(fmaf(a, b2f(in.s[t]), b));
    }
  }
  f32x4 acc[4][3] = {};
  for(int rd=0; rd<6; rd++){
    const int s = rd>>1, kc = rd&1;
    __syncthreads();
    #pragma unroll
    for(int i=0;i<3;i++){
      int chunk = i*256 + tid;
      int brow = chunk>>3, cc = chunk&7;
      *(uint4*)&Bs[brow*72 + cc*8] =
        *(const uint4*)(Wt + s*12288 + brow*128 + kc*64 + cc*8);
    }
    __syncthreads();
    #pragma unroll
    for(int kk=0; kk<64; kk+=32){
      short8 af[4], bfr[3];
      #pragma unroll
      for(int i=0;i<4;i++){
        int r = wm*64 + i*16 + mrow;
        af[i] = *(const short8*)&As[(r>>3)*1360 + ((r&7)+s)*136 + kc*64 + kk + kg];
      }
      #pragma unroll
      for(int j=0;j<3;j++)
        bfr[j] = *(const short8*)&Bs[(wn*48 + j*16 + mrow)*72 + kk + kg];
      #pragma unroll
      for(int i=0;i<4;i++){
        #pragma unroll
        for(int j=0;j<3;j++)
          acc[i][j] = __builtin_amdgcn_mfma_f32_16x16x32_bf16(af[i], bfr[j], acc[i][j], 0, 0, 0);
      }
    }
  }
  __syncthreads();
  #pragma unroll
  for(int i=0;i<4;i++){
    #pragma unroll
    for(int j=0;j<3;j++){
      #pragma unroll
      for(int r=0;r<4;r++)
        Cs[(wm*64 + i*16 + (lane>>4)*4 + r)*100 + wn*48 + j*16 + (lane&15)] = acc[i][j][r];
    }
  }
  __syncthreads();
  const int co = tid&31, rg = tid>>5;
  const float bb1=b1[co], bb2=b2[co], bb3=b3[co];
  float s=0.f, q=0.f;
  #pragma unroll
  for(int half=0; half<2; half++){
    U4 ov;
    #pragma unroll
    for(int t=0;t<8;t++){
      int r = rg*16 + half*8 + t;
      float c1 = Cs[r*100 + co]      + bb1;
      float c2 = Cs[r*100 + co + 32] + bb2;
      float c3 = Cs[r*100 + co + 64] + bb3;
      float sg = 1.f/(1.f+__expf(-c2));
      float v = fmaf(c1, sg, c3);
      v = v>0.f ? v : 0.f;
      s += v; q += v*v;
      ov.s[t] = f2b(v);
    }
    int node = node0 + rg*2 + half;
    *(uint4*)(y2 + (size_t)node*256 + co*8) = ov.v;
  }
  atomicAdd(&redS[co], s); atomicAdd(&redQ[co], q);
  __syncthreads();
  if(tid<32)      atomicAdd(&bn2_sum[tid], redS[tid]);
  else if(tid<64) atomicAdd(&bn2_sq[tid-32], redQ[tid-32]);
}

// ---------------- final ----------------
__global__ __launch_bounds__(256) void k_final(const us16* __restrict__ y2,
    const float* __restrict__ bn2_sum, const float* __restrict__ bn2_sq,
    const float* __restrict__ bn2g, const float* __restrict__ bn2b,
    const us16* __restrict__ resid, float* __restrict__ out)
{
  __shared__ float fa[32], fb[32];
  const int tid = threadIdx.x;
  if(tid<32){
    float m = bn2_sum[tid]*(1.f/160000.f);
    float v = bn2_sq[tid]*(1.f/160000.f) - m*m;
    float a = bn2g[tid]*rsqrtf(v + 1e-5f);
    fa[tid] = a; fb[tid] = bn2b[tid] - m*a;
  }
  __syncthreads();
  size_t base = ((size_t)blockIdx.x*256 + tid)*8;
  int ch = (int)((base>>3)&31);
  float a = fa[ch], b = fb[ch];
  U4 yv, rv;
  yv.v = *(const uint4*)(y2+base);
  rv.v = *(const uint4*)(resid+base);
  float4 o0, o1;
  float vv[8];
  #pragma unroll
  for(int j=0;j<8;j++){
    float v = fmaf(a, b2f(yv.s[j]), b) + b2f(rv.s[j]);
    vv[j] = v>0.f ? v : 0.f;
  }
  o0.x=vv[0]; o0.y=vv[1]; o0.z=vv[2]; o0.w=vv[3];
  o1.x=vv[4]; o1.y=vv[5]; o1.z=vv[6]; o1.w=vv[7];
  *(float4*)(out+base)   = o0;
  *(float4*)(out+base+4) = o1;
}

extern "C" void kernel_launch(void* const* d_in, const int* in_sizes, int n_in,
                              void* d_out, int out_size, void* d_ws, size_t ws_size,
                              hipStream_t stream)
{
  const float* X    = (const float*)d_in[0];
  const int*  src   = (const int*)d_in[1];
  const int*  dst   = (const int*)d_in[2];
  const float* rp_w = (const float*)d_in[3];
  const float* rp_b = (const float*)d_in[4];
  const float* g1w1 = (const float*)d_in[5];
  const float* g1b1 = (const float*)d_in[6];
  const float* g1w2 = (const float*)d_in[7];
  const float* g1b2 = (const float*)d_in[8];
  const float* g1w3 = (const float*)d_in[9];
  const float* g1b3 = (const float*)d_in[10];
  const float* bn0g = (const float*)d_in[11];
  const float* bn0b = (const float*)d_in[12];
  const float* gatw = (const float*)d_in[13];
  const float* attnl= (const float*)d_in[14];
  const float* attnr= (const float*)d_in[15];
  const float* gbias= (const float*)d_in[16];
  const float* bn1g = (const float*)d_in[17];
  const float* bn1b = (const float*)d_in[18];
  const float* g2w1 = (const float*)d_in[19];
  const float* g2b1 = (const float*)d_in[20];
  const float* g2w2 = (const float*)d_in[21];
  const float* g2b2 = (const float*)d_in[22];
  const float* g2w3 = (const float*)d_in[23];
  const float* g2b3 = (const float*)d_in[24];
  const float* bn2g = (const float*)d_in[25];
  const float* bn2b = (const float*)d_in[26];
  float* out = (float*)d_out;
  (void)in_sizes; (void)n_in; (void)out_size; (void)ws_size;

  char* w = (char*)d_ws;
  float* bn0_sum = (float*)w;                 // 32
  float* bn0_sq  = bn0_sum + 32;              // 32
  float* bn1_sum = bn0_sum + 64;              // 1024
  float* bn1_sq  = bn1_sum + 1024;            // 1024
  float* bn2_sum = bn1_sq  + 1024;            // 32
  float* bn2_sq  = bn2_sum + 32;              // 32
  int*   counts  = (int*)(bn2_sq + 32);       // 20000
  size_t zeroBytes = (size_t)((char*)(counts + NN) - w);   // ~88.7 KB
  int*   offsets = counts + NN;               // 20004
  int*   cursor  = offsets + 20004;           // 20000
  int*   esrc    = cursor + NN;               // 320000
  float* el      = (float*)(esrc + NE);       // 80000
  float* er      = el + NN*4;                 // 80000
  float* ew      = er + NN*4;                 // 1,280,000
  float* wl      = ew + (size_t)NE*4;         // 1024
  float* wr      = wl + 1024;                 // 1024
  us16*  wb      = (us16*)(wr + 1024);        // 262144
  us16*  resid   = wb + 262144;               // 5,120,000
  us16*  gc1     = resid + 5120000;           // 5,120,000 (raw gated conv1)
  us16*  Axg     = gc1   + 5120000;           // 20,480,000  [hd][node][256]
  us16*  rst     = Axg   + 20480000;          // 20,480,000
  us16*  Wt      = rst   + 20480000;          // 36,864
  us16*  Wt1     = Wt    + 36864;             // 12,288
  us16*  y2      = gc1;                       // alias: gc1 dead after k_agg2

  hipMemsetAsync(d_ws, 0, zeroBytes, stream);
  k_misc<<<1706, 256, 0, stream>>>(gatw, wb, g2w1, g2w2, g2w3, Wt,
                                   g1w1, g1w2, g1w3, rp_w, Wt1,
                                   attnl, attnr, wl, wr, dst, counts);
  k_gemm1<<<1250, 256, 0, stream>>>(X, Wt1, g1b1, g1b2, g1b3, rp_b,
                                    gc1, resid, bn0_sum, bn0_sq);
  k_eler2<<<5000, 256, 0, stream>>>(gc1, bn0_sum, bn0_sq, bn0g, bn0b, wl, wr, el, er);
  k_scan<<<1, 1024, 0, stream>>>(counts, offsets, cursor);
  k_scatter<<<1250, 256, 0, stream>>>(src, dst, cursor, esrc, el, er, ew);
  k_agg2<<<NN, 256, 0, stream>>>(offsets, esrc, ew, gc1, bn0_sum, bn0_sq, bn0g, bn0b, Axg);
  k_gemm3<<<dim3(157, 2, 4), 256, 0, stream>>>(Axg, wb, gbias, rst);
  k_colstats<<<313, 256, 0, stream>>>(rst, bn1_sum, bn1_sq);
  k_gemm2<<<1250, 256, 0, stream>>>(rst, Wt, bn1_sum, bn1_sq, bn1g, bn1b,
                                    g2b1, g2b2, g2b3, y2, bn2_sum, bn2_sq);
  k_final<<<2500, 256, 0, stream>>>(y2, bn2_sum, bn2_sq, bn2g, bn2b, resid, out);
}

// Round 9
// 392.968 us; speedup vs baseline: 2.2571x; 1.1645x over previous
//
#include <hip/hip_runtime.h>
#include <stdint.h>

#define NN 20000
#define NE 320000

typedef unsigned short us16;
typedef __attribute__((ext_vector_type(8))) short short8;
typedef __attribute__((ext_vector_type(4))) float f32x4;

union U4 { uint4 v; us16 s[8]; unsigned u[4]; };
union U2 { uint2 v; us16 s[4]; };

__device__ __forceinline__ float b2f(us16 u){ return __uint_as_float(((unsigned)u)<<16); }
__device__ __forceinline__ us16 f2b(float f){
  unsigned u = __float_as_uint(f);
  u += 0x7fffu + ((u>>16)&1u);
  return (us16)(u>>16);
}

// ---------------- merged misc: gat_w cvt + conv2 wprep + conv1 wprep + wl/wr + hist ----------------
__global__ __launch_bounds__(256) void k_misc(
    const float* __restrict__ gatw, us16* __restrict__ Wb,
    const float* __restrict__ w1, const float* __restrict__ w2, const float* __restrict__ w3,
    us16* __restrict__ Wt,
    const float* __restrict__ c1w1, const float* __restrict__ c1w2, const float* __restrict__ c1w3,
    const float* __restrict__ rp_w, us16* __restrict__ Wt1,
    const float* __restrict__ attnl, const float* __restrict__ attnr,
    float* __restrict__ wl, float* __restrict__ wr,
    const int* __restrict__ dst, int* __restrict__ counts)
{
  const int b = blockIdx.x, tid = threadIdx.x;
  if(b < 256){
    int i = b*256 + tid;
    float4 v = *(const float4*)(gatw + (size_t)i*4);
    U2 o;
    o.s[0]=f2b(v.x); o.s[1]=f2b(v.y); o.s[2]=f2b(v.z); o.s[3]=f2b(v.w);
    *(uint2*)(Wb + (size_t)i*4) = o.v;
  } else if(b < 400){
    int i = (b-256)*256 + tid;       // 36864: Wt[s][co3(96)][ci(128)]
    int s = i/12288, rem = i%12288;
    int co3 = rem>>7, ci = rem&127;
    const float* w = (co3<32) ? w1 : (co3<64) ? w2 : w3;
    Wt[i] = f2b(w[(co3&31)*384 + ci*3 + s]);
  } else if(b < 448){
    int i = (b-400)*256 + tid;       // 12288: Wt1[s][co3(128)][ci(32)]
    int s = i>>12, rem = i&4095;
    int co3 = rem>>5, ci = rem&31;
    float v;
    if(co3 < 96){
      const float* w = (co3<32) ? c1w1 : (co3<64) ? c1w2 : c1w3;
      v = w[(co3&31)*96 + ci*3 + s];
    } else {
      v = (s==1) ? rp_w[(co3-96)*32 + ci] : 0.f;
    }
    Wt1[i] = f2b(v);
  } else if(b < 456){
    // wl/wr[hd][k] = sum_f attn[hd][f] * W[hd*256+f][k]
    int bb = b-448;
    int sel = bb>>2, hd = bb&3, k = tid;
    const float* attn = sel ? attnr : attnl;
    float s = 0.f;
    for(int f=0; f<256; f++)
      s = fmaf(attn[hd*256+f], gatw[(size_t)(hd*256+f)*256 + k], s);
    (sel ? wr : wl)[hd*256+k] = s;
  } else {
    int e = (b-456)*256 + tid;
    if(e < NE) atomicAdd(&counts[dst[e]], 1);
  }
}

// ---------------- conv1 (+residual k1) as MFMA GEMM, X read direct (fp32) ----------------
__global__ __launch_bounds__(256) void k_gemm1(
    const float* __restrict__ X, const us16* __restrict__ Wt1,
    const float* __restrict__ b1, const float* __restrict__ b2, const float* __restrict__ b3,
    const float* __restrict__ rp_b,
    us16* __restrict__ gc1, us16* __restrict__ resid,
    float* __restrict__ bn0_sum, float* __restrict__ bn0_sq)
{
  __shared__ float smemF[16896];
  us16* As = (us16*)smemF;                // [16][10][40]
  us16* Bs = As + 6400;                   // [3][128][40]
  float* Cs = smemF;                      // [128][132]
  __shared__ float redS[32], redQ[32];
  const int tid = threadIdx.x;
  if(tid<32){ redS[tid]=0.f; redQ[tid]=0.f; }
  const int node0 = blockIdx.x*16;
  const int lane = tid&63, wv = tid>>6;
  const int wm = wv&1, wn = wv>>1;
  const int mrow = lane&15, kg = (lane>>4)*8;
  for(int idx=tid; idx<1024; idx+=256){
    int n = idx>>6, rem = idx&63, slot = (rem>>5)*9, ci = rem&31;
    As[n*400 + slot*40 + ci] = 0;
  }
  #pragma unroll
  for(int i=0;i<4;i++){
    int idx = i*256 + tid;
    int n = idx>>6, rem = idx&63, ci = rem>>1, tq = rem&1;
    float4 xv = *(const float4*)(X + (size_t)(node0+n)*256 + ci*8 + tq*4);
    us16* p = &As[n*400 + (tq*4+1)*40 + ci];
    p[0]   = f2b(xv.x);
    p[40]  = f2b(xv.y);
    p[80]  = f2b(xv.z);
    p[120] = f2b(xv.w);
  }
  #pragma unroll
  for(int i=0;i<6;i++){
    int c = i*256 + tid;
    int s = c>>9, rem = c&511, co = rem>>2, cq = rem&3;
    *(uint4*)&Bs[s*5120 + co*40 + cq*8] = *(const uint4*)(Wt1 + s*4096 + co*32 + cq*8);
  }
  __syncthreads();
  f32x4 acc[4][4] = {};
  #pragma unroll
  for(int s=0; s<3; s++){
    short8 af[4], bfr[4];
    #pragma unroll
    for(int i=0;i<4;i++){
      int r = wm*64 + i*16 + mrow;
      af[i] = *(const short8*)&As[(r>>3)*400 + ((r&7)+s)*40 + kg];
    }
    #pragma unroll
    for(int j=0;j<4;j++)
      bfr[j] = *(const short8*)&Bs[s*5120 + (wn*64 + j*16 + mrow)*40 + kg];
    #pragma unroll
    for(int i=0;i<4;i++){
      #pragma unroll
      for(int j=0;j<4;j++)
        acc[i][j] = __builtin_amdgcn_mfma_f32_16x16x32_bf16(af[i], bfr[j], acc[i][j], 0, 0, 0);
    }
  }
  __syncthreads();
  #pragma unroll
  for(int i=0;i<4;i++){
    #pragma unroll
    for(int j=0;j<4;j++){
      #pragma unroll
      for(int r=0;r<4;r++)
        Cs[(wm*64 + i*16 + (lane>>4)*4 + r)*132 + wn*64 + j*16 + (lane&15)] = acc[i][j][r];
    }
  }
  __syncthreads();
  const int co = tid&31, rg = tid>>5;
  const float bb1=b1[co], bb2=b2[co], bb3=b3[co], bbr=rp_b[co];
  float s=0.f, q=0.f;
  #pragma unroll
  for(int half=0; half<2; half++){
    U4 ov, rv;
    #pragma unroll
    for(int t=0;t<8;t++){
      int r = rg*16 + half*8 + t;
      float c1 = Cs[r*132 + co]      + bb1;
      float c2 = Cs[r*132 + co + 32] + bb2;
      float c3 = Cs[r*132 + co + 64] + bb3;
      float rr = Cs[r*132 + co + 96] + bbr;
      float sg = 1.f/(1.f+__expf(-c2));
      float v = fmaf(c1, sg, c3);
      v = v>0.f ? v : 0.f;
      s += v; q += v*v;
      ov.s[t] = f2b(v);
      rv.s[t] = f2b(rr);
    }
    int node = node0 + rg*2 + half;
    *(uint4*)(gc1   + (size_t)node*256 + co*8) = ov.v;
    *(uint4*)(resid + (size_t)node*256 + co*8) = rv.v;
  }
  atomicAdd(&redS[co], s); atomicAdd(&redQ[co], q);
  __syncthreads();
  if(tid<32)      atomicAdd(&bn0_sum[tid], redS[tid]);
  else if(tid<64) atomicAdd(&bn0_sq[tid-32], redQ[tid-32]);
}

// ---------------- el/er directly from gc1 (bn0 folded): wave per node ----------------
__global__ __launch_bounds__(256) void k_eler2(const us16* __restrict__ gc1,
    const float* __restrict__ bn0_sum, const float* __restrict__ bn0_sq,
    const float* __restrict__ bn0g, const float* __restrict__ bn0b,
    const float* __restrict__ wl, const float* __restrict__ wr,
    float* __restrict__ el, float* __restrict__ er)
{
  __shared__ float sa[32], sb[32];
  const int tid = threadIdx.x;
  if(tid<32){
    float m = bn0_sum[tid]*(1.f/160000.f);
    float v = bn0_sq[tid]*(1.f/160000.f) - m*m;
    float a = bn0g[tid]*rsqrtf(v + 1e-5f);
    sa[tid] = a; sb[tid] = bn0b[tid] - m*a;
  }
  __syncthreads();
  const int wv = tid>>6, lane = tid&63;
  const int node = blockIdx.x*4 + wv;
  U2 g; g.v = *(const uint2*)(gc1 + (size_t)node*256 + lane*4);
  const float a = sa[lane>>1], b = sb[lane>>1];
  float xv[4];
  #pragma unroll
  for(int j=0;j<4;j++) xv[j] = fmaf(a, b2f(g.s[j]), b);
  float res[8];
  #pragma unroll
  for(int hd=0; hd<4; hd++){
    float4 lv = *(const float4*)(wl + hd*256 + lane*4);
    float4 rv = *(const float4*)(wr + hd*256 + lane*4);
    res[hd]   = xv[0]*lv.x + xv[1]*lv.y + xv[2]*lv.z + xv[3]*lv.w;
    res[4+hd] = xv[0]*rv.x + xv[1]*rv.y + xv[2]*rv.z + xv[3]*rv.w;
  }
  #pragma unroll
  for(int o=32;o;o>>=1){
    #pragma unroll
    for(int k=0;k<8;k++) res[k] += __shfl_xor(res[k], o, 64);
  }
  if(lane==0){
    #pragma unroll
    for(int hd=0;hd<4;hd++){ el[node*4+hd]=res[hd]; er[node*4+hd]=res[4+hd]; }
  }
}

// ---------------- scan ----------------
__global__ __launch_bounds__(1024) void k_scan(const int* __restrict__ counts,
                                               int* __restrict__ offsets, int* __restrict__ cursor)
{
  __shared__ int buf[1024];
  const int tid = threadIdx.x;
  const int base = tid*20;
  int loc[20];
  int s = 0;
  #pragma unroll
  for(int j=0;j<20;j++){
    int idx = base+j;
    int v = (idx<NN) ? counts[idx] : 0;
    loc[j] = s; s += v;
  }
  buf[tid] = s;
  __syncthreads();
  for(int off=1; off<1024; off<<=1){
    int t = (tid>=off) ? buf[tid-off] : 0;
    __syncthreads();
    buf[tid] += t;
    __syncthreads();
  }
  int excl = buf[tid] - s;
  #pragma unroll
  for(int j=0;j<20;j++){
    int idx = base+j;
    if(idx<NN){ offsets[idx]=excl+loc[j]; cursor[idx]=excl+loc[j]; }
  }
  if(tid==1023) offsets[NN] = excl + s;
}

// ---------------- scatter + edge scores ----------------
__global__ __launch_bounds__(256) void k_scatter(const int* __restrict__ src, const int* __restrict__ dst,
    int* __restrict__ cursor, int* __restrict__ esrc,
    const float* __restrict__ el, const float* __restrict__ er,
    float* __restrict__ ew)
{
  int e = blockIdx.x*256 + threadIdx.x;
  if(e < NE){
    int s = src[e], d = dst[e];
    int pos = atomicAdd(&cursor[d], 1);
    esrc[pos] = s;
    float4 lv = *(const float4*)(el + s*4);
    float4 rv = *(const float4*)(er + d*4);
    float4 sc;
    sc.x = lv.x+rv.x; sc.x = sc.x>0.f ? sc.x : 0.2f*sc.x;
    sc.y = lv.y+rv.y; sc.y = sc.y>0.f ? sc.y : 0.2f*sc.y;
    sc.z = lv.z+rv.z; sc.z = sc.z>0.f ? sc.z : 0.2f*sc.z;
    sc.w = lv.w+rv.w; sc.w = sc.w>0.f ? sc.w : 0.2f*sc.w;
    *(float4*)(ew + (size_t)pos*4) = sc;
  }
}

// ---------------- GAT aggregate in x-space: one wave per node, no LDS, no barriers ----------------
__global__ __launch_bounds__(256) void k_agg2(
    const int* __restrict__ offsets, const int* __restrict__ esrc,
    const float* __restrict__ ew, const us16* __restrict__ gc1,
    const float* __restrict__ bn0_sum, const float* __restrict__ bn0_sq,
    const float* __restrict__ bn0g, const float* __restrict__ bn0b,
    us16* __restrict__ Axg)
{
  const int tid = threadIdx.x;
  const int wv = tid>>6, lane = tid&63;
  const int node = blockIdx.x*4 + wv;
  // per-lane bn0 affine for its single channel (feats lane*4..lane*4+3 all share ch = lane>>1)
  const int ch = lane>>1;
  float mmn = bn0_sum[ch]*(1.f/160000.f);
  float vvn = bn0_sq[ch]*(1.f/160000.f) - mmn*mmn;
  float sa = bn0g[ch]*rsqrtf(vvn + 1e-5f);
  float sb = bn0b[ch] - mmn*sa;
  const int beg = offsets[node];
  const int deg = offsets[node+1] - beg;
  // phase 1: head h = lane>>4, slot i0 = lane&15 — wave reads 256B coalesced per iter
  const int h = lane>>4, i0 = lane&15;
  float m = -3.0e38f;
  for(int i=i0; i<deg; i+=16) m = fmaxf(m, ew[(size_t)(beg+i)*4 + h]);
  m = fmaxf(m, __shfl_xor(m,1,64)); m = fmaxf(m, __shfl_xor(m,2,64));
  m = fmaxf(m, __shfl_xor(m,4,64)); m = fmaxf(m, __shfl_xor(m,8,64));
  float den = 0.f;
  for(int i=i0; i<deg; i+=16) den += __expf(ew[(size_t)(beg+i)*4 + h] - m);
  den += __shfl_xor(den,1,64); den += __shfl_xor(den,2,64);
  den += __shfl_xor(den,4,64); den += __shfl_xor(den,8,64);
  const float m0=__shfl(m,0,64),   m1=__shfl(m,16,64),  m2=__shfl(m,32,64),  m3=__shfl(m,48,64);
  const float d0=__shfl(den,0,64), d1=__shfl(den,16,64),d2=__shfl(den,32,64),d3=__shfl(den,48,64);
  const float v0=d0>0.f?1.f/d0:0.f, v1=d1>0.f?1.f/d1:0.f,
              v2=d2>0.f?1.f/d2:0.f, v3=d3>0.f?1.f/d3:0.f;
  float a0c[4]={},a1c[4]={},a2c[4]={},a3c[4]={};
  #pragma unroll 4
  for(int j=0; j<deg; j++){
    int pos = beg+j;
    float4 w4 = *(const float4*)(ew + (size_t)pos*4);   // broadcast
    int sN = esrc[pos];                                  // broadcast
    U2 hv; hv.v = *(const uint2*)(gc1 + (size_t)sN*256 + lane*4);  // 512B/wave
    float e0 = __expf(w4.x-m0)*v0;
    float e1 = __expf(w4.y-m1)*v1;
    float e2 = __expf(w4.z-m2)*v2;
    float e3 = __expf(w4.w-m3)*v3;
    #pragma unroll
    for(int kk=0;kk<4;kk++){
      float x = b2f(hv.s[kk]);
      a0c[kk] = fmaf(e0,x,a0c[kk]);
      a1c[kk] = fmaf(e1,x,a1c[kk]);
      a2c[kk] = fmaf(e2,x,a2c[kk]);
      a3c[kk] = fmaf(e3,x,a3c[kk]);
    }
  }
  const float sbi = sb * ((deg>0)?1.f:0.f);
  U2 o0,o1,o2,o3;
  #pragma unroll
  for(int kk=0;kk<4;kk++){
    o0.s[kk]=f2b(fmaf(sa,a0c[kk],sbi));
    o1.s[kk]=f2b(fmaf(sa,a1c[kk],sbi));
    o2.s[kk]=f2b(fmaf(sa,a2c[kk],sbi));
    o3.s[kk]=f2b(fmaf(sa,a3c[kk],sbi));
  }
  *(uint2*)(Axg + ((size_t)node)*256            + lane*4) = o0.v;
  *(uint2*)(Axg + ((size_t)NN + node)*256       + lane*4) = o1.v;
  *(uint2*)(Axg + ((size_t)2*NN + node)*256     + lane*4) = o2.v;
  *(uint2*)(Axg + ((size_t)3*NN + node)*256     + lane*4) = o3.v;
}

// ---------------- rst GEMM + fused bn1 column stats ----------------
__global__ __launch_bounds__(256) void k_gemm3(const us16* __restrict__ Axg, const us16* __restrict__ Wb,
    const float* __restrict__ gbias, us16* __restrict__ rst,
    float* __restrict__ bn1_sum, float* __restrict__ bn1_sq)
{
  __shared__ us16 As[128*72];
  __shared__ us16 Bs[128*72];
  const int tid = threadIdx.x;
  const int row0 = blockIdx.x*128;
  const int cb   = blockIdx.y*128;      // col within head
  const int hd   = blockIdx.z;
  const us16* A = Axg + (size_t)hd*NN*256;
  const us16* B = Wb  + (size_t)(hd*256 + cb)*256;
  const int lane = tid&63, wv = tid>>6;
  const int wm = wv&1, wn = wv>>1;
  const int mrow = lane&15, kg = (lane>>4)*8;
  f32x4 acc[4][4] = {};
  for(int k0=0; k0<256; k0+=64){
    #pragma unroll
    for(int i=0;i<4;i++){
      int chunk = i*256 + tid;
      int row = chunk>>3, cc = chunk&7;
      int g = row0 + row;
      uint4 av; av.x=0;av.y=0;av.z=0;av.w=0;
      if(g < NN) av = *(const uint4*)(A + (size_t)g*256 + k0 + cc*8);
      *(uint4*)&As[row*72 + cc*8] = av;
      *(uint4*)&Bs[row*72 + cc*8] = *(const uint4*)(B + (size_t)row*256 + k0 + cc*8);
    }
    __syncthreads();
    #pragma unroll
    for(int kk=0; kk<64; kk+=32){
      short8 af[4], bfr[4];
      #pragma unroll
      for(int i=0;i<4;i++) af[i]  = *(const short8*)&As[(wm*64 + i*16 + mrow)*72 + kk + kg];
      #pragma unroll
      for(int j=0;j<4;j++) bfr[j] = *(const short8*)&Bs[(wn*64 + j*16 + mrow)*72 + kk + kg];
      #pragma unroll
      for(int i=0;i<4;i++){
        #pragma unroll
        for(int j=0;j<4;j++)
          acc[i][j] = __builtin_amdgcn_mfma_f32_16x16x32_bf16(af[i], bfr[j], acc[i][j], 0, 0, 0);
      }
    }
    __syncthreads();
  }
  float gb[4];
  #pragma unroll
  for(int j=0;j<4;j++)
    gb[j] = gbias[hd*256 + cb + wn*64 + j*16 + (lane&15)];
  float cs[4]={}, cq[4]={};
  #pragma unroll
  for(int i=0;i<4;i++){
    #pragma unroll
    for(int j=0;j<4;j++){
      #pragma unroll
      for(int r=0;r<4;r++){
        int g = row0 + wm*64 + i*16 + (lane>>4)*4 + r;
        if(g < NN){
          float v = acc[i][j][r] + gb[j];
          v = v>0.f ? v : 0.f;
          rst[(size_t)g*1024 + hd*256 + cb + wn*64 + j*16 + (lane&15)] = f2b(v);
          cs[j] += v; cq[j] += v*v;
        }
      }
    }
  }
  #pragma unroll
  for(int j=0;j<4;j++){
    cs[j] += __shfl_xor(cs[j],16,64); cs[j] += __shfl_xor(cs[j],32,64);
    cq[j] += __shfl_xor(cq[j],16,64); cq[j] += __shfl_xor(cq[j],32,64);
  }
  if(lane < 16){
    #pragma unroll
    for(int j=0;j<4;j++){
      int col = hd*256 + cb + wn*64 + j*16 + lane;
      atomicAdd(&bn1_sum[col], cs[j]);
      atomicAdd(&bn1_sq[col],  cq[j]);
    }
  }
}

// ---------------- conv2 as MFMA GEMM; rst direct, bn1 at staging ----------------
__global__ __launch_bounds__(256) void k_gemm2(
    const us16* __restrict__ rst, const us16* __restrict__ Wt,
    const float* __restrict__ bn1_sum, const float* __restrict__ bn1_sq,
    const float* __restrict__ bn1g, const float* __restrict__ bn1b,
    const float* __restrict__ b1, const float* __restrict__ b2, const float* __restrict__ b3,
    us16* __restrict__ y2, float* __restrict__ bn2_sum, float* __restrict__ bn2_sq)
{
  __shared__ float smemF[16384];
  float* s1a = smemF;
  float* s1b = smemF + 1024;
  us16* As = (us16*)(smemF + 2048);       // [16][10][136]
  us16* Bs = As + 21760;                  // [96][72]
  float* Cs = (float*)(smemF + 2048);     // [128][100]
  __shared__ float redS[32], redQ[32];
  const int tid = threadIdx.x;
  if(tid<32){ redS[tid]=0.f; redQ[tid]=0.f; }
  const int node0 = blockIdx.x*16;
  const int lane = tid&63, wv = tid>>6;
  const int wm = wv&1, wn = wv>>1;
  const int mrow = lane&15, kg = (lane>>4)*8;
  for(int f=tid; f<1024; f+=256){
    float m = bn1_sum[f]*(1.f/20000.f);
    float v = bn1_sq[f]*(1.f/20000.f) - m*m;
    float a = bn1g[f]*rsqrtf(v + 1e-5f);
    int l = (f&7)*128 + (f>>3);
    s1a[l] = a; s1b[l] = bn1b[f] - m*a;
  }
  for(int idx=tid; idx<4096; idx+=256){
    int n = idx>>8, rem = idx&255, slot = (rem>>7)*9, ci = rem&127;
    As[n*1360 + slot*136 + ci] = 0;
  }
  __syncthreads();
  #pragma unroll
  for(int i=0;i<8;i++){
    int idx = i*256 + tid;
    int n = idx>>7, ci = idx&127;
    U4 in; in.v = *(const uint4*)(rst + (size_t)(node0+n)*1024 + ci*8);
    us16* p = &As[n*1360 + 136 + ci];
    #pragma unroll
    for(int t=0;t<8;t++){
      float a = s1a[t*128+ci], b = s1b[t*128+ci];
      p[t*136] = f2b(fmaf(a, b2f(in.s[t]), b));
    }
  }
  f32x4 acc[4][3] = {};
  for(int rd=0; rd<6; rd++){
    const int s = rd>>1, kc = rd&1;
    __syncthreads();
    #pragma unroll
    for(int i=0;i<3;i++){
      int chunk = i*256 + tid;
      int brow = chunk>>3, cc = chunk&7;
      *(uint4*)&Bs[brow*72 + cc*8] =
        *(const uint4*)(Wt + s*12288 + brow*128 + kc*64 + cc*8);
    }
    __syncthreads();
    #pragma unroll
    for(int kk=0; kk<64; kk+=32){
      short8 af[4], bfr[3];
      #pragma unroll
      for(int i=0;i<4;i++){
        int r = wm*64 + i*16 + mrow;
        af[i] = *(const short8*)&As[(r>>3)*1360 + ((r&7)+s)*136 + kc*64 + kk + kg];
      }
      #pragma unroll
      for(int j=0;j<3;j++)
        bfr[j] = *(const short8*)&Bs[(wn*48 + j*16 + mrow)*72 + kk + kg];
      #pragma unroll
      for(int i=0;i<4;i++){
        #pragma unroll
        for(int j=0;j<3;j++)
          acc[i][j] = __builtin_amdgcn_mfma_f32_16x16x32_bf16(af[i], bfr[j], acc[i][j], 0, 0, 0);
      }
    }
  }
  __syncthreads();
  #pragma unroll
  for(int i=0;i<4;i++){
    #pragma unroll
    for(int j=0;j<3;j++){
      #pragma unroll
      for(int r=0;r<4;r++)
        Cs[(wm*64 + i*16 + (lane>>4)*4 + r)*100 + wn*48 + j*16 + (lane&15)] = acc[i][j][r];
    }
  }
  __syncthreads();
  const int co = tid&31, rg = tid>>5;
  const float bb1=b1[co], bb2=b2[co], bb3=b3[co];
  float s=0.f, q=0.f;
  #pragma unroll
  for(int half=0; half<2; half++){
    U4 ov;
    #pragma unroll
    for(int t=0;t<8;t++){
      int r = rg*16 + half*8 + t;
      float c1 = Cs[r*100 + co]      + bb1;
      float c2 = Cs[r*100 + co + 32] + bb2;
      float c3 = Cs[r*100 + co + 64] + bb3;
      float sg = 1.f/(1.f+__expf(-c2));
      float v = fmaf(c1, sg, c3);
      v = v>0.f ? v : 0.f;
      s += v; q += v*v;
      ov.s[t] = f2b(v);
    }
    int node = node0 + rg*2 + half;
    *(uint4*)(y2 + (size_t)node*256 + co*8) = ov.v;
  }
  atomicAdd(&redS[co], s); atomicAdd(&redQ[co], q);
  __syncthreads();
  if(tid<32)      atomicAdd(&bn2_sum[tid], redS[tid]);
  else if(tid<64) atomicAdd(&bn2_sq[tid-32], redQ[tid-32]);
}

// ---------------- final ----------------
__global__ __launch_bounds__(256) void k_final(const us16* __restrict__ y2,
    const float* __restrict__ bn2_sum, const float* __restrict__ bn2_sq,
    const float* __restrict__ bn2g, const float* __restrict__ bn2b,
    const us16* __restrict__ resid, float* __restrict__ out)
{
  __shared__ float fa[32], fb[32];
  const int tid = threadIdx.x;
  if(tid<32){
    float m = bn2_sum[tid]*(1.f/160000.f);
    float v = bn2_sq[tid]*(1.f/160000.f) - m*m;
    float a = bn2g[tid]*rsqrtf(v + 1e-5f);
    fa[tid] = a; fb[tid] = bn2b[tid] - m*a;
  }
  __syncthreads();
  size_t base = ((size_t)blockIdx.x*256 + tid)*8;
  int ch = (int)((base>>3)&31);
  float a = fa[ch], b = fb[ch];
  U4 yv, rv;
  yv.v = *(const uint4*)(y2+base);
  rv.v = *(const uint4*)(resid+base);
  float4 o0, o1;
  float vv[8];
  #pragma unroll
  for(int j=0;j<8;j++){
    float v = fmaf(a, b2f(yv.s[j]), b) + b2f(rv.s[j]);
    vv[j] = v>0.f ? v : 0.f;
  }
  o0.x=vv[0]; o0.y=vv[1]; o0.z=vv[2]; o0.w=vv[3];
  o1.x=vv[4]; o1.y=vv[5]; o1.z=vv[6]; o1.w=vv[7];
  *(float4*)(out+base)   = o0;
  *(float4*)(out+base+4) = o1;
}

extern "C" void kernel_launch(void* const* d_in, const int* in_sizes, int n_in,
                              void* d_out, int out_size, void* d_ws, size_t ws_size,
                              hipStream_t stream)
{
  const float* X    = (const float*)d_in[0];
  const int*  src   = (const int*)d_in[1];
  const int*  dst   = (const int*)d_in[2];
  const float* rp_w = (const float*)d_in[3];
  const float* rp_b = (const float*)d_in[4];
  const float* g1w1 = (const float*)d_in[5];
  const float* g1b1 = (const float*)d_in[6];
  const float* g1w2 = (const float*)d_in[7];
  const float* g1b2 = (const float*)d_in[8];
  const float* g1w3 = (const float*)d_in[9];
  const float* g1b3 = (const float*)d_in[10];
  const float* bn0g = (const float*)d_in[11];
  const float* bn0b = (const float*)d_in[12];
  const float* gatw = (const float*)d_in[13];
  const float* attnl= (const float*)d_in[14];
  const float* attnr= (const float*)d_in[15];
  const float* gbias= (const float*)d_in[16];
  const float* bn1g = (const float*)d_in[17];
  const float* bn1b = (const float*)d_in[18];
  const float* g2w1 = (const float*)d_in[19];
  const float* g2b1 = (const float*)d_in[20];
  const float* g2w2 = (const float*)d_in[21];
  const float* g2b2 = (const float*)d_in[22];
  const float* g2w3 = (const float*)d_in[23];
  const float* g2b3 = (const float*)d_in[24];
  const float* bn2g = (const float*)d_in[25];
  const float* bn2b = (const float*)d_in[26];
  float* out = (float*)d_out;
  (void)in_sizes; (void)n_in; (void)out_size; (void)ws_size;

  char* w = (char*)d_ws;
  float* bn0_sum = (float*)w;                 // 32
  float* bn0_sq  = bn0_sum + 32;              // 32
  float* bn1_sum = bn0_sum + 64;              // 1024
  float* bn1_sq  = bn1_sum + 1024;            // 1024
  float* bn2_sum = bn1_sq  + 1024;            // 32
  float* bn2_sq  = bn2_sum + 32;              // 32
  int*   counts  = (int*)(bn2_sq + 32);       // 20000
  size_t zeroBytes = (size_t)((char*)(counts + NN) - w);   // ~88.7 KB
  int*   offsets = counts + NN;               // 20004
  int*   cursor  = offsets + 20004;           // 20000
  int*   esrc    = cursor + NN;               // 320000
  float* el      = (float*)(esrc + NE);       // 80000
  float* er      = el + NN*4;                 // 80000
  float* ew      = er + NN*4;                 // 1,280,000
  float* wl      = ew + (size_t)NE*4;         // 1024
  float* wr      = wl + 1024;                 // 1024
  us16*  wb      = (us16*)(wr + 1024);        // 262144
  us16*  resid   = wb + 262144;               // 5,120,000
  us16*  gc1     = resid + 5120000;           // 5,120,000 (raw gated conv1)
  us16*  Axg     = gc1   + 5120000;           // 20,480,000  [hd][node][256]
  us16*  rst     = Axg   + 20480000;          // 20,480,000
  us16*  Wt      = rst   + 20480000;          // 36,864
  us16*  Wt1     = Wt    + 36864;             // 12,288
  us16*  y2      = gc1;                       // alias: gc1 dead after k_agg2

  hipMemsetAsync(d_ws, 0, zeroBytes, stream);
  k_misc<<<1706, 256, 0, stream>>>(gatw, wb, g2w1, g2w2, g2w3, Wt,
                                   g1w1, g1w2, g1w3, rp_w, Wt1,
                                   attnl, attnr, wl, wr, dst, counts);
  k_gemm1<<<1250, 256, 0, stream>>>(X, Wt1, g1b1, g1b2, g1b3, rp_b,
                                    gc1, resid, bn0_sum, bn0_sq);
  k_eler2<<<5000, 256, 0, stream>>>(gc1, bn0_sum, bn0_sq, bn0g, bn0b, wl, wr, el, er);
  k_scan<<<1, 1024, 0, stream>>>(counts, offsets, cursor);
  k_scatter<<<1250, 256, 0, stream>>>(src, dst, cursor, esrc, el, er, ew);
  k_agg2<<<5000, 256, 0, stream>>>(offsets, esrc, ew, gc1, bn0_sum, bn0_sq, bn0g, bn0b, Axg);
  k_gemm3<<<dim3(157, 2, 4), 256, 0, stream>>>(Axg, wb, gbias, rst, bn1_sum, bn1_sq);
  k_gemm2<<<1250, 256, 0, stream>>>(rst, Wt, bn1_sum, bn1_sq, bn1g, bn1b,
                                    g2b1, g2b2, g2b3, y2, bn2_sum, bn2_sq);
  k_final<<<2500, 256, 0, stream>>>(y2, bn2_sum, bn2_sq, bn2g, bn2b, resid, out);
}